// Round 10
// baseline (321.525 us; speedup 1.0000x reference)
//
#include <hip/hip_runtime.h>
#include <math.h>

#define DD   46
#define LL0  4000
#define LL1  600
#define CATV 250
#define NC   50
#define NJ   100
#define HC   256
#define H2C  128
#define NPOS (LL0*NJ)
#define EPSV 1e-5f
#define NT   64
#define XROW 104
#define C1ROW 268
#define C2PAD 68
#define TILES (NPOS/NT)   // 6250
#define GRIDP 768

// ---- workspace float offsets ----
#define W_MEAN0   0
#define W_MEANH   64
#define W_MEANL   128
#define W_RM4     192
#define W_RM5     256
#define W_S1      320
#define W_HBAR    384
#define W_RAWMH   448
#define W_RAWML   2752
#define W_H       5056
#define W_L       7360
#define W_BN1S    9664            // 256 sum + 256 sumsq
#define W_SC1     10176           // 256 scale + 256 shift
#define W_BN2S    10688           // 128+128
#define W_SC2     10944           // 128+128 -> 11200
#define W_HBF     11200           // 2400 ushort [j][48]
#define W_LBF     12400           // 2400 ushort
#define W_AWT     13632           // [4001][144] f32
#define W_W1P     589776          // 256*96 bf16
#define W_W2BF    602064          // 128*256 bf16
#define W_BIAS2   618448          // 128 floats

typedef __attribute__((ext_vector_type(8))) short bf8;
typedef __attribute__((ext_vector_type(4))) float f32x4;
typedef __attribute__((ext_vector_type(4))) unsigned u32x4;

__device__ __forceinline__ float sigf(float x){ return 1.0f/(1.0f+__expf(-x)); }

__device__ __forceinline__ unsigned short f2bf(float f){
  unsigned u = __float_as_uint(f);
  return (unsigned short)((u + 0x7FFFu + ((u>>16)&1u)) >> 16);
}
__device__ __forceinline__ unsigned pk2bf(float a, float b){
  return ((unsigned)f2bf(b)<<16) | (unsigned)f2bf(a);
}
__device__ __forceinline__ float bf2f(unsigned short h){
  return __uint_as_float(((unsigned)h)<<16);
}

__device__ float blockReduceSum(float v, float* sm){
  int tid=threadIdx.x;
  sm[tid]=v; __syncthreads();
  for(int s=128;s>0;s>>=1){ if(tid<s) sm[tid]+=sm[tid+s]; __syncthreads(); }
  float r=sm[0]; __syncthreads();
  return r;
}

// W1 -> bf16 permuted [o][2d+p]; block 0 zeros BN stat region
__global__ void k_prep(const float* __restrict__ conv_w, float* __restrict__ ws){
  int t=blockIdx.x*256+threadIdx.x;
  if(blockIdx.x==0){ for(int e=threadIdx.x;e<1536;e+=256) ws[W_BN1S+e]=0.f; }
  if(t<HC*96){
    int o=t/96, c=t-o*96;
    unsigned short v=0;
    if(c<92){ int d=c>>1, p=c&1; v=f2bf(conv_w[o*92 + (p? 46+d : d)]); }
    ((unsigned short*)(ws+W_W1P))[t]=v;
  }
}

// W2' = W2*sc1 (bf16), bias2' = b2 + sum_k W2[o2,k]*sh1[k]
__global__ void k_prep2(const float* __restrict__ conv2_w, const float* __restrict__ conv2_b,
                        float* __restrict__ ws){
  __shared__ float sm[256];
  int o2=blockIdx.x, t=threadIdx.x;
  float wv=conv2_w[o2*HC+t];
  float sc=ws[W_SC1+t], sh=ws[W_SC1+HC+t];
  ((unsigned short*)(ws+W_W2BF))[o2*HC+t]=f2bf(wv*sc);
  float r=blockReduceSum(wv*sh,sm);
  if(t==0) ws[W_BIAS2+o2]=conv2_b[o2]+r;
}

// fused: per-channel means + raw pair-difference means, block d
__global__ void k_means(const float* __restrict__ z0, const float* __restrict__ z1,
                        const int* cdrH, const int* notH,
                        const int* cdrL, const int* notL,
                        int nCdrH,int nNotH,int nCdrL,int nNotL, float* ws){
  __shared__ float v[LL1];
  __shared__ float sm[256];
  int d=blockIdx.x, tid=threadIdx.x;
  float s0=0.f; for(int i=tid;i<LL0;i+=256) s0+=z0[i*DD+d];
  for(int k=tid;k<LL1;k+=256) v[k]=z1[k*DD+d];
  float r0=blockReduceSum(s0,sm);
  __syncthreads();
  float sH=0.f; for(int k=tid;k<CATV;k+=256) sH+=v[k];
  float sL=0.f; for(int k=CATV+tid;k<LL1;k+=256) sL+=v[k];
  float rH=blockReduceSum(sH,sm);
  float rL=blockReduceSum(sL,sm);
  float partH=0.f, partL=0.f;
  for(int i=tid;i<nCdrH;i+=256){
    float c=v[cdrH[i]]; float s=0.f;
    for(int j=0;j<nNotH;j++) s+=fabsf(c-v[notH[j]]);
    s/= (float)nNotH;
    ws[W_RAWMH+d*NC+i]=s; partH+=s;
  }
  for(int i=tid;i<nCdrL;i+=256){
    float c=v[CATV+cdrL[i]]; float s=0.f;
    for(int j=0;j<nNotL;j++) s+=fabsf(c-v[CATV+notL[j]]);
    s/= (float)nNotL;
    ws[W_RAWML+d*NC+i]=s; partL+=s;
  }
  float pH=blockReduceSum(partH,sm);
  float pL=blockReduceSum(partL,sm);
  if(tid==0){
    ws[W_MEAN0+d]=r0/(float)LL0;
    ws[W_MEANH+d]=rH/(float)CATV;
    ws[W_MEANL+d]=rL/(float)(LL1-CATV);
    ws[W_RM4+d]=pH/(float)nCdrH;
    ws[W_RM5+d]=pL/(float)nCdrL;
  }
}

__device__ __forceinline__ float conv3(const float* a, int d, const float* w){
  float acc = w[1]*a[d];
  if(d>0)    acc += w[0]*a[d-1];
  if(d<DD-1) acc += w[2]*a[d+1];
  return acc;
}

// scales + final h, l, hbar + bf16 table copies [j][48]
__global__ void k_scales(const float* w1,const float* w2,const float* w3,
                         const float* w4,const float* w5, float* ws){
  __shared__ float m0[DD], mH[DD], mL[DD];
  __shared__ float s1s[DD],s2s[DD],s3s[DD],s4s[DD],s5s[DD],y4[DD],y5[DD];
  int tid=threadIdx.x;
  if(tid<DD){ m0[tid]=ws[W_MEAN0+tid]; mH[tid]=ws[W_MEANH+tid]; mL[tid]=ws[W_MEANL+tid]; }
  __syncthreads();
  if(tid<DD){
    s1s[tid]=sigf(conv3(m0,tid,w1));
    s2s[tid]=sigf(conv3(mH,tid,w2));
    s3s[tid]=sigf(conv3(mL,tid,w3));
  }
  __syncthreads();
  if(tid<DD){ y4[tid]=s2s[tid]*ws[W_RM4+tid]; y5[tid]=s3s[tid]*ws[W_RM5+tid]; }
  __syncthreads();
  if(tid<DD){
    s4s[tid]=sigf(conv3(y4,tid,w4));
    s5s[tid]=sigf(conv3(y5,tid,w5));
    ws[W_S1+tid]=s1s[tid];
  }
  __syncthreads();
  for(int e=tid;e<DD*NC;e+=256){
    int d=e/NC;
    ws[W_H+e]=s4s[d]*s2s[d]*ws[W_RAWMH+e];
    ws[W_L+e]=s5s[d]*s3s[d]*ws[W_RAWML+e];
  }
  __syncthreads();
  if(tid<DD){
    float s=0.f;
    for(int j=0;j<NC;j++) s+=ws[W_H+tid*NC+j];
    ws[W_HBAR+tid]=s/(float)NC;
  }
  __syncthreads();
  for(int e=tid;e<2400;e+=256){
    int j=e/48, d=e-48*j;
    unsigned short hv=0, lv=0;
    if(d<DD){ hv=f2bf(ws[W_H+d*NC+j]); lv=f2bf(ws[W_L+d*NC+j]); }
    ((unsigned short*)(ws+W_HBF))[e]=hv;
    ((unsigned short*)(ws+W_LBF))[e]=lv;
  }
}

// AWt[i][144] = { a0[48] | dif[48] | mul[48] }
__global__ void k_aw(const float* __restrict__ z0, float* __restrict__ ws){
  int e=blockIdx.x*256+threadIdx.x;
  if(e>=LL0*48) return;
  int i=e/48, d=e-48*i;
  float a=0.f, df=0.f, ml=0.f;
  if(d<DD){
    a = ws[W_S1+d]*z0[i*DD+d];
    float s=0.f;
    #pragma unroll 10
    for(int j=0;j<NC;j++) s+=fabsf(a-ws[W_H+d*NC+j]);
    df = s*(1.0f/(float)NC);
    ml = a*ws[W_HBAR+d];
  }
  ws[W_AWT + i*144 + d]      = a;
  ws[W_AWT + i*144 + 48 + d] = df;
  ws[W_AWT + i*144 + 96 + d] = ml;
}

// stage bf16 h/l tables into LDS via uint4
__device__ __forceinline__ void stage_tables(unsigned short* hT, unsigned short* lT,
                                             const float* __restrict__ ws, int tid){
  for(int e=tid;e<300;e+=256){
    ((u32x4*)hT)[e]=((const u32x4*)(ws+W_HBF))[e];
    ((u32x4*)lT)[e]=((const u32x4*)(ws+W_LBF))[e];
  }
}

// build X tile (bf16, interleaved c=2d+p)
__device__ __forceinline__ void build_X(unsigned short* Xl, const float* aw,
                                        const unsigned short* hT, const unsigned short* lT,
                                        int n0, int i0, int tid){
  int ibase=i0*100, ib1=ibase+100;
  for(int e=tid;e<NT*12;e+=256){
    int n=e/12, g=e-12*n, d4=g*4;
    int ncol=n0+n;
    int ii=(ncol>=ib1)?1:0;
    int j=ncol-ibase-ii*100;
    const float* ar=aw+ii*144;
    float x10,x11,x12,x13, x20,x21,x22,x23;
    if(j<NC){
      float4 a=*(const float4*)(ar+d4);
      ushort4 hb=*(const ushort4*)(hT+j*48+d4);
      float h0=bf2f(hb.x),h1=bf2f(hb.y),h2=bf2f(hb.z),h3=bf2f(hb.w);
      x10=fabsf(a.x-h0); x20=a.x*h0;
      x11=fabsf(a.y-h1); x21=a.y*h1;
      x12=fabsf(a.z-h2); x22=a.z*h2;
      x13=fabsf(a.w-h3); x23=a.w*h3;
    }else{
      float4 df=*(const float4*)(ar+48+d4);
      float4 ml=*(const float4*)(ar+96+d4);
      ushort4 lb=*(const ushort4*)(lT+(j-NC)*48+d4);
      float l0=bf2f(lb.x),l1=bf2f(lb.y),l2=bf2f(lb.z),l3=bf2f(lb.w);
      x10=fabsf(df.x-l0); x20=fabsf(ml.x-l0);
      x11=fabsf(df.y-l1); x21=fabsf(ml.y-l1);
      x12=fabsf(df.z-l2); x22=fabsf(ml.z-l2);
      x13=fabsf(df.w-l3); x23=fabsf(ml.w-l3);
    }
    u32x4 pv;
    pv.x=pk2bf(x10,x20); pv.y=pk2bf(x11,x21); pv.z=pk2bf(x12,x22); pv.w=pk2bf(x13,x23);
    *(u32x4*)(Xl + n*XROW + 8*g) = pv;
  }
}

// pass A (persistent): build + gemm1 + BN1 stats; aw double-buffer prefetch
__global__ __launch_bounds__(256,3) void k_gemmA(const float* __restrict__ ws,
                                                 const float* __restrict__ conv_b,
                                                 float* __restrict__ bnsum){
  __shared__ unsigned short hT[2400], lT[2400];
  __shared__ float aw[2][288];
  __shared__ unsigned short Xl[NT*XROW];
  __shared__ float bnred[512];
  int tid=threadIdx.x;
  int l=tid&63, w=tid>>6, lr=l&15, hi=l>>4, mb=w*64;
  stage_tables(hT,lT,ws,tid);
  const unsigned short* W1p=(const unsigned short*)(ws+W_W1P);
  bf8 w1f[4][3];
  #pragma unroll
  for(int tm=0;tm<4;tm++)
    #pragma unroll
    for(int ks=0;ks<3;ks++)
      w1f[tm][ks]=*(const bf8*)(W1p + (mb+tm*16+lr)*96 + ks*32 + hi*8);
  float bb[4][4];
  #pragma unroll
  for(int tm=0;tm<4;tm++)
    #pragma unroll
    for(int r=0;r<4;r++) bb[tm][r]=conv_b[mb+tm*16+hi*4+r];
  float s[4][4], q[4][4];
  #pragma unroll
  for(int tm=0;tm<4;tm++)
    #pragma unroll
    for(int r=0;r<4;r++){ s[tm][r]=0.f; q[tm][r]=0.f; }
  if(tid<72) ((float4*)aw[0])[tid]=*(((const float4*)(ws+W_AWT+((blockIdx.x*NT)/100)*144))+tid);
  __syncthreads();

  int pb=0;
  for(int t=blockIdx.x;t<TILES;t+=GRIDP){
    int n0=t*NT, i0=n0/100, nxt=t+GRIDP;
    build_X(Xl,aw[pb],hT,lT,n0,i0,tid);
    __syncthreads();                             // X ready; aw[pb] consumed
    if(tid<72 && nxt<TILES)
      ((float4*)aw[pb^1])[tid]=*(((const float4*)(ws+W_AWT+((nxt*NT)/100)*144))+tid);
    f32x4 acc[4][4];
    #pragma unroll
    for(int tm=0;tm<4;tm++)
      #pragma unroll
      for(int tn=0;tn<4;tn++) acc[tm][tn]=(f32x4){0.f,0.f,0.f,0.f};
    #pragma unroll
    for(int ks=0;ks<3;ks++){
      bf8 b[4];
      #pragma unroll
      for(int tn=0;tn<4;tn++)
        b[tn]=*(const bf8*)(Xl + (tn*16+lr)*XROW + ks*32 + hi*8);
      #pragma unroll
      for(int tm=0;tm<4;tm++)
        #pragma unroll
        for(int tn=0;tn<4;tn++)
          acc[tm][tn]=__builtin_amdgcn_mfma_f32_16x16x32_bf16(w1f[tm][ks],b[tn],acc[tm][tn],0,0,0);
    }
    #pragma unroll
    for(int tm=0;tm<4;tm++)
      #pragma unroll
      for(int tn=0;tn<4;tn++)
        #pragma unroll
        for(int r=0;r<4;r++){
          float vv=fmaxf(acc[tm][tn][r]+bb[tm][r],0.f);
          s[tm][r]+=vv; q[tm][r]+=vv*vv;
        }
    __syncthreads();                             // Xl reads done before next build
    pb^=1;
  }
  #pragma unroll
  for(int m=1;m<16;m<<=1)
    #pragma unroll
    for(int tm=0;tm<4;tm++)
      #pragma unroll
      for(int r=0;r<4;r++){
        s[tm][r]+=__shfl_xor(s[tm][r],m);
        q[tm][r]+=__shfl_xor(q[tm][r],m);
      }
  if(lr==0){
    #pragma unroll
    for(int tm=0;tm<4;tm++)
      #pragma unroll
      for(int r=0;r<4;r++){
        int o=mb+tm*16+hi*4+r;
        bnred[o]=s[tm][r]; bnred[256+o]=q[tm][r];
      }
  }
  __syncthreads();
  for(int e=tid;e<512;e+=256) atomicAdd(&bnsum[e],bnred[e]);
}

__global__ void k_bnparams(float* ws, const float* g, const float* b,
                           int nch, int sumoff, int scoff){
  int o=threadIdx.x;
  if(o<nch){
    float mu =ws[sumoff+o]    *(1.0f/(float)NPOS);
    float ex2=ws[sumoff+nch+o]*(1.0f/(float)NPOS);
    float var=ex2-mu*mu; if(var<0.f) var=0.f;
    float sc=g[o]*rsqrtf(var+EPSV);
    ws[scoff+o]=sc;
    ws[scoff+nch+o]=b[o]-mu*sc;
  }
}

// pass B (persistent): gemm1+pack+gemm2; c2 bf16 pairs stored NT into out's EVEN rows
__global__ __launch_bounds__(256,3) void k_gemmB(const float* __restrict__ ws,
      const float* __restrict__ conv_b, float* __restrict__ out,
      float* __restrict__ bn2sum){
  __shared__ unsigned short hT[2400], lT[2400];   // 9600 B
  __shared__ float aw[2][288];                    // 2304 B
  __shared__ unsigned short BUF[NT*C1ROW];        // 34304 B: Xl / C1s / C2s union
  __shared__ float bnred[256];                    // 1024 B
  int tid=threadIdx.x;
  int l=tid&63, w=tid>>6, lr=l&15, hi=l>>4, mb=w*64, mb2=w*32;
  stage_tables(hT,lT,ws,tid);
  const unsigned short* W1p =(const unsigned short*)(ws+W_W1P);
  const unsigned short* W2bf=(const unsigned short*)(ws+W_W2BF);
  const float* bias2=ws+W_BIAS2;
  unsigned* outu=(unsigned*)out;
  bf8 w1f[4][3];
  #pragma unroll
  for(int tm=0;tm<4;tm++)
    #pragma unroll
    for(int ks=0;ks<3;ks++)
      w1f[tm][ks]=*(const bf8*)(W1p + (mb+tm*16+lr)*96 + ks*32 + hi*8);
  bf8 w2f[2][8];
  #pragma unroll
  for(int tm2=0;tm2<2;tm2++)
    #pragma unroll
    for(int ks=0;ks<8;ks++)
      w2f[tm2][ks]=*(const bf8*)(W2bf + (mb2+tm2*16+lr)*HC + ks*32 + hi*8);
  float bb[4][4];
  #pragma unroll
  for(int tm=0;tm<4;tm++)
    #pragma unroll
    for(int r=0;r<4;r++) bb[tm][r]=conv_b[mb+tm*16+hi*4+r];
  float bb2[2][4];
  #pragma unroll
  for(int tm2=0;tm2<2;tm2++)
    #pragma unroll
    for(int r=0;r<4;r++) bb2[tm2][r]=bias2[mb2+tm2*16+hi*4+r];
  float s2[2][4], q2[2][4];
  #pragma unroll
  for(int tm2=0;tm2<2;tm2++)
    #pragma unroll
    for(int r=0;r<4;r++){ s2[tm2][r]=0.f; q2[tm2][r]=0.f; }
  if(tid<72) ((float4*)aw[0])[tid]=*(((const float4*)(ws+W_AWT+((blockIdx.x*NT)/100)*144))+tid);
  __syncthreads();

  int pb=0;
  for(int t=blockIdx.x;t<TILES;t+=GRIDP){
    int n0=t*NT, i0=n0/100, nxt=t+GRIDP;
    build_X(BUF,aw[pb],hT,lT,n0,i0,tid);       // BUF as Xl
    __syncthreads();                           // B1: X ready; aw[pb] consumed
    if(tid<72 && nxt<TILES)
      ((float4*)aw[pb^1])[tid]=*(((const float4*)(ws+W_AWT+((nxt*NT)/100)*144))+tid);
    f32x4 acc[4][4];
    #pragma unroll
    for(int tm=0;tm<4;tm++)
      #pragma unroll
      for(int tn=0;tn<4;tn++) acc[tm][tn]=(f32x4){0.f,0.f,0.f,0.f};
    #pragma unroll
    for(int ks=0;ks<3;ks++){
      bf8 b[4];
      #pragma unroll
      for(int tn=0;tn<4;tn++)
        b[tn]=*(const bf8*)(BUF + (tn*16+lr)*XROW + ks*32 + hi*8);
      #pragma unroll
      for(int tm=0;tm<4;tm++)
        #pragma unroll
        for(int tn=0;tn<4;tn++)
          acc[tm][tn]=__builtin_amdgcn_mfma_f32_16x16x32_bf16(w1f[tm][ks],b[tn],acc[tm][tn],0,0,0);
    }
    __syncthreads();                           // B2: Xl reads done
    #pragma unroll
    for(int tm=0;tm<4;tm++)
      #pragma unroll
      for(int tn=0;tn<4;tn++){
        int n=tn*16+lr, ob=mb+tm*16+hi*4;
        float v0=fmaxf(acc[tm][tn][0]+bb[tm][0],0.f);
        float v1=fmaxf(acc[tm][tn][1]+bb[tm][1],0.f);
        float v2=fmaxf(acc[tm][tn][2]+bb[tm][2],0.f);
        float v3=fmaxf(acc[tm][tn][3]+bb[tm][3],0.f);
        uint2 pv; pv.x=pk2bf(v0,v1); pv.y=pk2bf(v2,v3);
        *(uint2*)&BUF[n*C1ROW+ob]=pv;          // BUF as C1s
      }
    __syncthreads();                           // B3: C1 ready
    f32x4 acc2[2][4];
    #pragma unroll
    for(int tm2=0;tm2<2;tm2++)
      #pragma unroll
      for(int tn=0;tn<4;tn++) acc2[tm2][tn]=(f32x4){0.f,0.f,0.f,0.f};
    #pragma unroll
    for(int ks=0;ks<8;ks++){
      bf8 b2[4];
      #pragma unroll
      for(int tn=0;tn<4;tn++)
        b2[tn]=*(const bf8*)(BUF + (tn*16+lr)*C1ROW + ks*32 + hi*8);
      #pragma unroll
      for(int tm2=0;tm2<2;tm2++)
        #pragma unroll
        for(int tn=0;tn<4;tn++)
          acc2[tm2][tn]=__builtin_amdgcn_mfma_f32_16x16x32_bf16(w2f[tm2][ks],b2[tn],acc2[tm2][tn],0,0,0);
    }
    __syncthreads();                           // B4: C1 reads done
    // epilogue: relu + stats + stage C2 pairs into BUF (u32[64][C2PAD])
    unsigned* C2s=(unsigned*)BUF;
    #pragma unroll
    for(int tm2=0;tm2<2;tm2++)
      #pragma unroll
      for(int tn=0;tn<4;tn++){
        float v0=fmaxf(acc2[tm2][tn][0]+bb2[tm2][0],0.f);
        float v1=fmaxf(acc2[tm2][tn][1]+bb2[tm2][1],0.f);
        float v2=fmaxf(acc2[tm2][tn][2]+bb2[tm2][2],0.f);
        float v3=fmaxf(acc2[tm2][tn][3]+bb2[tm2][3],0.f);
        s2[tm2][0]+=v0; q2[tm2][0]+=v0*v0;
        s2[tm2][1]+=v1; q2[tm2][1]+=v1*v1;
        s2[tm2][2]+=v2; q2[tm2][2]+=v2*v2;
        s2[tm2][3]+=v3; q2[tm2][3]+=v3*v3;
        int n=tn*16+lr;
        int q0=(mb2+tm2*16+hi*4)>>1;
        C2s[q0*C2PAD+n]    =pk2bf(v0,v1);
        C2s[(q0+1)*C2PAD+n]=pk2bf(v2,v3);
      }
    __syncthreads();                           // B5: C2s ready
    // nontemporal full-line stores into out's EVEN rows (u32 pair per (2q,2q+1))
    #pragma unroll
    for(int p16=0;p16<4;p16++){
      int row=p16*16+(tid>>4), chunk=tid&15;
      u32x4 v=*(const u32x4*)&C2s[row*C2PAD+chunk*4];
      __builtin_nontemporal_store(v,
        (u32x4*)(outu + (size_t)(2*row)*NPOS + n0 + chunk*4));
    }
    __syncthreads();                           // B6: C2s drained before next build
    pb^=1;
  }
  #pragma unroll
  for(int m=1;m<16;m<<=1)
    #pragma unroll
    for(int tm2=0;tm2<2;tm2++)
      #pragma unroll
      for(int r=0;r<4;r++){
        s2[tm2][r]+=__shfl_xor(s2[tm2][r],m);
        q2[tm2][r]+=__shfl_xor(q2[tm2][r],m);
      }
  if(lr==0){
    #pragma unroll
    for(int tm2=0;tm2<2;tm2++)
      #pragma unroll
      for(int r=0;r<4;r++){
        int o=mb2+tm2*16+hi*4+r;
        bnred[o]=s2[tm2][r]; bnred[128+o]=q2[tm2][r];
      }
  }
  __syncthreads();
  if(tid<256) atomicAdd(&bn2sum[tid],bnred[tid]);
}

// pass C: read bf16 pair u32 from even row (same address), expand+affine,
// write f32 to even row (in place) + odd row. Same-thread read-before-write.
__global__ void k_passC(float* __restrict__ out, const float* __restrict__ ws){
  const int NQ4=NPOS/4;
  int idx=blockIdx.x*256+threadIdx.x;
  int stride=gridDim.x*256;
  unsigned* outu=(unsigned*)out;
  for(int e=idx;e<64*NQ4;e+=stride){
    int qq=e/NQ4, nb=(e-qq*NQ4)*4;
    size_t base=(size_t)(2*qq)*NPOS + nb;
    u32x4 v=__builtin_nontemporal_load((const u32x4*)(outu+base));
    float sc0=ws[W_SC2+2*qq],   sh0=ws[W_SC2+H2C+2*qq];
    float sc1=ws[W_SC2+2*qq+1], sh1=ws[W_SC2+H2C+2*qq+1];
    f32x4 o0,o1;
    o0.x=bf2f((unsigned short)(v.x&0xffff))*sc0+sh0;
    o1.x=bf2f((unsigned short)(v.x>>16))  *sc1+sh1;
    o0.y=bf2f((unsigned short)(v.y&0xffff))*sc0+sh0;
    o1.y=bf2f((unsigned short)(v.y>>16))  *sc1+sh1;
    o0.z=bf2f((unsigned short)(v.z&0xffff))*sc0+sh0;
    o1.z=bf2f((unsigned short)(v.z>>16))  *sc1+sh1;
    o0.w=bf2f((unsigned short)(v.w&0xffff))*sc0+sh0;
    o1.w=bf2f((unsigned short)(v.w>>16))  *sc1+sh1;
    __builtin_nontemporal_store(o0,(f32x4*)(out+base));
    __builtin_nontemporal_store(o1,(f32x4*)(out+base+NPOS));
  }
}

extern "C" void kernel_launch(void* const* d_in, const int* in_sizes, int n_in,
                              void* d_out, int out_size, void* d_ws, size_t ws_size,
                              hipStream_t stream){
  const float* z0     =(const float*)d_in[0];
  const float* z1     =(const float*)d_in[1];
  const float* we1    =(const float*)d_in[2];
  const float* we2    =(const float*)d_in[3];
  const float* we3    =(const float*)d_in[4];
  const float* we4    =(const float*)d_in[5];
  const float* we5    =(const float*)d_in[6];
  const float* conv_w =(const float*)d_in[7];
  const float* conv_b =(const float*)d_in[8];
  const float* bn_g   =(const float*)d_in[9];
  const float* bn_b   =(const float*)d_in[10];
  const float* conv2_w=(const float*)d_in[11];
  const float* conv2_b=(const float*)d_in[12];
  const float* bn2_g  =(const float*)d_in[13];
  const float* bn2_b  =(const float*)d_in[14];
  const int* cdrH=(const int*)d_in[15];
  const int* cdrL=(const int*)d_in[16];
  const int* notH=(const int*)d_in[17];
  const int* notL=(const int*)d_in[18];
  int nCdrH=in_sizes[15], nCdrL=in_sizes[16], nNotH=in_sizes[17], nNotL=in_sizes[18];
  float* ws=(float*)d_ws;
  float* out=(float*)d_out;

  hipLaunchKernelGGL(k_prep,     dim3(96),   dim3(256),0,stream, conv_w,ws);
  hipLaunchKernelGGL(k_means,    dim3(DD),   dim3(256),0,stream, z0,z1,cdrH,notH,cdrL,notL,
                     nCdrH,nNotH,nCdrL,nNotL,ws);
  hipLaunchKernelGGL(k_scales,   dim3(1),    dim3(256),0,stream, we1,we2,we3,we4,we5,ws);
  hipLaunchKernelGGL(k_aw,       dim3((LL0*48+255)/256), dim3(256),0,stream, z0,ws);
  hipLaunchKernelGGL(k_gemmA,    dim3(GRIDP),dim3(256),0,stream, ws,conv_b, ws+W_BN1S);
  hipLaunchKernelGGL(k_bnparams, dim3(1),    dim3(256),0,stream, ws,bn_g,bn_b, HC, W_BN1S, W_SC1);
  hipLaunchKernelGGL(k_prep2,    dim3(H2C),  dim3(256),0,stream, conv2_w,conv2_b,ws);
  hipLaunchKernelGGL(k_gemmB,    dim3(GRIDP),dim3(256),0,stream, ws,conv_b, out, ws+W_BN2S);
  hipLaunchKernelGGL(k_bnparams, dim3(1),    dim3(256),0,stream, ws,bn2_g,bn2_b, H2C, W_BN2S, W_SC2);
  hipLaunchKernelGGL(k_passC,    dim3(2048), dim3(256),0,stream, out, ws);
}

// Round 11
// 233.354 us; speedup vs baseline: 1.3778x; 1.3778x over previous
//
#include <hip/hip_runtime.h>
#include <math.h>

#define DD   46
#define LL0  4000
#define LL1  600
#define CATV 250
#define NC   50
#define NJ   100
#define HC   256
#define H2C  128
#define NPOS (LL0*NJ)
#define EPSV 1e-5f
#define NT   64
#define XROW 104
#define C1ROW 268
#define C2PAD 68
#define TILES (NPOS/NT)   // 6250
#define GRIDP 512

// ---- workspace float offsets ----
#define W_MEAN0   0
#define W_MEANH   64
#define W_MEANL   128
#define W_RM4     192
#define W_RM5     256
#define W_S1      320
#define W_HBAR    384
#define W_RAWMH   448
#define W_RAWML   2752
#define W_H       5056
#define W_L       7360
#define W_BN1S    9664            // 256 sum + 256 sumsq
#define W_SC1     10176           // 256 scale + 256 shift
#define W_BN2S    10688           // 128+128
#define W_SC2     10944           // 128+128 -> 11200
#define W_HBF     11200           // 2400 ushort [j][48]
#define W_LBF     12400           // 2400 ushort
#define W_AWT     13632           // [4001][144] f32
#define W_W1P     589776          // 256*96 bf16
#define W_W2BF    602064          // 128*256 bf16
#define W_BIAS2   618448          // 128 floats

typedef __attribute__((ext_vector_type(8))) short bf8;
typedef __attribute__((ext_vector_type(4))) float f32x4;
typedef __attribute__((ext_vector_type(4))) unsigned u32x4;

__device__ __forceinline__ float sigf(float x){ return 1.0f/(1.0f+__expf(-x)); }

__device__ __forceinline__ unsigned short f2bf(float f){
  unsigned u = __float_as_uint(f);
  return (unsigned short)((u + 0x7FFFu + ((u>>16)&1u)) >> 16);
}
__device__ __forceinline__ unsigned pk2bf(float a, float b){
  return ((unsigned)f2bf(b)<<16) | (unsigned)f2bf(a);
}
__device__ __forceinline__ float bf2f(unsigned short h){
  return __uint_as_float(((unsigned)h)<<16);
}

__device__ float blockReduceSum(float v, float* sm){
  int tid=threadIdx.x;
  sm[tid]=v; __syncthreads();
  for(int s=128;s>0;s>>=1){ if(tid<s) sm[tid]+=sm[tid+s]; __syncthreads(); }
  float r=sm[0]; __syncthreads();
  return r;
}

// W1 -> bf16 permuted [o][2d+p]; block 0 zeros BN stat region
__global__ void k_prep(const float* __restrict__ conv_w, float* __restrict__ ws){
  int t=blockIdx.x*256+threadIdx.x;
  if(blockIdx.x==0){ for(int e=threadIdx.x;e<1536;e+=256) ws[W_BN1S+e]=0.f; }
  if(t<HC*96){
    int o=t/96, c=t-o*96;
    unsigned short v=0;
    if(c<92){ int d=c>>1, p=c&1; v=f2bf(conv_w[o*92 + (p? 46+d : d)]); }
    ((unsigned short*)(ws+W_W1P))[t]=v;
  }
}

// W2' = W2*sc1 (bf16), bias2' = b2 + sum_k W2[o2,k]*sh1[k]
__global__ void k_prep2(const float* __restrict__ conv2_w, const float* __restrict__ conv2_b,
                        float* __restrict__ ws){
  __shared__ float sm[256];
  int o2=blockIdx.x, t=threadIdx.x;
  float wv=conv2_w[o2*HC+t];
  float sc=ws[W_SC1+t], sh=ws[W_SC1+HC+t];
  ((unsigned short*)(ws+W_W2BF))[o2*HC+t]=f2bf(wv*sc);
  float r=blockReduceSum(wv*sh,sm);
  if(t==0) ws[W_BIAS2+o2]=conv2_b[o2]+r;
}

// fused: per-channel means + raw pair-difference means, block d
__global__ void k_means(const float* __restrict__ z0, const float* __restrict__ z1,
                        const int* cdrH, const int* notH,
                        const int* cdrL, const int* notL,
                        int nCdrH,int nNotH,int nCdrL,int nNotL, float* ws){
  __shared__ float v[LL1];
  __shared__ float sm[256];
  int d=blockIdx.x, tid=threadIdx.x;
  float s0=0.f; for(int i=tid;i<LL0;i+=256) s0+=z0[i*DD+d];
  for(int k=tid;k<LL1;k+=256) v[k]=z1[k*DD+d];
  float r0=blockReduceSum(s0,sm);
  __syncthreads();
  float sH=0.f; for(int k=tid;k<CATV;k+=256) sH+=v[k];
  float sL=0.f; for(int k=CATV+tid;k<LL1;k+=256) sL+=v[k];
  float rH=blockReduceSum(sH,sm);
  float rL=blockReduceSum(sL,sm);
  float partH=0.f, partL=0.f;
  for(int i=tid;i<nCdrH;i+=256){
    float c=v[cdrH[i]]; float s=0.f;
    for(int j=0;j<nNotH;j++) s+=fabsf(c-v[notH[j]]);
    s/= (float)nNotH;
    ws[W_RAWMH+d*NC+i]=s; partH+=s;
  }
  for(int i=tid;i<nCdrL;i+=256){
    float c=v[CATV+cdrL[i]]; float s=0.f;
    for(int j=0;j<nNotL;j++) s+=fabsf(c-v[CATV+notL[j]]);
    s/= (float)nNotL;
    ws[W_RAWML+d*NC+i]=s; partL+=s;
  }
  float pH=blockReduceSum(partH,sm);
  float pL=blockReduceSum(partL,sm);
  if(tid==0){
    ws[W_MEAN0+d]=r0/(float)LL0;
    ws[W_MEANH+d]=rH/(float)CATV;
    ws[W_MEANL+d]=rL/(float)(LL1-CATV);
    ws[W_RM4+d]=pH/(float)nCdrH;
    ws[W_RM5+d]=pL/(float)nCdrL;
  }
}

__device__ __forceinline__ float conv3(const float* a, int d, const float* w){
  float acc = w[1]*a[d];
  if(d>0)    acc += w[0]*a[d-1];
  if(d<DD-1) acc += w[2]*a[d+1];
  return acc;
}

// scales + final h, l, hbar + bf16 table copies [j][48]
__global__ void k_scales(const float* w1,const float* w2,const float* w3,
                         const float* w4,const float* w5, float* ws){
  __shared__ float m0[DD], mH[DD], mL[DD];
  __shared__ float s1s[DD],s2s[DD],s3s[DD],s4s[DD],s5s[DD],y4[DD],y5[DD];
  int tid=threadIdx.x;
  if(tid<DD){ m0[tid]=ws[W_MEAN0+tid]; mH[tid]=ws[W_MEANH+tid]; mL[tid]=ws[W_MEANL+tid]; }
  __syncthreads();
  if(tid<DD){
    s1s[tid]=sigf(conv3(m0,tid,w1));
    s2s[tid]=sigf(conv3(mH,tid,w2));
    s3s[tid]=sigf(conv3(mL,tid,w3));
  }
  __syncthreads();
  if(tid<DD){ y4[tid]=s2s[tid]*ws[W_RM4+tid]; y5[tid]=s3s[tid]*ws[W_RM5+tid]; }
  __syncthreads();
  if(tid<DD){
    s4s[tid]=sigf(conv3(y4,tid,w4));
    s5s[tid]=sigf(conv3(y5,tid,w5));
    ws[W_S1+tid]=s1s[tid];
  }
  __syncthreads();
  for(int e=tid;e<DD*NC;e+=256){
    int d=e/NC;
    ws[W_H+e]=s4s[d]*s2s[d]*ws[W_RAWMH+e];
    ws[W_L+e]=s5s[d]*s3s[d]*ws[W_RAWML+e];
  }
  __syncthreads();
  if(tid<DD){
    float s=0.f;
    for(int j=0;j<NC;j++) s+=ws[W_H+tid*NC+j];
    ws[W_HBAR+tid]=s/(float)NC;
  }
  __syncthreads();
  for(int e=tid;e<2400;e+=256){
    int j=e/48, d=e-48*j;
    unsigned short hv=0, lv=0;
    if(d<DD){ hv=f2bf(ws[W_H+d*NC+j]); lv=f2bf(ws[W_L+d*NC+j]); }
    ((unsigned short*)(ws+W_HBF))[e]=hv;
    ((unsigned short*)(ws+W_LBF))[e]=lv;
  }
}

// AWt[i][144] = { a0[48] | dif[48] | mul[48] }
__global__ void k_aw(const float* __restrict__ z0, float* __restrict__ ws){
  int e=blockIdx.x*256+threadIdx.x;
  if(e>=LL0*48) return;
  int i=e/48, d=e-48*i;
  float a=0.f, df=0.f, ml=0.f;
  if(d<DD){
    a = ws[W_S1+d]*z0[i*DD+d];
    float s=0.f;
    #pragma unroll 10
    for(int j=0;j<NC;j++) s+=fabsf(a-ws[W_H+d*NC+j]);
    df = s*(1.0f/(float)NC);
    ml = a*ws[W_HBAR+d];
  }
  ws[W_AWT + i*144 + d]      = a;
  ws[W_AWT + i*144 + 48 + d] = df;
  ws[W_AWT + i*144 + 96 + d] = ml;
}

// stage bf16 h/l tables into LDS via 16B vectors
__device__ __forceinline__ void stage_tables(unsigned short* hT, unsigned short* lT,
                                             const float* __restrict__ ws, int tid){
  for(int e=tid;e<300;e+=256){
    ((u32x4*)hT)[e]=((const u32x4*)(ws+W_HBF))[e];
    ((u32x4*)lT)[e]=((const u32x4*)(ws+W_LBF))[e];
  }
}

// build X tile (bf16, interleaved c=2d+p)
__device__ __forceinline__ void build_X(unsigned short* Xl, const float* aw,
                                        const unsigned short* hT, const unsigned short* lT,
                                        int n0, int i0, int tid){
  int ibase=i0*100, ib1=ibase+100;
  for(int e=tid;e<NT*12;e+=256){
    int n=e/12, g=e-12*n, d4=g*4;
    int ncol=n0+n;
    int ii=(ncol>=ib1)?1:0;
    int j=ncol-ibase-ii*100;
    const float* ar=aw+ii*144;
    float x10,x11,x12,x13, x20,x21,x22,x23;
    if(j<NC){
      float4 a=*(const float4*)(ar+d4);
      ushort4 hb=*(const ushort4*)(hT+j*48+d4);
      float h0=bf2f(hb.x),h1=bf2f(hb.y),h2=bf2f(hb.z),h3=bf2f(hb.w);
      x10=fabsf(a.x-h0); x20=a.x*h0;
      x11=fabsf(a.y-h1); x21=a.y*h1;
      x12=fabsf(a.z-h2); x22=a.z*h2;
      x13=fabsf(a.w-h3); x23=a.w*h3;
    }else{
      float4 df=*(const float4*)(ar+48+d4);
      float4 ml=*(const float4*)(ar+96+d4);
      ushort4 lb=*(const ushort4*)(lT+(j-NC)*48+d4);
      float l0=bf2f(lb.x),l1=bf2f(lb.y),l2=bf2f(lb.z),l3=bf2f(lb.w);
      x10=fabsf(df.x-l0); x20=fabsf(ml.x-l0);
      x11=fabsf(df.y-l1); x21=fabsf(ml.y-l1);
      x12=fabsf(df.z-l2); x22=fabsf(ml.z-l2);
      x13=fabsf(df.w-l3); x23=fabsf(ml.w-l3);
    }
    u32x4 pv;
    pv.x=pk2bf(x10,x20); pv.y=pk2bf(x11,x21); pv.z=pk2bf(x12,x22); pv.w=pk2bf(x13,x23);
    *(u32x4*)(Xl + n*XROW + 8*g) = pv;
  }
}

// pass A (persistent): build + gemm1 + BN1 stats; weights register-resident
// (256,2): reg cap 256 -> w1f stays live across the tile loop
__global__ __launch_bounds__(256,2) void k_gemmA(const float* __restrict__ ws,
                                                 const float* __restrict__ conv_b,
                                                 float* __restrict__ bnsum){
  __shared__ unsigned short hT[2400], lT[2400];
  __shared__ float aw[2][288];
  __shared__ unsigned short Xl[NT*XROW];
  __shared__ float bnred[512];
  int tid=threadIdx.x;
  int l=tid&63, w=tid>>6, lr=l&15, hi=l>>4, mb=w*64;
  stage_tables(hT,lT,ws,tid);
  const unsigned short* W1p=(const unsigned short*)(ws+W_W1P);
  bf8 w1f[4][3];
  #pragma unroll
  for(int tm=0;tm<4;tm++)
    #pragma unroll
    for(int ks=0;ks<3;ks++)
      w1f[tm][ks]=*(const bf8*)(W1p + (mb+tm*16+lr)*96 + ks*32 + hi*8);
  float bb[4][4];
  #pragma unroll
  for(int tm=0;tm<4;tm++)
    #pragma unroll
    for(int r=0;r<4;r++) bb[tm][r]=conv_b[mb+tm*16+hi*4+r];
  float s[4][4], q[4][4];
  #pragma unroll
  for(int tm=0;tm<4;tm++)
    #pragma unroll
    for(int r=0;r<4;r++){ s[tm][r]=0.f; q[tm][r]=0.f; }
  if(tid<72) ((float4*)aw[0])[tid]=*(((const float4*)(ws+W_AWT+((blockIdx.x*NT)/100)*144))+tid);
  __syncthreads();

  int pb=0;
  for(int t=blockIdx.x;t<TILES;t+=GRIDP){
    int n0=t*NT, i0=n0/100, nxt=t+GRIDP;
    build_X(Xl,aw[pb],hT,lT,n0,i0,tid);
    __syncthreads();                             // X ready; aw[pb] consumed
    if(tid<72 && nxt<TILES)
      ((float4*)aw[pb^1])[tid]=*(((const float4*)(ws+W_AWT+((nxt*NT)/100)*144))+tid);
    f32x4 acc[4][4];
    #pragma unroll
    for(int tm=0;tm<4;tm++)
      #pragma unroll
      for(int tn=0;tn<4;tn++) acc[tm][tn]=(f32x4){0.f,0.f,0.f,0.f};
    #pragma unroll
    for(int ks=0;ks<3;ks++){
      bf8 b[4];
      #pragma unroll
      for(int tn=0;tn<4;tn++)
        b[tn]=*(const bf8*)(Xl + (tn*16+lr)*XROW + ks*32 + hi*8);
      #pragma unroll
      for(int tm=0;tm<4;tm++)
        #pragma unroll
        for(int tn=0;tn<4;tn++)
          acc[tm][tn]=__builtin_amdgcn_mfma_f32_16x16x32_bf16(w1f[tm][ks],b[tn],acc[tm][tn],0,0,0);
    }
    #pragma unroll
    for(int tm=0;tm<4;tm++)
      #pragma unroll
      for(int tn=0;tn<4;tn++)
        #pragma unroll
        for(int r=0;r<4;r++){
          float vv=fmaxf(acc[tm][tn][r]+bb[tm][r],0.f);
          s[tm][r]+=vv; q[tm][r]+=vv*vv;
        }
    __syncthreads();                             // Xl reads done before next build
    pb^=1;
  }
  #pragma unroll
  for(int m=1;m<16;m<<=1)
    #pragma unroll
    for(int tm=0;tm<4;tm++)
      #pragma unroll
      for(int r=0;r<4;r++){
        s[tm][r]+=__shfl_xor(s[tm][r],m);
        q[tm][r]+=__shfl_xor(q[tm][r],m);
      }
  if(lr==0){
    #pragma unroll
    for(int tm=0;tm<4;tm++)
      #pragma unroll
      for(int r=0;r<4;r++){
        int o=mb+tm*16+hi*4+r;
        bnred[o]=s[tm][r]; bnred[256+o]=q[tm][r];
      }
  }
  __syncthreads();
  for(int e=tid;e<512;e+=256) atomicAdd(&bnsum[e],bnred[e]);
}

__global__ void k_bnparams(float* ws, const float* g, const float* b,
                           int nch, int sumoff, int scoff){
  int o=threadIdx.x;
  if(o<nch){
    float mu =ws[sumoff+o]    *(1.0f/(float)NPOS);
    float ex2=ws[sumoff+nch+o]*(1.0f/(float)NPOS);
    float var=ex2-mu*mu; if(var<0.f) var=0.f;
    float sc=g[o]*rsqrtf(var+EPSV);
    ws[scoff+o]=sc;
    ws[scoff+nch+o]=b[o]-mu*sc;
  }
}

// pass B (persistent): gemm1+pack+gemm2; weights register-resident via (256,2)
__global__ __launch_bounds__(256,2) void k_gemmB(const float* __restrict__ ws,
      const float* __restrict__ conv_b, float* __restrict__ out,
      float* __restrict__ bn2sum){
  __shared__ unsigned short hT[2400], lT[2400];   // 9600 B
  __shared__ float aw[2][288];                    // 2304 B
  __shared__ unsigned short BUF[NT*C1ROW];        // 34304 B: Xl / C1s / C2s union
  __shared__ float bnred[256];                    // 1024 B
  int tid=threadIdx.x;
  int l=tid&63, w=tid>>6, lr=l&15, hi=l>>4, mb=w*64, mb2=w*32;
  stage_tables(hT,lT,ws,tid);
  const unsigned short* W1p =(const unsigned short*)(ws+W_W1P);
  const unsigned short* W2bf=(const unsigned short*)(ws+W_W2BF);
  const float* bias2=ws+W_BIAS2;
  unsigned* outu=(unsigned*)out;
  bf8 w1f[4][3];
  #pragma unroll
  for(int tm=0;tm<4;tm++)
    #pragma unroll
    for(int ks=0;ks<3;ks++)
      w1f[tm][ks]=*(const bf8*)(W1p + (mb+tm*16+lr)*96 + ks*32 + hi*8);
  bf8 w2f[2][8];
  #pragma unroll
  for(int tm2=0;tm2<2;tm2++)
    #pragma unroll
    for(int ks=0;ks<8;ks++)
      w2f[tm2][ks]=*(const bf8*)(W2bf + (mb2+tm2*16+lr)*HC + ks*32 + hi*8);
  float bb[4][4];
  #pragma unroll
  for(int tm=0;tm<4;tm++)
    #pragma unroll
    for(int r=0;r<4;r++) bb[tm][r]=conv_b[mb+tm*16+hi*4+r];
  float bb2[2][4];
  #pragma unroll
  for(int tm2=0;tm2<2;tm2++)
    #pragma unroll
    for(int r=0;r<4;r++) bb2[tm2][r]=bias2[mb2+tm2*16+hi*4+r];
  float s2[2][4], q2[2][4];
  #pragma unroll
  for(int tm2=0;tm2<2;tm2++)
    #pragma unroll
    for(int r=0;r<4;r++){ s2[tm2][r]=0.f; q2[tm2][r]=0.f; }
  if(tid<72) ((float4*)aw[0])[tid]=*(((const float4*)(ws+W_AWT+((blockIdx.x*NT)/100)*144))+tid);
  __syncthreads();

  int pb=0;
  for(int t=blockIdx.x;t<TILES;t+=GRIDP){
    int n0=t*NT, i0=n0/100, nxt=t+GRIDP;
    build_X(BUF,aw[pb],hT,lT,n0,i0,tid);       // BUF as Xl
    __syncthreads();                           // B1: X ready; aw[pb] consumed
    if(tid<72 && nxt<TILES)
      ((float4*)aw[pb^1])[tid]=*(((const float4*)(ws+W_AWT+((nxt*NT)/100)*144))+tid);
    f32x4 acc[4][4];
    #pragma unroll
    for(int tm=0;tm<4;tm++)
      #pragma unroll
      for(int tn=0;tn<4;tn++) acc[tm][tn]=(f32x4){0.f,0.f,0.f,0.f};
    #pragma unroll
    for(int ks=0;ks<3;ks++){
      bf8 b[4];
      #pragma unroll
      for(int tn=0;tn<4;tn++)
        b[tn]=*(const bf8*)(BUF + (tn*16+lr)*XROW + ks*32 + hi*8);
      #pragma unroll
      for(int tm=0;tm<4;tm++)
        #pragma unroll
        for(int tn=0;tn<4;tn++)
          acc[tm][tn]=__builtin_amdgcn_mfma_f32_16x16x32_bf16(w1f[tm][ks],b[tn],acc[tm][tn],0,0,0);
    }
    __syncthreads();                           // B2: Xl reads done
    #pragma unroll
    for(int tm=0;tm<4;tm++)
      #pragma unroll
      for(int tn=0;tn<4;tn++){
        int n=tn*16+lr, ob=mb+tm*16+hi*4;
        float v0=fmaxf(acc[tm][tn][0]+bb[tm][0],0.f);
        float v1=fmaxf(acc[tm][tn][1]+bb[tm][1],0.f);
        float v2=fmaxf(acc[tm][tn][2]+bb[tm][2],0.f);
        float v3=fmaxf(acc[tm][tn][3]+bb[tm][3],0.f);
        uint2 pv; pv.x=pk2bf(v0,v1); pv.y=pk2bf(v2,v3);
        *(uint2*)&BUF[n*C1ROW+ob]=pv;          // BUF as C1s
      }
    __syncthreads();                           // B3: C1 ready
    f32x4 acc2[2][4];
    #pragma unroll
    for(int tm2=0;tm2<2;tm2++)
      #pragma unroll
      for(int tn=0;tn<4;tn++) acc2[tm2][tn]=(f32x4){0.f,0.f,0.f,0.f};
    #pragma unroll
    for(int ks=0;ks<8;ks++){
      bf8 b2[4];
      #pragma unroll
      for(int tn=0;tn<4;tn++)
        b2[tn]=*(const bf8*)(BUF + (tn*16+lr)*C1ROW + ks*32 + hi*8);
      #pragma unroll
      for(int tm2=0;tm2<2;tm2++)
        #pragma unroll
        for(int tn=0;tn<4;tn++)
          acc2[tm2][tn]=__builtin_amdgcn_mfma_f32_16x16x32_bf16(w2f[tm2][ks],b2[tn],acc2[tm2][tn],0,0,0);
    }
    __syncthreads();                           // B4: C1 reads done
    // epilogue: relu + stats + stage C2 pairs into BUF (u32[64][C2PAD])
    unsigned* C2s=(unsigned*)BUF;
    #pragma unroll
    for(int tm2=0;tm2<2;tm2++)
      #pragma unroll
      for(int tn=0;tn<4;tn++){
        float v0=fmaxf(acc2[tm2][tn][0]+bb2[tm2][0],0.f);
        float v1=fmaxf(acc2[tm2][tn][1]+bb2[tm2][1],0.f);
        float v2=fmaxf(acc2[tm2][tn][2]+bb2[tm2][2],0.f);
        float v3=fmaxf(acc2[tm2][tn][3]+bb2[tm2][3],0.f);
        s2[tm2][0]+=v0; q2[tm2][0]+=v0*v0;
        s2[tm2][1]+=v1; q2[tm2][1]+=v1*v1;
        s2[tm2][2]+=v2; q2[tm2][2]+=v2*v2;
        s2[tm2][3]+=v3; q2[tm2][3]+=v3*v3;
        int n=tn*16+lr;
        int q0=(mb2+tm2*16+hi*4)>>1;
        C2s[q0*C2PAD+n]    =pk2bf(v0,v1);
        C2s[(q0+1)*C2PAD+n]=pk2bf(v2,v3);
      }
    __syncthreads();                           // B5: C2s ready
    // full-line stores into out's EVEN rows (u32 pair per (2q,2q+1))
    #pragma unroll
    for(int p16=0;p16<4;p16++){
      int row=p16*16+(tid>>4), chunk=tid&15;
      u32x4 v=*(const u32x4*)&C2s[row*C2PAD+chunk*4];
      *(u32x4*)(outu + (size_t)(2*row)*NPOS + n0 + chunk*4) = v;
    }
    __syncthreads();                           // B6: C2s drained before next build
    pb^=1;
  }
  #pragma unroll
  for(int m=1;m<16;m<<=1)
    #pragma unroll
    for(int tm2=0;tm2<2;tm2++)
      #pragma unroll
      for(int r=0;r<4;r++){
        s2[tm2][r]+=__shfl_xor(s2[tm2][r],m);
        q2[tm2][r]+=__shfl_xor(q2[tm2][r],m);
      }
  if(lr==0){
    #pragma unroll
    for(int tm2=0;tm2<2;tm2++)
      #pragma unroll
      for(int r=0;r<4;r++){
        int o=mb2+tm2*16+hi*4+r;
        bnred[o]=s2[tm2][r]; bnred[128+o]=q2[tm2][r];
      }
  }
  __syncthreads();
  if(tid<256) atomicAdd(&bn2sum[tid],bnred[tid]);
}

// pass C: read bf16 pair u32 from even row, expand+affine, write f32 even+odd rows
__global__ void k_passC(float* __restrict__ out, const float* __restrict__ ws){
  const int NQ4=NPOS/4;
  int idx=blockIdx.x*256+threadIdx.x;
  int stride=gridDim.x*256;
  unsigned* outu=(unsigned*)out;
  for(int e=idx;e<64*NQ4;e+=stride){
    int qq=e/NQ4, nb=(e-qq*NQ4)*4;
    size_t base=(size_t)(2*qq)*NPOS + nb;
    u32x4 v=__builtin_nontemporal_load((const u32x4*)(outu+base));
    float sc0=ws[W_SC2+2*qq],   sh0=ws[W_SC2+H2C+2*qq];
    float sc1=ws[W_SC2+2*qq+1], sh1=ws[W_SC2+H2C+2*qq+1];
    f32x4 o0,o1;
    o0.x=bf2f((unsigned short)(v.x&0xffff))*sc0+sh0;
    o1.x=bf2f((unsigned short)(v.x>>16))  *sc1+sh1;
    o0.y=bf2f((unsigned short)(v.y&0xffff))*sc0+sh0;
    o1.y=bf2f((unsigned short)(v.y>>16))  *sc1+sh1;
    o0.z=bf2f((unsigned short)(v.z&0xffff))*sc0+sh0;
    o1.z=bf2f((unsigned short)(v.z>>16))  *sc1+sh1;
    o0.w=bf2f((unsigned short)(v.w&0xffff))*sc0+sh0;
    o1.w=bf2f((unsigned short)(v.w>>16))  *sc1+sh1;
    __builtin_nontemporal_store(o0,(f32x4*)(out+base));
    __builtin_nontemporal_store(o1,(f32x4*)(out+base+NPOS));
  }
}

extern "C" void kernel_launch(void* const* d_in, const int* in_sizes, int n_in,
                              void* d_out, int out_size, void* d_ws, size_t ws_size,
                              hipStream_t stream){
  const float* z0     =(const float*)d_in[0];
  const float* z1     =(const float*)d_in[1];
  const float* we1    =(const float*)d_in[2];
  const float* we2    =(const float*)d_in[3];
  const float* we3    =(const float*)d_in[4];
  const float* we4    =(const float*)d_in[5];
  const float* we5    =(const float*)d_in[6];
  const float* conv_w =(const float*)d_in[7];
  const float* conv_b =(const float*)d_in[8];
  const float* bn_g   =(const float*)d_in[9];
  const float* bn_b   =(const float*)d_in[10];
  const float* conv2_w=(const float*)d_in[11];
  const float* conv2_b=(const float*)d_in[12];
  const float* bn2_g  =(const float*)d_in[13];
  const float* bn2_b  =(const float*)d_in[14];
  const int* cdrH=(const int*)d_in[15];
  const int* cdrL=(const int*)d_in[16];
  const int* notH=(const int*)d_in[17];
  const int* notL=(const int*)d_in[18];
  int nCdrH=in_sizes[15], nCdrL=in_sizes[16], nNotH=in_sizes[17], nNotL=in_sizes[18];
  float* ws=(float*)d_ws;
  float* out=(float*)d_out;

  hipLaunchKernelGGL(k_prep,     dim3(96),   dim3(256),0,stream, conv_w,ws);
  hipLaunchKernelGGL(k_means,    dim3(DD),   dim3(256),0,stream, z0,z1,cdrH,notH,cdrL,notL,
                     nCdrH,nNotH,nCdrL,nNotL,ws);
  hipLaunchKernelGGL(k_scales,   dim3(1),    dim3(256),0,stream, we1,we2,we3,we4,we5,ws);
  hipLaunchKernelGGL(k_aw,       dim3((LL0*48+255)/256), dim3(256),0,stream, z0,ws);
  hipLaunchKernelGGL(k_gemmA,    dim3(GRIDP),dim3(256),0,stream, ws,conv_b, ws+W_BN1S);
  hipLaunchKernelGGL(k_bnparams, dim3(1),    dim3(256),0,stream, ws,bn_g,bn_b, HC, W_BN1S, W_SC1);
  hipLaunchKernelGGL(k_prep2,    dim3(H2C),  dim3(256),0,stream, conv2_w,conv2_b,ws);
  hipLaunchKernelGGL(k_gemmB,    dim3(GRIDP),dim3(256),0,stream, ws,conv_b, out, ws+W_BN2S);
  hipLaunchKernelGGL(k_bnparams, dim3(1),    dim3(256),0,stream, ws,bn2_g,bn2_b, H2C, W_BN2S, W_SC2);
  hipLaunchKernelGGL(k_passC,    dim3(2048), dim3(256),0,stream, out, ws);
}

// Round 12
// 230.656 us; speedup vs baseline: 1.3940x; 1.0117x over previous
//
#include <hip/hip_runtime.h>
#include <math.h>

#define DD   46
#define LL0  4000
#define LL1  600
#define CATV 250
#define NC   50
#define NJ   100
#define HC   256
#define H2C  128
#define NPOS (LL0*NJ)
#define EPSV 1e-5f
#define NT   64
#define XROW 104
#define C1ROW 268
#define C2PAD 68
#define TILES (NPOS/NT)   // 6250
#define GRIDP 512

// ---- workspace float offsets ----
#define W_MEAN0   0
#define W_MEANH   64
#define W_MEANL   128
#define W_RM4     192
#define W_RM5     256
#define W_S1      320
#define W_HBAR    384
#define W_RAWMH   448
#define W_RAWML   2752
#define W_H       5056
#define W_L       7360
#define W_BN1S    9664            // 256 sum + 256 sumsq
#define W_SC1     10176           // 256 scale + 256 shift
#define W_BN2S    10688           // 128+128
#define W_SC2     10944           // 128+128 -> 11200
#define W_HBF     11200           // 2400 ushort [j][48]
#define W_LBF     12400           // 2400 ushort
#define W_AWT     13632           // [4001][144] f32
#define W_W1P     589776          // 256*96 bf16
#define W_W2BF    602064          // 128*256 bf16
#define W_BIAS2   618448          // 128 floats

typedef __attribute__((ext_vector_type(8))) short bf8;
typedef __attribute__((ext_vector_type(4))) float f32x4;
typedef __attribute__((ext_vector_type(4))) unsigned u32x4;

__device__ __forceinline__ float sigf(float x){ return 1.0f/(1.0f+__expf(-x)); }

__device__ __forceinline__ unsigned short f2bf(float f){
  unsigned u = __float_as_uint(f);
  return (unsigned short)((u + 0x7FFFu + ((u>>16)&1u)) >> 16);
}
__device__ __forceinline__ unsigned pk2bf(float a, float b){
  return ((unsigned)f2bf(b)<<16) | (unsigned)f2bf(a);
}
__device__ __forceinline__ float bf2f(unsigned short h){
  return __uint_as_float(((unsigned)h)<<16);
}

__device__ float blockReduceSum(float v, float* sm){
  int tid=threadIdx.x;
  sm[tid]=v; __syncthreads();
  for(int s=128;s>0;s>>=1){ if(tid<s) sm[tid]+=sm[tid+s]; __syncthreads(); }
  float r=sm[0]; __syncthreads();
  return r;
}

// W1 -> bf16 permuted [o][2d+p]; block 0 zeros BN stat region
__global__ void k_prep(const float* __restrict__ conv_w, float* __restrict__ ws){
  int t=blockIdx.x*256+threadIdx.x;
  if(blockIdx.x==0){ for(int e=threadIdx.x;e<1536;e+=256) ws[W_BN1S+e]=0.f; }
  if(t<HC*96){
    int o=t/96, c=t-o*96;
    unsigned short v=0;
    if(c<92){ int d=c>>1, p=c&1; v=f2bf(conv_w[o*92 + (p? 46+d : d)]); }
    ((unsigned short*)(ws+W_W1P))[t]=v;
  }
}

// W2' = W2*sc1 (bf16), bias2' = b2 + sum_k W2[o2,k]*sh1[k]
__global__ void k_prep2(const float* __restrict__ conv2_w, const float* __restrict__ conv2_b,
                        float* __restrict__ ws){
  __shared__ float sm[256];
  int o2=blockIdx.x, t=threadIdx.x;
  float wv=conv2_w[o2*HC+t];
  float sc=ws[W_SC1+t], sh=ws[W_SC1+HC+t];
  ((unsigned short*)(ws+W_W2BF))[o2*HC+t]=f2bf(wv*sc);
  float r=blockReduceSum(wv*sh,sm);
  if(t==0) ws[W_BIAS2+o2]=conv2_b[o2]+r;
}

// fused: per-channel means + raw pair-difference means, block d
__global__ void k_means(const float* __restrict__ z0, const float* __restrict__ z1,
                        const int* cdrH, const int* notH,
                        const int* cdrL, const int* notL,
                        int nCdrH,int nNotH,int nCdrL,int nNotL, float* ws){
  __shared__ float v[LL1];
  __shared__ float sm[256];
  int d=blockIdx.x, tid=threadIdx.x;
  float s0=0.f; for(int i=tid;i<LL0;i+=256) s0+=z0[i*DD+d];
  for(int k=tid;k<LL1;k+=256) v[k]=z1[k*DD+d];
  float r0=blockReduceSum(s0,sm);
  __syncthreads();
  float sH=0.f; for(int k=tid;k<CATV;k+=256) sH+=v[k];
  float sL=0.f; for(int k=CATV+tid;k<LL1;k+=256) sL+=v[k];
  float rH=blockReduceSum(sH,sm);
  float rL=blockReduceSum(sL,sm);
  float partH=0.f, partL=0.f;
  for(int i=tid;i<nCdrH;i+=256){
    float c=v[cdrH[i]]; float s=0.f;
    for(int j=0;j<nNotH;j++) s+=fabsf(c-v[notH[j]]);
    s/= (float)nNotH;
    ws[W_RAWMH+d*NC+i]=s; partH+=s;
  }
  for(int i=tid;i<nCdrL;i+=256){
    float c=v[CATV+cdrL[i]]; float s=0.f;
    for(int j=0;j<nNotL;j++) s+=fabsf(c-v[CATV+notL[j]]);
    s/= (float)nNotL;
    ws[W_RAWML+d*NC+i]=s; partL+=s;
  }
  float pH=blockReduceSum(partH,sm);
  float pL=blockReduceSum(partL,sm);
  if(tid==0){
    ws[W_MEAN0+d]=r0/(float)LL0;
    ws[W_MEANH+d]=rH/(float)CATV;
    ws[W_MEANL+d]=rL/(float)(LL1-CATV);
    ws[W_RM4+d]=pH/(float)nCdrH;
    ws[W_RM5+d]=pL/(float)nCdrL;
  }
}

__device__ __forceinline__ float conv3(const float* a, int d, const float* w){
  float acc = w[1]*a[d];
  if(d>0)    acc += w[0]*a[d-1];
  if(d<DD-1) acc += w[2]*a[d+1];
  return acc;
}

// scales + final h, l, hbar + bf16 table copies [j][48]
__global__ void k_scales(const float* w1,const float* w2,const float* w3,
                         const float* w4,const float* w5, float* ws){
  __shared__ float m0[DD], mH[DD], mL[DD];
  __shared__ float s1s[DD],s2s[DD],s3s[DD],s4s[DD],s5s[DD],y4[DD],y5[DD];
  int tid=threadIdx.x;
  if(tid<DD){ m0[tid]=ws[W_MEAN0+tid]; mH[tid]=ws[W_MEANH+tid]; mL[tid]=ws[W_MEANL+tid]; }
  __syncthreads();
  if(tid<DD){
    s1s[tid]=sigf(conv3(m0,tid,w1));
    s2s[tid]=sigf(conv3(mH,tid,w2));
    s3s[tid]=sigf(conv3(mL,tid,w3));
  }
  __syncthreads();
  if(tid<DD){ y4[tid]=s2s[tid]*ws[W_RM4+tid]; y5[tid]=s3s[tid]*ws[W_RM5+tid]; }
  __syncthreads();
  if(tid<DD){
    s4s[tid]=sigf(conv3(y4,tid,w4));
    s5s[tid]=sigf(conv3(y5,tid,w5));
    ws[W_S1+tid]=s1s[tid];
  }
  __syncthreads();
  for(int e=tid;e<DD*NC;e+=256){
    int d=e/NC;
    ws[W_H+e]=s4s[d]*s2s[d]*ws[W_RAWMH+e];
    ws[W_L+e]=s5s[d]*s3s[d]*ws[W_RAWML+e];
  }
  __syncthreads();
  if(tid<DD){
    float s=0.f;
    for(int j=0;j<NC;j++) s+=ws[W_H+tid*NC+j];
    ws[W_HBAR+tid]=s/(float)NC;
  }
  __syncthreads();
  for(int e=tid;e<2400;e+=256){
    int j=e/48, d=e-48*j;
    unsigned short hv=0, lv=0;
    if(d<DD){ hv=f2bf(ws[W_H+d*NC+j]); lv=f2bf(ws[W_L+d*NC+j]); }
    ((unsigned short*)(ws+W_HBF))[e]=hv;
    ((unsigned short*)(ws+W_LBF))[e]=lv;
  }
}

// AWt[i][144] = { a0[48] | dif[48] | mul[48] }
__global__ void k_aw(const float* __restrict__ z0, float* __restrict__ ws){
  int e=blockIdx.x*256+threadIdx.x;
  if(e>=LL0*48) return;
  int i=e/48, d=e-48*i;
  float a=0.f, df=0.f, ml=0.f;
  if(d<DD){
    a = ws[W_S1+d]*z0[i*DD+d];
    float s=0.f;
    #pragma unroll 10
    for(int j=0;j<NC;j++) s+=fabsf(a-ws[W_H+d*NC+j]);
    df = s*(1.0f/(float)NC);
    ml = a*ws[W_HBAR+d];
  }
  ws[W_AWT + i*144 + d]      = a;
  ws[W_AWT + i*144 + 48 + d] = df;
  ws[W_AWT + i*144 + 96 + d] = ml;
}

// stage bf16 h/l tables into LDS via 16B vectors
__device__ __forceinline__ void stage_tables(unsigned short* hT, unsigned short* lT,
                                             const float* __restrict__ ws, int tid){
  for(int e=tid;e<300;e+=256){
    ((u32x4*)hT)[e]=((const u32x4*)(ws+W_HBF))[e];
    ((u32x4*)lT)[e]=((const u32x4*)(ws+W_LBF))[e];
  }
}

// build X tile (bf16, interleaved c=2d+p)
__device__ __forceinline__ void build_X(unsigned short* Xl, const float* aw,
                                        const unsigned short* hT, const unsigned short* lT,
                                        int n0, int i0, int tid){
  int ibase=i0*100, ib1=ibase+100;
  for(int e=tid;e<NT*12;e+=256){
    int n=e/12, g=e-12*n, d4=g*4;
    int ncol=n0+n;
    int ii=(ncol>=ib1)?1:0;
    int j=ncol-ibase-ii*100;
    const float* ar=aw+ii*144;
    float x10,x11,x12,x13, x20,x21,x22,x23;
    if(j<NC){
      float4 a=*(const float4*)(ar+d4);
      ushort4 hb=*(const ushort4*)(hT+j*48+d4);
      float h0=bf2f(hb.x),h1=bf2f(hb.y),h2=bf2f(hb.z),h3=bf2f(hb.w);
      x10=fabsf(a.x-h0); x20=a.x*h0;
      x11=fabsf(a.y-h1); x21=a.y*h1;
      x12=fabsf(a.z-h2); x22=a.z*h2;
      x13=fabsf(a.w-h3); x23=a.w*h3;
    }else{
      float4 df=*(const float4*)(ar+48+d4);
      float4 ml=*(const float4*)(ar+96+d4);
      ushort4 lb=*(const ushort4*)(lT+(j-NC)*48+d4);
      float l0=bf2f(lb.x),l1=bf2f(lb.y),l2=bf2f(lb.z),l3=bf2f(lb.w);
      x10=fabsf(df.x-l0); x20=fabsf(ml.x-l0);
      x11=fabsf(df.y-l1); x21=fabsf(ml.y-l1);
      x12=fabsf(df.z-l2); x22=fabsf(ml.z-l2);
      x13=fabsf(df.w-l3); x23=fabsf(ml.w-l3);
    }
    u32x4 pv;
    pv.x=pk2bf(x10,x20); pv.y=pk2bf(x11,x21); pv.z=pk2bf(x12,x22); pv.w=pk2bf(x13,x23);
    *(u32x4*)(Xl + n*XROW + 8*g) = pv;
  }
}

// pass A (persistent, r11-proven): build + gemm1 + BN1 stats; weights register-resident
__global__ __launch_bounds__(256,2) void k_gemmA(const float* __restrict__ ws,
                                                 const float* __restrict__ conv_b,
                                                 float* __restrict__ bnsum){
  __shared__ unsigned short hT[2400], lT[2400];
  __shared__ float aw[2][288];
  __shared__ unsigned short Xl[NT*XROW];
  __shared__ float bnred[512];
  int tid=threadIdx.x;
  int l=tid&63, w=tid>>6, lr=l&15, hi=l>>4, mb=w*64;
  stage_tables(hT,lT,ws,tid);
  const unsigned short* W1p=(const unsigned short*)(ws+W_W1P);
  bf8 w1f[4][3];
  #pragma unroll
  for(int tm=0;tm<4;tm++)
    #pragma unroll
    for(int ks=0;ks<3;ks++)
      w1f[tm][ks]=*(const bf8*)(W1p + (mb+tm*16+lr)*96 + ks*32 + hi*8);
  float bb[4][4];
  #pragma unroll
  for(int tm=0;tm<4;tm++)
    #pragma unroll
    for(int r=0;r<4;r++) bb[tm][r]=conv_b[mb+tm*16+hi*4+r];
  float s[4][4], q[4][4];
  #pragma unroll
  for(int tm=0;tm<4;tm++)
    #pragma unroll
    for(int r=0;r<4;r++){ s[tm][r]=0.f; q[tm][r]=0.f; }
  if(tid<72) ((float4*)aw[0])[tid]=*(((const float4*)(ws+W_AWT+((blockIdx.x*NT)/100)*144))+tid);
  __syncthreads();

  int pb=0;
  for(int t=blockIdx.x;t<TILES;t+=GRIDP){
    int n0=t*NT, i0=n0/100, nxt=t+GRIDP;
    build_X(Xl,aw[pb],hT,lT,n0,i0,tid);
    __syncthreads();                             // X ready; aw[pb] consumed
    if(tid<72 && nxt<TILES)
      ((float4*)aw[pb^1])[tid]=*(((const float4*)(ws+W_AWT+((nxt*NT)/100)*144))+tid);
    f32x4 acc[4][4];
    #pragma unroll
    for(int tm=0;tm<4;tm++)
      #pragma unroll
      for(int tn=0;tn<4;tn++) acc[tm][tn]=(f32x4){0.f,0.f,0.f,0.f};
    #pragma unroll
    for(int ks=0;ks<3;ks++){
      bf8 b[4];
      #pragma unroll
      for(int tn=0;tn<4;tn++)
        b[tn]=*(const bf8*)(Xl + (tn*16+lr)*XROW + ks*32 + hi*8);
      #pragma unroll
      for(int tm=0;tm<4;tm++)
        #pragma unroll
        for(int tn=0;tn<4;tn++)
          acc[tm][tn]=__builtin_amdgcn_mfma_f32_16x16x32_bf16(w1f[tm][ks],b[tn],acc[tm][tn],0,0,0);
    }
    #pragma unroll
    for(int tm=0;tm<4;tm++)
      #pragma unroll
      for(int tn=0;tn<4;tn++)
        #pragma unroll
        for(int r=0;r<4;r++){
          float vv=fmaxf(acc[tm][tn][r]+bb[tm][r],0.f);
          s[tm][r]+=vv; q[tm][r]+=vv*vv;
        }
    __syncthreads();                             // Xl reads done before next build
    pb^=1;
  }
  #pragma unroll
  for(int m=1;m<16;m<<=1)
    #pragma unroll
    for(int tm=0;tm<4;tm++)
      #pragma unroll
      for(int r=0;r<4;r++){
        s[tm][r]+=__shfl_xor(s[tm][r],m);
        q[tm][r]+=__shfl_xor(q[tm][r],m);
      }
  if(lr==0){
    #pragma unroll
    for(int tm=0;tm<4;tm++)
      #pragma unroll
      for(int r=0;r<4;r++){
        int o=mb+tm*16+hi*4+r;
        bnred[o]=s[tm][r]; bnred[256+o]=q[tm][r];
      }
  }
  __syncthreads();
  for(int e=tid;e<512;e+=256) atomicAdd(&bnsum[e],bnred[e]);
}

__global__ void k_bnparams(float* ws, const float* g, const float* b,
                           int nch, int sumoff, int scoff){
  int o=threadIdx.x;
  if(o<nch){
    float mu =ws[sumoff+o]    *(1.0f/(float)NPOS);
    float ex2=ws[sumoff+nch+o]*(1.0f/(float)NPOS);
    float var=ex2-mu*mu; if(var<0.f) var=0.f;
    float sc=g[o]*rsqrtf(var+EPSV);
    ws[scoff+o]=sc;
    ws[scoff+nch+o]=b[o]-mu*sc;
  }
}

// pass B (persistent, pipelined): build(t+1) || gemm1(t); dbuf Xl; 4 barriers/tile
__global__ __launch_bounds__(256,2) void k_gemmB(const float* __restrict__ ws,
      const float* __restrict__ conv_b, float* __restrict__ out,
      float* __restrict__ bn2sum){
  __shared__ unsigned short hT[2400], lT[2400];   // 9600 B
  __shared__ float aw[2][288];                    // 2304 B
  __shared__ unsigned short Xl[2][NT*XROW];       // 26624 B
  __shared__ unsigned short C1s[NT*C1ROW];        // 34304 B (C2s reuses this)
  __shared__ float bnred[256];                    // 1024 B   -> total 73856 B
  int tid=threadIdx.x;
  int l=tid&63, w=tid>>6, lr=l&15, hi=l>>4, mb=w*64, mb2=w*32;
  stage_tables(hT,lT,ws,tid);
  const unsigned short* W1p =(const unsigned short*)(ws+W_W1P);
  const unsigned short* W2bf=(const unsigned short*)(ws+W_W2BF);
  const float* bias2=ws+W_BIAS2;
  unsigned* outu=(unsigned*)out;
  bf8 w1f[4][3];
  #pragma unroll
  for(int tm=0;tm<4;tm++)
    #pragma unroll
    for(int ks=0;ks<3;ks++)
      w1f[tm][ks]=*(const bf8*)(W1p + (mb+tm*16+lr)*96 + ks*32 + hi*8);
  bf8 w2f[2][8];
  #pragma unroll
  for(int tm2=0;tm2<2;tm2++)
    #pragma unroll
    for(int ks=0;ks<8;ks++)
      w2f[tm2][ks]=*(const bf8*)(W2bf + (mb2+tm2*16+lr)*HC + ks*32 + hi*8);
  float bb[4][4];
  #pragma unroll
  for(int tm=0;tm<4;tm++)
    #pragma unroll
    for(int r=0;r<4;r++) bb[tm][r]=conv_b[mb+tm*16+hi*4+r];
  float bb2[2][4];
  #pragma unroll
  for(int tm2=0;tm2<2;tm2++)
    #pragma unroll
    for(int r=0;r<4;r++) bb2[tm2][r]=bias2[mb2+tm2*16+hi*4+r];
  float s2[2][4], q2[2][4];
  #pragma unroll
  for(int tm2=0;tm2<2;tm2++)
    #pragma unroll
    for(int r=0;r<4;r++){ s2[tm2][r]=0.f; q2[tm2][r]=0.f; }
  // prologue: aw(t0) -> build X(t0) ; aw(t1)
  {
    int t0=blockIdx.x;
    if(tid<72) ((float4*)aw[0])[tid]=*(((const float4*)(ws+W_AWT+((t0*NT)/100)*144))+tid);
    __syncthreads();
    build_X(Xl[0],aw[0],hT,lT,t0*NT,(t0*NT)/100,tid);
    if(tid<72 && t0+GRIDP<TILES)
      ((float4*)aw[1])[tid]=*(((const float4*)(ws+W_AWT+(((t0+GRIDP)*NT)/100)*144))+tid);
    __syncthreads();
  }

  int p=0, qb=1;
  for(int t=blockIdx.x;t<TILES;t+=GRIDP){
    int n0=t*NT, nxt=t+GRIDP, nn2=t+2*GRIDP;
    // phase a: aw prefetch (t+2) + build(t+1 -> Xl[p^1])  ||  gemm1(t <- Xl[p])
    if(tid<72 && nn2<TILES)
      ((float4*)aw[qb^1])[tid]=*(((const float4*)(ws+W_AWT+((nn2*NT)/100)*144))+tid);
    if(nxt<TILES) build_X(Xl[p^1],aw[qb],hT,lT,nxt*NT,(nxt*NT)/100,tid);
    f32x4 acc[4][4];
    #pragma unroll
    for(int tm=0;tm<4;tm++)
      #pragma unroll
      for(int tn=0;tn<4;tn++) acc[tm][tn]=(f32x4){0.f,0.f,0.f,0.f};
    #pragma unroll
    for(int ks=0;ks<3;ks++){
      bf8 b[4];
      #pragma unroll
      for(int tn=0;tn<4;tn++)
        b[tn]=*(const bf8*)(Xl[p] + (tn*16+lr)*XROW + ks*32 + hi*8);
      #pragma unroll
      for(int tm=0;tm<4;tm++)
        #pragma unroll
        for(int tn=0;tn<4;tn++)
          acc[tm][tn]=__builtin_amdgcn_mfma_f32_16x16x32_bf16(w1f[tm][ks],b[tn],acc[tm][tn],0,0,0);
    }
    __syncthreads();                           // B1: build done; Xl[p] reads done; C1 free
    // pack C1(t)
    #pragma unroll
    for(int tm=0;tm<4;tm++)
      #pragma unroll
      for(int tn=0;tn<4;tn++){
        int n=tn*16+lr, ob=mb+tm*16+hi*4;
        float v0=fmaxf(acc[tm][tn][0]+bb[tm][0],0.f);
        float v1=fmaxf(acc[tm][tn][1]+bb[tm][1],0.f);
        float v2=fmaxf(acc[tm][tn][2]+bb[tm][2],0.f);
        float v3=fmaxf(acc[tm][tn][3]+bb[tm][3],0.f);
        uint2 pv; pv.x=pk2bf(v0,v1); pv.y=pk2bf(v2,v3);
        *(uint2*)&C1s[n*C1ROW+ob]=pv;
      }
    __syncthreads();                           // B2: C1 visible
    // gemm2(t)
    f32x4 acc2[2][4];
    #pragma unroll
    for(int tm2=0;tm2<2;tm2++)
      #pragma unroll
      for(int tn=0;tn<4;tn++) acc2[tm2][tn]=(f32x4){0.f,0.f,0.f,0.f};
    #pragma unroll
    for(int ks=0;ks<8;ks++){
      bf8 b2[4];
      #pragma unroll
      for(int tn=0;tn<4;tn++)
        b2[tn]=*(const bf8*)(C1s + (tn*16+lr)*C1ROW + ks*32 + hi*8);
      #pragma unroll
      for(int tm2=0;tm2<2;tm2++)
        #pragma unroll
        for(int tn=0;tn<4;tn++)
          acc2[tm2][tn]=__builtin_amdgcn_mfma_f32_16x16x32_bf16(w2f[tm2][ks],b2[tn],acc2[tm2][tn],0,0,0);
    }
    __syncthreads();                           // B3: C1 reads done
    // epilogue: relu + stats + stage C2 pairs into C1 region (u32[64][C2PAD])
    unsigned* C2s=(unsigned*)C1s;
    #pragma unroll
    for(int tm2=0;tm2<2;tm2++)
      #pragma unroll
      for(int tn=0;tn<4;tn++){
        float v0=fmaxf(acc2[tm2][tn][0]+bb2[tm2][0],0.f);
        float v1=fmaxf(acc2[tm2][tn][1]+bb2[tm2][1],0.f);
        float v2=fmaxf(acc2[tm2][tn][2]+bb2[tm2][2],0.f);
        float v3=fmaxf(acc2[tm2][tn][3]+bb2[tm2][3],0.f);
        s2[tm2][0]+=v0; q2[tm2][0]+=v0*v0;
        s2[tm2][1]+=v1; q2[tm2][1]+=v1*v1;
        s2[tm2][2]+=v2; q2[tm2][2]+=v2*v2;
        s2[tm2][3]+=v3; q2[tm2][3]+=v3*v3;
        int n=tn*16+lr;
        int q0=(mb2+tm2*16+hi*4)>>1;
        C2s[q0*C2PAD+n]    =pk2bf(v0,v1);
        C2s[(q0+1)*C2PAD+n]=pk2bf(v2,v3);
      }
    __syncthreads();                           // B4: C2s ready
    // full-line stores into out's EVEN rows (u32 pair per (2q,2q+1))
    #pragma unroll
    for(int p16=0;p16<4;p16++){
      int row=p16*16+(tid>>4), chunk=tid&15;
      u32x4 v=*(const u32x4*)&C2s[row*C2PAD+chunk*4];
      *(u32x4*)(outu + (size_t)(2*row)*NPOS + n0 + chunk*4) = v;
    }
    p^=1; qb^=1;
    // no barrier: next pack(C1) is gated by next B1; each thread finished its C2s reads
  }
  #pragma unroll
  for(int m=1;m<16;m<<=1)
    #pragma unroll
    for(int tm2=0;tm2<2;tm2++)
      #pragma unroll
      for(int r=0;r<4;r++){
        s2[tm2][r]+=__shfl_xor(s2[tm2][r],m);
        q2[tm2][r]+=__shfl_xor(q2[tm2][r],m);
      }
  if(lr==0){
    #pragma unroll
    for(int tm2=0;tm2<2;tm2++)
      #pragma unroll
      for(int r=0;r<4;r++){
        int o=mb2+tm2*16+hi*4+r;
        bnred[o]=s2[tm2][r]; bnred[128+o]=q2[tm2][r];
      }
  }
  __syncthreads();
  if(tid<256) atomicAdd(&bn2sum[tid],bnred[tid]);
}

// pass C: read bf16 pair u32 from even row, expand+affine, write f32 even+odd rows
__global__ void k_passC(float* __restrict__ out, const float* __restrict__ ws){
  const int NQ4=NPOS/4;
  int idx=blockIdx.x*256+threadIdx.x;
  int stride=gridDim.x*256;
  unsigned* outu=(unsigned*)out;
  for(int e=idx;e<64*NQ4;e+=stride){
    int qq=e/NQ4, nb=(e-qq*NQ4)*4;
    size_t base=(size_t)(2*qq)*NPOS + nb;
    u32x4 v=__builtin_nontemporal_load((const u32x4*)(outu+base));
    float sc0=ws[W_SC2+2*qq],   sh0=ws[W_SC2+H2C+2*qq];
    float sc1=ws[W_SC2+2*qq+1], sh1=ws[W_SC2+H2C+2*qq+1];
    f32x4 o0,o1;
    o0.x=bf2f((unsigned short)(v.x&0xffff))*sc0+sh0;
    o1.x=bf2f((unsigned short)(v.x>>16))  *sc1+sh1;
    o0.y=bf2f((unsigned short)(v.y&0xffff))*sc0+sh0;
    o1.y=bf2f((unsigned short)(v.y>>16))  *sc1+sh1;
    o0.z=bf2f((unsigned short)(v.z&0xffff))*sc0+sh0;
    o1.z=bf2f((unsigned short)(v.z>>16))  *sc1+sh1;
    o0.w=bf2f((unsigned short)(v.w&0xffff))*sc0+sh0;
    o1.w=bf2f((unsigned short)(v.w>>16))  *sc1+sh1;
    __builtin_nontemporal_store(o0,(f32x4*)(out+base));
    __builtin_nontemporal_store(o1,(f32x4*)(out+base+NPOS));
  }
}

extern "C" void kernel_launch(void* const* d_in, const int* in_sizes, int n_in,
                              void* d_out, int out_size, void* d_ws, size_t ws_size,
                              hipStream_t stream){
  const float* z0     =(const float*)d_in[0];
  const float* z1     =(const float*)d_in[1];
  const float* we1    =(const float*)d_in[2];
  const float* we2    =(const float*)d_in[3];
  const float* we3    =(const float*)d_in[4];
  const float* we4    =(const float*)d_in[5];
  const float* we5    =(const float*)d_in[6];
  const float* conv_w =(const float*)d_in[7];
  const float* conv_b =(const float*)d_in[8];
  const float* bn_g   =(const float*)d_in[9];
  const float* bn_b   =(const float*)d_in[10];
  const float* conv2_w=(const float*)d_in[11];
  const float* conv2_b=(const float*)d_in[12];
  const float* bn2_g  =(const float*)d_in[13];
  const float* bn2_b  =(const float*)d_in[14];
  const int* cdrH=(const int*)d_in[15];
  const int* cdrL=(const int*)d_in[16];
  const int* notH=(const int*)d_in[17];
  const int* notL=(const int*)d_in[18];
  int nCdrH=in_sizes[15], nCdrL=in_sizes[16], nNotH=in_sizes[17], nNotL=in_sizes[18];
  float* ws=(float*)d_ws;
  float* out=(float*)d_out;

  hipLaunchKernelGGL(k_prep,     dim3(96),   dim3(256),0,stream, conv_w,ws);
  hipLaunchKernelGGL(k_means,    dim3(DD),   dim3(256),0,stream, z0,z1,cdrH,notH,cdrL,notL,
                     nCdrH,nNotH,nCdrL,nNotL,ws);
  hipLaunchKernelGGL(k_scales,   dim3(1),    dim3(256),0,stream, we1,we2,we3,we4,we5,ws);
  hipLaunchKernelGGL(k_aw,       dim3((LL0*48+255)/256), dim3(256),0,stream, z0,ws);
  hipLaunchKernelGGL(k_gemmA,    dim3(GRIDP),dim3(256),0,stream, ws,conv_b, ws+W_BN1S);
  hipLaunchKernelGGL(k_bnparams, dim3(1),    dim3(256),0,stream, ws,bn_g,bn_b, HC, W_BN1S, W_SC1);
  hipLaunchKernelGGL(k_prep2,    dim3(H2C),  dim3(256),0,stream, conv2_w,conv2_b,ws);
  hipLaunchKernelGGL(k_gemmB,    dim3(GRIDP),dim3(256),0,stream, ws,conv_b, out, ws+W_BN2S);
  hipLaunchKernelGGL(k_bnparams, dim3(1),    dim3(256),0,stream, ws,bn2_g,bn2_b, H2C, W_BN2S, W_SC2);
  hipLaunchKernelGGL(k_passC,    dim3(2048), dim3(256),0,stream, out, ws);
}

// Round 13
// 214.155 us; speedup vs baseline: 1.5014x; 1.0770x over previous
//
#include <hip/hip_runtime.h>
#include <math.h>

#define DD   46
#define LL0  4000
#define LL1  600
#define CATV 250
#define NC   50
#define NJ   100
#define HC   256
#define H2C  128
#define NPOS (LL0*NJ)
#define EPSV 1e-5f
#define NT   64
#define XROW 104
#define C1ROW 268
#define C2PAD 68
#define TILES (NPOS/NT)   // 6250
#define GRIDP 512

// ---- workspace float offsets ----
#define W_MEAN0   0
#define W_MEANH   64
#define W_MEANL   128
#define W_RM4     192
#define W_RM5     256
#define W_S1      320
#define W_HBAR    384
#define W_RAWMH   448
#define W_RAWML   2752
#define W_H       5056
#define W_L       7360
#define W_BN1S    9664            // 256 sum + 256 sumsq
#define W_SC1     10176           // 256 scale + 256 shift
#define W_BN2S    10688           // 128+128
#define W_SC2     10944           // 128+128 -> 11200
#define W_HBF     11200           // 2400 ushort [j][48]
#define W_LBF     12400           // 2400 ushort
#define W_AWT     13632           // [4001][144] f32
#define W_W1P     589776          // 256*96 bf16
#define W_W2BF    602064          // 128*256 bf16
#define W_BIAS2   618448          // 128 floats

typedef __attribute__((ext_vector_type(8))) short bf8;
typedef __attribute__((ext_vector_type(4))) float f32x4;
typedef __attribute__((ext_vector_type(4))) unsigned u32x4;

__device__ __forceinline__ float sigf(float x){ return 1.0f/(1.0f+__expf(-x)); }

__device__ __forceinline__ unsigned short f2bf(float f){
  unsigned u = __float_as_uint(f);
  return (unsigned short)((u + 0x7FFFu + ((u>>16)&1u)) >> 16);
}
// HW packed f32->bf16 (RTNE, same as f2bf): lo=a, hi=b, one instruction
__device__ __forceinline__ unsigned pkcvt(float a, float b){
  unsigned r;
  asm("v_cvt_pk_bf16_f32 %0, %1, %2" : "=v"(r) : "v"(a), "v"(b));
  return r;
}
__device__ __forceinline__ float bf2f(unsigned short h){
  return __uint_as_float(((unsigned)h)<<16);
}

__device__ float blockReduceSum(float v, float* sm){
  int tid=threadIdx.x;
  sm[tid]=v; __syncthreads();
  for(int s=128;s>0;s>>=1){ if(tid<s) sm[tid]+=sm[tid+s]; __syncthreads(); }
  float r=sm[0]; __syncthreads();
  return r;
}

// fused: blocks 0..95 -> W1 bf16 permute (+stat zero); blocks 96..141 -> means
__global__ void k_prepmeans(const float* __restrict__ conv_w,
                            const float* __restrict__ z0, const float* __restrict__ z1,
                            const int* cdrH, const int* notH,
                            const int* cdrL, const int* notL,
                            int nCdrH,int nNotH,int nCdrL,int nNotL, float* ws){
  __shared__ float v[LL1];
  __shared__ float sm[256];
  int tid=threadIdx.x;
  if(blockIdx.x<96){
    int t=blockIdx.x*256+tid;
    if(blockIdx.x==0){ for(int e=tid;e<1536;e+=256) ws[W_BN1S+e]=0.f; }
    if(t<HC*96){
      int o=t/96, c=t-o*96;
      unsigned short vv=0;
      if(c<92){ int d=c>>1, p=c&1; vv=f2bf(conv_w[o*92 + (p? 46+d : d)]); }
      ((unsigned short*)(ws+W_W1P))[t]=vv;
    }
    return;
  }
  int d=blockIdx.x-96;
  float s0=0.f; for(int i=tid;i<LL0;i+=256) s0+=z0[i*DD+d];
  for(int k=tid;k<LL1;k+=256) v[k]=z1[k*DD+d];
  float r0=blockReduceSum(s0,sm);
  __syncthreads();
  float sH=0.f; for(int k=tid;k<CATV;k+=256) sH+=v[k];
  float sL=0.f; for(int k=CATV+tid;k<LL1;k+=256) sL+=v[k];
  float rH=blockReduceSum(sH,sm);
  float rL=blockReduceSum(sL,sm);
  float partH=0.f, partL=0.f;
  for(int i=tid;i<nCdrH;i+=256){
    float c=v[cdrH[i]]; float s=0.f;
    for(int j=0;j<nNotH;j++) s+=fabsf(c-v[notH[j]]);
    s/= (float)nNotH;
    ws[W_RAWMH+d*NC+i]=s; partH+=s;
  }
  for(int i=tid;i<nCdrL;i+=256){
    float c=v[CATV+cdrL[i]]; float s=0.f;
    for(int j=0;j<nNotL;j++) s+=fabsf(c-v[CATV+notL[j]]);
    s/= (float)nNotL;
    ws[W_RAWML+d*NC+i]=s; partL+=s;
  }
  float pH=blockReduceSum(partH,sm);
  float pL=blockReduceSum(partL,sm);
  if(tid==0){
    ws[W_MEAN0+d]=r0/(float)LL0;
    ws[W_MEANH+d]=rH/(float)CATV;
    ws[W_MEANL+d]=rL/(float)(LL1-CATV);
    ws[W_RM4+d]=pH/(float)nCdrH;
    ws[W_RM5+d]=pL/(float)nCdrL;
  }
}

// W2' = W2*sc1 (bf16), bias2' = b2 + sum_k W2[o2,k]*sh1[k]
__global__ void k_prep2(const float* __restrict__ conv2_w, const float* __restrict__ conv2_b,
                        float* __restrict__ ws){
  __shared__ float sm[256];
  int o2=blockIdx.x, t=threadIdx.x;
  float wv=conv2_w[o2*HC+t];
  float sc=ws[W_SC1+t], sh=ws[W_SC1+HC+t];
  ((unsigned short*)(ws+W_W2BF))[o2*HC+t]=f2bf(wv*sc);
  float r=blockReduceSum(wv*sh,sm);
  if(t==0) ws[W_BIAS2+o2]=conv2_b[o2]+r;
}

__device__ __forceinline__ float conv3(const float* a, int d, const float* w){
  float acc = w[1]*a[d];
  if(d>0)    acc += w[0]*a[d-1];
  if(d<DD-1) acc += w[2]*a[d+1];
  return acc;
}

// scales + final h, l, hbar + bf16 table copies [j][48]
__global__ void k_scales(const float* w1,const float* w2,const float* w3,
                         const float* w4,const float* w5, float* ws){
  __shared__ float m0[DD], mH[DD], mL[DD];
  __shared__ float s1s[DD],s2s[DD],s3s[DD],s4s[DD],s5s[DD],y4[DD],y5[DD];
  int tid=threadIdx.x;
  if(tid<DD){ m0[tid]=ws[W_MEAN0+tid]; mH[tid]=ws[W_MEANH+tid]; mL[tid]=ws[W_MEANL+tid]; }
  __syncthreads();
  if(tid<DD){
    s1s[tid]=sigf(conv3(m0,tid,w1));
    s2s[tid]=sigf(conv3(mH,tid,w2));
    s3s[tid]=sigf(conv3(mL,tid,w3));
  }
  __syncthreads();
  if(tid<DD){ y4[tid]=s2s[tid]*ws[W_RM4+tid]; y5[tid]=s3s[tid]*ws[W_RM5+tid]; }
  __syncthreads();
  if(tid<DD){
    s4s[tid]=sigf(conv3(y4,tid,w4));
    s5s[tid]=sigf(conv3(y5,tid,w5));
    ws[W_S1+tid]=s1s[tid];
  }
  __syncthreads();
  for(int e=tid;e<DD*NC;e+=256){
    int d=e/NC;
    ws[W_H+e]=s4s[d]*s2s[d]*ws[W_RAWMH+e];
    ws[W_L+e]=s5s[d]*s3s[d]*ws[W_RAWML+e];
  }
  __syncthreads();
  if(tid<DD){
    float s=0.f;
    for(int j=0;j<NC;j++) s+=ws[W_H+tid*NC+j];
    ws[W_HBAR+tid]=s/(float)NC;
  }
  __syncthreads();
  for(int e=tid;e<2400;e+=256){
    int j=e/48, d=e-48*j;
    unsigned short hv=0, lv=0;
    if(d<DD){ hv=f2bf(ws[W_H+d*NC+j]); lv=f2bf(ws[W_L+d*NC+j]); }
    ((unsigned short*)(ws+W_HBF))[e]=hv;
    ((unsigned short*)(ws+W_LBF))[e]=lv;
  }
}

// AWt[i][144] = { a0[48] | dif[48] | mul[48] }
__global__ void k_aw(const float* __restrict__ z0, float* __restrict__ ws){
  int e=blockIdx.x*256+threadIdx.x;
  if(e>=LL0*48) return;
  int i=e/48, d=e-48*i;
  float a=0.f, df=0.f, ml=0.f;
  if(d<DD){
    a = ws[W_S1+d]*z0[i*DD+d];
    float s=0.f;
    #pragma unroll 10
    for(int j=0;j<NC;j++) s+=fabsf(a-ws[W_H+d*NC+j]);
    df = s*(1.0f/(float)NC);
    ml = a*ws[W_HBAR+d];
  }
  ws[W_AWT + i*144 + d]      = a;
  ws[W_AWT + i*144 + 48 + d] = df;
  ws[W_AWT + i*144 + 96 + d] = ml;
}

// stage bf16 h/l tables into LDS via 16B vectors
__device__ __forceinline__ void stage_tables(unsigned short* hT, unsigned short* lT,
                                             const float* __restrict__ ws, int tid){
  for(int e=tid;e<300;e+=256){
    ((u32x4*)hT)[e]=((const u32x4*)(ws+W_HBF))[e];
    ((u32x4*)lT)[e]=((const u32x4*)(ws+W_LBF))[e];
  }
}

// build X tile (bf16, interleaved c=2d+p); HW packed cvt
__device__ __forceinline__ void build_X(unsigned short* Xl, const float* aw,
                                        const unsigned short* hT, const unsigned short* lT,
                                        int n0, int i0, int tid){
  int ibase=i0*100, ib1=ibase+100;
  for(int e=tid;e<NT*12;e+=256){
    int n=e/12, g=e-12*n, d4=g*4;
    int ncol=n0+n;
    int ii=(ncol>=ib1)?1:0;
    int j=ncol-ibase-ii*100;
    const float* ar=aw+ii*144;
    float x10,x11,x12,x13, x20,x21,x22,x23;
    if(j<NC){
      float4 a=*(const float4*)(ar+d4);
      ushort4 hb=*(const ushort4*)(hT+j*48+d4);
      float h0=bf2f(hb.x),h1=bf2f(hb.y),h2=bf2f(hb.z),h3=bf2f(hb.w);
      x10=fabsf(a.x-h0); x20=a.x*h0;
      x11=fabsf(a.y-h1); x21=a.y*h1;
      x12=fabsf(a.z-h2); x22=a.z*h2;
      x13=fabsf(a.w-h3); x23=a.w*h3;
    }else{
      float4 df=*(const float4*)(ar+48+d4);
      float4 ml=*(const float4*)(ar+96+d4);
      ushort4 lb=*(const ushort4*)(lT+(j-NC)*48+d4);
      float l0=bf2f(lb.x),l1=bf2f(lb.y),l2=bf2f(lb.z),l3=bf2f(lb.w);
      x10=fabsf(df.x-l0); x20=fabsf(ml.x-l0);
      x11=fabsf(df.y-l1); x21=fabsf(ml.y-l1);
      x12=fabsf(df.z-l2); x22=fabsf(ml.z-l2);
      x13=fabsf(df.w-l3); x23=fabsf(ml.w-l3);
    }
    u32x4 pv;
    pv.x=pkcvt(x10,x20); pv.y=pkcvt(x11,x21); pv.z=pkcvt(x12,x22); pv.w=pkcvt(x13,x23);
    *(u32x4*)(Xl + n*XROW + 8*g) = pv;
  }
}

// pass A (persistent): build + gemm1(bias in C) + BN1 stats
__global__ __launch_bounds__(256,2) void k_gemmA(const float* __restrict__ ws,
                                                 const float* __restrict__ conv_b,
                                                 float* __restrict__ bnsum){
  __shared__ unsigned short hT[2400], lT[2400];
  __shared__ float aw[2][288];
  __shared__ unsigned short Xl[NT*XROW];
  __shared__ float bnred[512];
  int tid=threadIdx.x;
  int l=tid&63, w=tid>>6, lr=l&15, hi=l>>4, mb=w*64;
  stage_tables(hT,lT,ws,tid);
  const unsigned short* W1p=(const unsigned short*)(ws+W_W1P);
  bf8 w1f[4][3];
  #pragma unroll
  for(int tm=0;tm<4;tm++)
    #pragma unroll
    for(int ks=0;ks<3;ks++)
      w1f[tm][ks]=*(const bf8*)(W1p + (mb+tm*16+lr)*96 + ks*32 + hi*8);
  f32x4 binit[4];
  #pragma unroll
  for(int tm=0;tm<4;tm++)
    #pragma unroll
    for(int r=0;r<4;r++) binit[tm][r]=conv_b[mb+tm*16+hi*4+r];
  float s[4][4], q[4][4];
  #pragma unroll
  for(int tm=0;tm<4;tm++)
    #pragma unroll
    for(int r=0;r<4;r++){ s[tm][r]=0.f; q[tm][r]=0.f; }
  if(tid<72) ((float4*)aw[0])[tid]=*(((const float4*)(ws+W_AWT+((blockIdx.x*NT)/100)*144))+tid);
  __syncthreads();

  int pb=0;
  for(int t=blockIdx.x;t<TILES;t+=GRIDP){
    int n0=t*NT, i0=n0/100, nxt=t+GRIDP;
    build_X(Xl,aw[pb],hT,lT,n0,i0,tid);
    __syncthreads();                             // X ready; aw[pb] consumed
    if(tid<72 && nxt<TILES)
      ((float4*)aw[pb^1])[tid]=*(((const float4*)(ws+W_AWT+((nxt*NT)/100)*144))+tid);
    f32x4 acc[4][4];
    #pragma unroll
    for(int tm=0;tm<4;tm++)
      #pragma unroll
      for(int tn=0;tn<4;tn++) acc[tm][tn]=binit[tm];
    #pragma unroll
    for(int ks=0;ks<3;ks++){
      bf8 b[4];
      #pragma unroll
      for(int tn=0;tn<4;tn++)
        b[tn]=*(const bf8*)(Xl + (tn*16+lr)*XROW + ks*32 + hi*8);
      #pragma unroll
      for(int tm=0;tm<4;tm++)
        #pragma unroll
        for(int tn=0;tn<4;tn++)
          acc[tm][tn]=__builtin_amdgcn_mfma_f32_16x16x32_bf16(w1f[tm][ks],b[tn],acc[tm][tn],0,0,0);
    }
    #pragma unroll
    for(int tm=0;tm<4;tm++)
      #pragma unroll
      for(int tn=0;tn<4;tn++)
        #pragma unroll
        for(int r=0;r<4;r++){
          float vv=fmaxf(acc[tm][tn][r],0.f);
          s[tm][r]+=vv; q[tm][r]+=vv*vv;
        }
    __syncthreads();                             // Xl reads done before next build
    pb^=1;
  }
  #pragma unroll
  for(int m=1;m<16;m<<=1)
    #pragma unroll
    for(int tm=0;tm<4;tm++)
      #pragma unroll
      for(int r=0;r<4;r++){
        s[tm][r]+=__shfl_xor(s[tm][r],m);
        q[tm][r]+=__shfl_xor(q[tm][r],m);
      }
  if(lr==0){
    #pragma unroll
    for(int tm=0;tm<4;tm++)
      #pragma unroll
      for(int r=0;r<4;r++){
        int o=mb+tm*16+hi*4+r;
        bnred[o]=s[tm][r]; bnred[256+o]=q[tm][r];
      }
  }
  __syncthreads();
  for(int e=tid;e<512;e+=256) atomicAdd(&bnsum[e],bnred[e]);
}

__global__ void k_bnparams(float* ws, const float* g, const float* b,
                           int nch, int sumoff, int scoff){
  int o=threadIdx.x;
  if(o<nch){
    float mu =ws[sumoff+o]    *(1.0f/(float)NPOS);
    float ex2=ws[sumoff+nch+o]*(1.0f/(float)NPOS);
    float var=ex2-mu*mu; if(var<0.f) var=0.f;
    float sc=g[o]*rsqrtf(var+EPSV);
    ws[scoff+o]=sc;
    ws[scoff+nch+o]=b[o]-mu*sc;
  }
}

// pass B (persistent, pipelined): build(t+1) || gemm1(t); bias in C; cvt_pk packs
__global__ __launch_bounds__(256,2) void k_gemmB(const float* __restrict__ ws,
      const float* __restrict__ conv_b, float* __restrict__ out,
      float* __restrict__ bn2sum){
  __shared__ unsigned short hT[2400], lT[2400];   // 9600 B
  __shared__ float aw[2][288];                    // 2304 B
  __shared__ unsigned short Xl[2][NT*XROW];       // 26624 B
  __shared__ unsigned short C1s[NT*C1ROW];        // 34304 B (C2s reuses this)
  __shared__ float bnred[256];                    // 1024 B
  int tid=threadIdx.x;
  int l=tid&63, w=tid>>6, lr=l&15, hi=l>>4, mb=w*64, mb2=w*32;
  stage_tables(hT,lT,ws,tid);
  const unsigned short* W1p =(const unsigned short*)(ws+W_W1P);
  const unsigned short* W2bf=(const unsigned short*)(ws+W_W2BF);
  const float* bias2=ws+W_BIAS2;
  unsigned* outu=(unsigned*)out;
  bf8 w1f[4][3];
  #pragma unroll
  for(int tm=0;tm<4;tm++)
    #pragma unroll
    for(int ks=0;ks<3;ks++)
      w1f[tm][ks]=*(const bf8*)(W1p + (mb+tm*16+lr)*96 + ks*32 + hi*8);
  bf8 w2f[2][8];
  #pragma unroll
  for(int tm2=0;tm2<2;tm2++)
    #pragma unroll
    for(int ks=0;ks<8;ks++)
      w2f[tm2][ks]=*(const bf8*)(W2bf + (mb2+tm2*16+lr)*HC + ks*32 + hi*8);
  f32x4 binit[4];
  #pragma unroll
  for(int tm=0;tm<4;tm++)
    #pragma unroll
    for(int r=0;r<4;r++) binit[tm][r]=conv_b[mb+tm*16+hi*4+r];
  f32x4 b2init[2];
  #pragma unroll
  for(int tm2=0;tm2<2;tm2++)
    #pragma unroll
    for(int r=0;r<4;r++) b2init[tm2][r]=bias2[mb2+tm2*16+hi*4+r];
  float s2[2][4], q2[2][4];
  #pragma unroll
  for(int tm2=0;tm2<2;tm2++)
    #pragma unroll
    for(int r=0;r<4;r++){ s2[tm2][r]=0.f; q2[tm2][r]=0.f; }
  // prologue
  {
    int t0=blockIdx.x;
    if(tid<72) ((float4*)aw[0])[tid]=*(((const float4*)(ws+W_AWT+((t0*NT)/100)*144))+tid);
    __syncthreads();
    build_X(Xl[0],aw[0],hT,lT,t0*NT,(t0*NT)/100,tid);
    if(tid<72 && t0+GRIDP<TILES)
      ((float4*)aw[1])[tid]=*(((const float4*)(ws+W_AWT+(((t0+GRIDP)*NT)/100)*144))+tid);
    __syncthreads();
  }

  int p=0, qb=1;
  for(int t=blockIdx.x;t<TILES;t+=GRIDP){
    int n0=t*NT, nxt=t+GRIDP, nn2=t+2*GRIDP;
    if(tid<72 && nn2<TILES)
      ((float4*)aw[qb^1])[tid]=*(((const float4*)(ws+W_AWT+((nn2*NT)/100)*144))+tid);
    if(nxt<TILES) build_X(Xl[p^1],aw[qb],hT,lT,nxt*NT,(nxt*NT)/100,tid);
    f32x4 acc[4][4];
    #pragma unroll
    for(int tm=0;tm<4;tm++)
      #pragma unroll
      for(int tn=0;tn<4;tn++) acc[tm][tn]=binit[tm];
    #pragma unroll
    for(int ks=0;ks<3;ks++){
      bf8 b[4];
      #pragma unroll
      for(int tn=0;tn<4;tn++)
        b[tn]=*(const bf8*)(Xl[p] + (tn*16+lr)*XROW + ks*32 + hi*8);
      #pragma unroll
      for(int tm=0;tm<4;tm++)
        #pragma unroll
        for(int tn=0;tn<4;tn++)
          acc[tm][tn]=__builtin_amdgcn_mfma_f32_16x16x32_bf16(w1f[tm][ks],b[tn],acc[tm][tn],0,0,0);
    }
    __syncthreads();                           // B1: build done; Xl[p] reads done
    // pack C1(t): relu + HW packed cvt
    #pragma unroll
    for(int tm=0;tm<4;tm++)
      #pragma unroll
      for(int tn=0;tn<4;tn++){
        int n=tn*16+lr, ob=mb+tm*16+hi*4;
        float v0=fmaxf(acc[tm][tn][0],0.f);
        float v1=fmaxf(acc[tm][tn][1],0.f);
        float v2=fmaxf(acc[tm][tn][2],0.f);
        float v3=fmaxf(acc[tm][tn][3],0.f);
        uint2 pv; pv.x=pkcvt(v0,v1); pv.y=pkcvt(v2,v3);
        *(uint2*)&C1s[n*C1ROW+ob]=pv;
      }
    __syncthreads();                           // B2: C1 visible
    f32x4 acc2[2][4];
    #pragma unroll
    for(int tm2=0;tm2<2;tm2++)
      #pragma unroll
      for(int tn=0;tn<4;tn++) acc2[tm2][tn]=b2init[tm2];
    #pragma unroll
    for(int ks=0;ks<8;ks++){
      bf8 b2[4];
      #pragma unroll
      for(int tn=0;tn<4;tn++)
        b2[tn]=*(const bf8*)(C1s + (tn*16+lr)*C1ROW + ks*32 + hi*8);
      #pragma unroll
      for(int tm2=0;tm2<2;tm2++)
        #pragma unroll
        for(int tn=0;tn<4;tn++)
          acc2[tm2][tn]=__builtin_amdgcn_mfma_f32_16x16x32_bf16(w2f[tm2][ks],b2[tn],acc2[tm2][tn],0,0,0);
    }
    __syncthreads();                           // B3: C1 reads done
    unsigned* C2s=(unsigned*)C1s;
    #pragma unroll
    for(int tm2=0;tm2<2;tm2++)
      #pragma unroll
      for(int tn=0;tn<4;tn++){
        float v0=fmaxf(acc2[tm2][tn][0],0.f);
        float v1=fmaxf(acc2[tm2][tn][1],0.f);
        float v2=fmaxf(acc2[tm2][tn][2],0.f);
        float v3=fmaxf(acc2[tm2][tn][3],0.f);
        s2[tm2][0]+=v0; q2[tm2][0]+=v0*v0;
        s2[tm2][1]+=v1; q2[tm2][1]+=v1*v1;
        s2[tm2][2]+=v2; q2[tm2][2]+=v2*v2;
        s2[tm2][3]+=v3; q2[tm2][3]+=v3*v3;
        int n=tn*16+lr;
        int q0=(mb2+tm2*16+hi*4)>>1;
        C2s[q0*C2PAD+n]    =pkcvt(v0,v1);
        C2s[(q0+1)*C2PAD+n]=pkcvt(v2,v3);
      }
    __syncthreads();                           // B4: C2s ready
    #pragma unroll
    for(int p16=0;p16<4;p16++){
      int row=p16*16+(tid>>4), chunk=tid&15;
      u32x4 v=*(const u32x4*)&C2s[row*C2PAD+chunk*4];
      *(u32x4*)(outu + (size_t)(2*row)*NPOS + n0 + chunk*4) = v;
    }
    p^=1; qb^=1;
  }
  #pragma unroll
  for(int m=1;m<16;m<<=1)
    #pragma unroll
    for(int tm2=0;tm2<2;tm2++)
      #pragma unroll
      for(int r=0;r<4;r++){
        s2[tm2][r]+=__shfl_xor(s2[tm2][r],m);
        q2[tm2][r]+=__shfl_xor(q2[tm2][r],m);
      }
  if(lr==0){
    #pragma unroll
    for(int tm2=0;tm2<2;tm2++)
      #pragma unroll
      for(int r=0;r<4;r++){
        int o=mb2+tm2*16+hi*4+r;
        bnred[o]=s2[tm2][r]; bnred[128+o]=q2[tm2][r];
      }
  }
  __syncthreads();
  if(tid<256) atomicAdd(&bn2sum[tid],bnred[tid]);
}

// pass C: read bf16 pair u32 from even row, expand+affine, write f32 even+odd rows
__global__ void k_passC(float* __restrict__ out, const float* __restrict__ ws){
  const int NQ4=NPOS/4;
  int idx=blockIdx.x*256+threadIdx.x;
  int stride=gridDim.x*256;
  unsigned* outu=(unsigned*)out;
  for(int e=idx;e<64*NQ4;e+=stride){
    int qq=e/NQ4, nb=(e-qq*NQ4)*4;
    size_t base=(size_t)(2*qq)*NPOS + nb;
    u32x4 v=__builtin_nontemporal_load((const u32x4*)(outu+base));
    float sc0=ws[W_SC2+2*qq],   sh0=ws[W_SC2+H2C+2*qq];
    float sc1=ws[W_SC2+2*qq+1], sh1=ws[W_SC2+H2C+2*qq+1];
    f32x4 o0,o1;
    o0.x=bf2f((unsigned short)(v.x&0xffff))*sc0+sh0;
    o1.x=bf2f((unsigned short)(v.x>>16))  *sc1+sh1;
    o0.y=bf2f((unsigned short)(v.y&0xffff))*sc0+sh0;
    o1.y=bf2f((unsigned short)(v.y>>16))  *sc1+sh1;
    o0.z=bf2f((unsigned short)(v.z&0xffff))*sc0+sh0;
    o1.z=bf2f((unsigned short)(v.z>>16))  *sc1+sh1;
    o0.w=bf2f((unsigned short)(v.w&0xffff))*sc0+sh0;
    o1.w=bf2f((unsigned short)(v.w>>16))  *sc1+sh1;
    __builtin_nontemporal_store(o0,(f32x4*)(out+base));
    __builtin_nontemporal_store(o1,(f32x4*)(out+base+NPOS));
  }
}

extern "C" void kernel_launch(void* const* d_in, const int* in_sizes, int n_in,
                              void* d_out, int out_size, void* d_ws, size_t ws_size,
                              hipStream_t stream){
  const float* z0     =(const float*)d_in[0];
  const float* z1     =(const float*)d_in[1];
  const float* we1    =(const float*)d_in[2];
  const float* we2    =(const float*)d_in[3];
  const float* we3    =(const float*)d_in[4];
  const float* we4    =(const float*)d_in[5];
  const float* we5    =(const float*)d_in[6];
  const float* conv_w =(const float*)d_in[7];
  const float* conv_b =(const float*)d_in[8];
  const float* bn_g   =(const float*)d_in[9];
  const float* bn_b   =(const float*)d_in[10];
  const float* conv2_w=(const float*)d_in[11];
  const float* conv2_b=(const float*)d_in[12];
  const float* bn2_g  =(const float*)d_in[13];
  const float* bn2_b  =(const float*)d_in[14];
  const int* cdrH=(const int*)d_in[15];
  const int* cdrL=(const int*)d_in[16];
  const int* notH=(const int*)d_in[17];
  const int* notL=(const int*)d_in[18];
  int nCdrH=in_sizes[15], nCdrL=in_sizes[16], nNotH=in_sizes[17], nNotL=in_sizes[18];
  float* ws=(float*)d_ws;
  float* out=(float*)d_out;

  hipLaunchKernelGGL(k_prepmeans,dim3(96+DD),dim3(256),0,stream, conv_w,z0,z1,cdrH,notH,cdrL,notL,
                     nCdrH,nNotH,nCdrL,nNotL,ws);
  hipLaunchKernelGGL(k_scales,   dim3(1),    dim3(256),0,stream, we1,we2,we3,we4,we5,ws);
  hipLaunchKernelGGL(k_aw,       dim3((LL0*48+255)/256), dim3(256),0,stream, z0,ws);
  hipLaunchKernelGGL(k_gemmA,    dim3(GRIDP),dim3(256),0,stream, ws,conv_b, ws+W_BN1S);
  hipLaunchKernelGGL(k_bnparams, dim3(1),    dim3(256),0,stream, ws,bn_g,bn_b, HC, W_BN1S, W_SC1);
  hipLaunchKernelGGL(k_prep2,    dim3(H2C),  dim3(256),0,stream, conv2_w,conv2_b,ws);
  hipLaunchKernelGGL(k_gemmB,    dim3(GRIDP),dim3(256),0,stream, ws,conv_b, out, ws+W_BN2S);
  hipLaunchKernelGGL(k_bnparams, dim3(1),    dim3(256),0,stream, ws,bn2_g,bn2_b, H2C, W_BN2S, W_SC2);
  hipLaunchKernelGGL(k_passC,    dim3(2048), dim3(256),0,stream, out, ws);
}

// Round 14
// 210.347 us; speedup vs baseline: 1.5285x; 1.0181x over previous
//
#include <hip/hip_runtime.h>
#include <math.h>

#define DD   46
#define LL0  4000
#define LL1  600
#define CATV 250
#define NC   50
#define NJ   100
#define HC   256
#define H2C  128
#define NPOS (LL0*NJ)
#define EPSV 1e-5f
#define NT   64
#define XROW 104
#define C1ROW 268
#define C2PAD 68
#define TILES (NPOS/NT)   // 6250
#define GROUPS (TILES/2)  // 3125
#define GRIDP 512

// ---- workspace float offsets ----
#define W_MEAN0   0
#define W_MEANH   64
#define W_MEANL   128
#define W_RM4     192
#define W_RM5     256
#define W_S1      320
#define W_HBAR    384
#define W_RAWMH   448
#define W_RAWML   2752
#define W_H       5056
#define W_L       7360
#define W_BN1S    9664            // 256 sum + 256 sumsq
#define W_SC1     10176           // (unused now)
#define W_BN2S    10688           // 128+128
#define W_SC2     10944           // (unused now)
#define W_HBF     11200           // 2400 ushort [j][48]
#define W_LBF     12400           // 2400 ushort
#define W_AWT     13632           // [4001][144] f32
#define W_W1P     589776          // 256*96 bf16
#define W_W2BF    602064          // 128*256 bf16
#define W_BIAS2   618448          // 128 floats

typedef __attribute__((ext_vector_type(8))) short bf8;
typedef __attribute__((ext_vector_type(4))) float f32x4;
typedef __attribute__((ext_vector_type(4))) unsigned u32x4;

__device__ __forceinline__ float sigf(float x){ return 1.0f/(1.0f+__expf(-x)); }

__device__ __forceinline__ unsigned short f2bf(float f){
  unsigned u = __float_as_uint(f);
  return (unsigned short)((u + 0x7FFFu + ((u>>16)&1u)) >> 16);
}
// HW packed f32->bf16 (RTNE): lo=a, hi=b
__device__ __forceinline__ unsigned pkcvt(float a, float b){
  unsigned r;
  asm("v_cvt_pk_bf16_f32 %0, %1, %2" : "=v"(r) : "v"(a), "v"(b));
  return r;
}
__device__ __forceinline__ float bf2f(unsigned short h){
  return __uint_as_float(((unsigned)h)<<16);
}

__device__ float blockReduceSum(float v, float* sm){
  int tid=threadIdx.x;
  sm[tid]=v; __syncthreads();
  for(int s=128;s>0;s>>=1){ if(tid<s) sm[tid]+=sm[tid+s]; __syncthreads(); }
  float r=sm[0]; __syncthreads();
  return r;
}

// fused: blocks 0..95 -> W1 bf16 permute (+stat zero); blocks 96..141 -> means
__global__ void k_prepmeans(const float* __restrict__ conv_w,
                            const float* __restrict__ z0, const float* __restrict__ z1,
                            const int* cdrH, const int* notH,
                            const int* cdrL, const int* notL,
                            int nCdrH,int nNotH,int nCdrL,int nNotL, float* ws){
  __shared__ float v[LL1];
  __shared__ float sm[256];
  int tid=threadIdx.x;
  if(blockIdx.x<96){
    int t=blockIdx.x*256+tid;
    if(blockIdx.x==0){ for(int e=tid;e<1536;e+=256) ws[W_BN1S+e]=0.f; }
    if(t<HC*96){
      int o=t/96, c=t-o*96;
      unsigned short vv=0;
      if(c<92){ int d=c>>1, p=c&1; vv=f2bf(conv_w[o*92 + (p? 46+d : d)]); }
      ((unsigned short*)(ws+W_W1P))[t]=vv;
    }
    return;
  }
  int d=blockIdx.x-96;
  float s0=0.f; for(int i=tid;i<LL0;i+=256) s0+=z0[i*DD+d];
  for(int k=tid;k<LL1;k+=256) v[k]=z1[k*DD+d];
  float r0=blockReduceSum(s0,sm);
  __syncthreads();
  float sH=0.f; for(int k=tid;k<CATV;k+=256) sH+=v[k];
  float sL=0.f; for(int k=CATV+tid;k<LL1;k+=256) sL+=v[k];
  float rH=blockReduceSum(sH,sm);
  float rL=blockReduceSum(sL,sm);
  float partH=0.f, partL=0.f;
  for(int i=tid;i<nCdrH;i+=256){
    float c=v[cdrH[i]]; float s=0.f;
    for(int j=0;j<nNotH;j++) s+=fabsf(c-v[notH[j]]);
    s/= (float)nNotH;
    ws[W_RAWMH+d*NC+i]=s; partH+=s;
  }
  for(int i=tid;i<nCdrL;i+=256){
    float c=v[CATV+cdrL[i]]; float s=0.f;
    for(int j=0;j<nNotL;j++) s+=fabsf(c-v[CATV+notL[j]]);
    s/= (float)nNotL;
    ws[W_RAWML+d*NC+i]=s; partL+=s;
  }
  float pH=blockReduceSum(partH,sm);
  float pL=blockReduceSum(partL,sm);
  if(tid==0){
    ws[W_MEAN0+d]=r0/(float)LL0;
    ws[W_MEANH+d]=rH/(float)CATV;
    ws[W_MEANL+d]=rL/(float)(LL1-CATV);
    ws[W_RM4+d]=pH/(float)nCdrH;
    ws[W_RM5+d]=pL/(float)nCdrL;
  }
}

// W2' = W2*sc1 (bf16), bias2' = b2 + sum_k W2[o2,k]*sh1[k]; sc1/sh1 computed inline
__global__ void k_prep2(const float* __restrict__ conv2_w, const float* __restrict__ conv2_b,
                        const float* __restrict__ g1, const float* __restrict__ b1,
                        float* __restrict__ ws){
  __shared__ float sm[256];
  int o2=blockIdx.x, t=threadIdx.x;
  float mu =ws[W_BN1S+t]    *(1.0f/(float)NPOS);
  float ex2=ws[W_BN1S+256+t]*(1.0f/(float)NPOS);
  float var=ex2-mu*mu; if(var<0.f) var=0.f;
  float sc=g1[t]*rsqrtf(var+EPSV);
  float sh=b1[t]-mu*sc;
  float wv=conv2_w[o2*HC+t];
  ((unsigned short*)(ws+W_W2BF))[o2*HC+t]=f2bf(wv*sc);
  float r=blockReduceSum(wv*sh,sm);
  if(t==0) ws[W_BIAS2+o2]=conv2_b[o2]+r;
}

__device__ __forceinline__ float conv3(const float* a, int d, const float* w){
  float acc = w[1]*a[d];
  if(d>0)    acc += w[0]*a[d-1];
  if(d<DD-1) acc += w[2]*a[d+1];
  return acc;
}

// scales + final h, l, hbar + bf16 table copies [j][48]
__global__ void k_scales(const float* w1,const float* w2,const float* w3,
                         const float* w4,const float* w5, float* ws){
  __shared__ float m0[DD], mH[DD], mL[DD];
  __shared__ float s1s[DD],s2s[DD],s3s[DD],s4s[DD],s5s[DD],y4[DD],y5[DD];
  int tid=threadIdx.x;
  if(tid<DD){ m0[tid]=ws[W_MEAN0+tid]; mH[tid]=ws[W_MEANH+tid]; mL[tid]=ws[W_MEANL+tid]; }
  __syncthreads();
  if(tid<DD){
    s1s[tid]=sigf(conv3(m0,tid,w1));
    s2s[tid]=sigf(conv3(mH,tid,w2));
    s3s[tid]=sigf(conv3(mL,tid,w3));
  }
  __syncthreads();
  if(tid<DD){ y4[tid]=s2s[tid]*ws[W_RM4+tid]; y5[tid]=s3s[tid]*ws[W_RM5+tid]; }
  __syncthreads();
  if(tid<DD){
    s4s[tid]=sigf(conv3(y4,tid,w4));
    s5s[tid]=sigf(conv3(y5,tid,w5));
    ws[W_S1+tid]=s1s[tid];
  }
  __syncthreads();
  for(int e=tid;e<DD*NC;e+=256){
    int d=e/NC;
    ws[W_H+e]=s4s[d]*s2s[d]*ws[W_RAWMH+e];
    ws[W_L+e]=s5s[d]*s3s[d]*ws[W_RAWML+e];
  }
  __syncthreads();
  if(tid<DD){
    float s=0.f;
    for(int j=0;j<NC;j++) s+=ws[W_H+tid*NC+j];
    ws[W_HBAR+tid]=s/(float)NC;
  }
  __syncthreads();
  for(int e=tid;e<2400;e+=256){
    int j=e/48, d=e-48*j;
    unsigned short hv=0, lv=0;
    if(d<DD){ hv=f2bf(ws[W_H+d*NC+j]); lv=f2bf(ws[W_L+d*NC+j]); }
    ((unsigned short*)(ws+W_HBF))[e]=hv;
    ((unsigned short*)(ws+W_LBF))[e]=lv;
  }
}

// AWt[i][144] = { a0[48] | dif[48] | mul[48] }
__global__ void k_aw(const float* __restrict__ z0, float* __restrict__ ws){
  int e=blockIdx.x*256+threadIdx.x;
  if(e>=LL0*48) return;
  int i=e/48, d=e-48*i;
  float a=0.f, df=0.f, ml=0.f;
  if(d<DD){
    a = ws[W_S1+d]*z0[i*DD+d];
    float s=0.f;
    #pragma unroll 10
    for(int j=0;j<NC;j++) s+=fabsf(a-ws[W_H+d*NC+j]);
    df = s*(1.0f/(float)NC);
    ml = a*ws[W_HBAR+d];
  }
  ws[W_AWT + i*144 + d]      = a;
  ws[W_AWT + i*144 + 48 + d] = df;
  ws[W_AWT + i*144 + 96 + d] = ml;
}

// stage bf16 h/l tables into LDS via 16B vectors
__device__ __forceinline__ void stage_tables(unsigned short* hT, unsigned short* lT,
                                             const float* __restrict__ ws, int tid){
  for(int e=tid;e<300;e+=256){
    ((u32x4*)hT)[e]=((const u32x4*)(ws+W_HBF))[e];
    ((u32x4*)lT)[e]=((const u32x4*)(ws+W_LBF))[e];
  }
}

// build X tile (bf16, interleaved c=2d+p); HW packed cvt
__device__ __forceinline__ void build_X(unsigned short* Xl, const float* aw,
                                        const unsigned short* hT, const unsigned short* lT,
                                        int n0, int i0, int tid){
  int ibase=i0*100, ib1=ibase+100;
  for(int e=tid;e<NT*12;e+=256){
    int n=e/12, g=e-12*n, d4=g*4;
    int ncol=n0+n;
    int ii=(ncol>=ib1)?1:0;
    int j=ncol-ibase-ii*100;
    const float* ar=aw+ii*144;
    float x10,x11,x12,x13, x20,x21,x22,x23;
    if(j<NC){
      float4 a=*(const float4*)(ar+d4);
      ushort4 hb=*(const ushort4*)(hT+j*48+d4);
      float h0=bf2f(hb.x),h1=bf2f(hb.y),h2=bf2f(hb.z),h3=bf2f(hb.w);
      x10=fabsf(a.x-h0); x20=a.x*h0;
      x11=fabsf(a.y-h1); x21=a.y*h1;
      x12=fabsf(a.z-h2); x22=a.z*h2;
      x13=fabsf(a.w-h3); x23=a.w*h3;
    }else{
      float4 df=*(const float4*)(ar+48+d4);
      float4 ml=*(const float4*)(ar+96+d4);
      ushort4 lb=*(const ushort4*)(lT+(j-NC)*48+d4);
      float l0=bf2f(lb.x),l1=bf2f(lb.y),l2=bf2f(lb.z),l3=bf2f(lb.w);
      x10=fabsf(df.x-l0); x20=fabsf(ml.x-l0);
      x11=fabsf(df.y-l1); x21=fabsf(ml.y-l1);
      x12=fabsf(df.z-l2); x22=fabsf(ml.z-l2);
      x13=fabsf(df.w-l3); x23=fabsf(ml.w-l3);
    }
    u32x4 pv;
    pv.x=pkcvt(x10,x20); pv.y=pkcvt(x11,x21); pv.z=pkcvt(x12,x22); pv.w=pkcvt(x13,x23);
    *(u32x4*)(Xl + n*XROW + 8*g) = pv;
  }
}

// pass A (persistent, group-of-2): build both tiles -> B1 -> gemm both + stats -> B2
__global__ __launch_bounds__(256,2) void k_gemmA(const float* __restrict__ ws,
                                                 const float* __restrict__ conv_b,
                                                 float* __restrict__ bnsum){
  __shared__ unsigned short hT[2400], lT[2400];
  __shared__ float aw[2][576];
  __shared__ unsigned short Xl[2][NT*XROW];
  __shared__ float bnred[512];
  int tid=threadIdx.x;
  int l=tid&63, w=tid>>6, lr=l&15, hi=l>>4, mb=w*64;
  stage_tables(hT,lT,ws,tid);
  const unsigned short* W1p=(const unsigned short*)(ws+W_W1P);
  bf8 w1f[4][3];
  #pragma unroll
  for(int tm=0;tm<4;tm++)
    #pragma unroll
    for(int ks=0;ks<3;ks++)
      w1f[tm][ks]=*(const bf8*)(W1p + (mb+tm*16+lr)*96 + ks*32 + hi*8);
  f32x4 binit[4];
  #pragma unroll
  for(int tm=0;tm<4;tm++)
    #pragma unroll
    for(int r=0;r<4;r++) binit[tm][r]=conv_b[mb+tm*16+hi*4+r];
  float s[4][4], q[4][4];
  #pragma unroll
  for(int tm=0;tm<4;tm++)
    #pragma unroll
    for(int r=0;r<4;r++){ s[tm][r]=0.f; q[tm][r]=0.f; }
  // prologue aw load for group g0 (both tiles)
  if(tid<144){
    int tl=tid/72, off=tid-72*tl;
    int n0=(blockIdx.x*2+tl)*NT;
    ((float4*)aw[0])[tid]=*(((const float4*)(ws+W_AWT+(n0/100)*144))+off);
  }
  __syncthreads();

  int pb=0;
  for(int g=blockIdx.x;g<GROUPS;g+=GRIDP){
    int n0=g*2*NT;
    build_X(Xl[0],aw[pb],     hT,lT,n0,    n0/100,     tid);
    build_X(Xl[1],aw[pb]+288, hT,lT,n0+NT,(n0+NT)/100, tid);
    __syncthreads();                             // B1: X ready; aw consumed
    int nxt=g+GRIDP;
    if(tid<144 && nxt<GROUPS){
      int tl=tid/72, off=tid-72*tl;
      int nn=(nxt*2+tl)*NT;
      ((float4*)aw[pb^1])[tid]=*(((const float4*)(ws+W_AWT+(nn/100)*144))+off);
    }
    #pragma unroll
    for(int sub=0;sub<2;sub++){
      f32x4 acc[4][4];
      #pragma unroll
      for(int tm=0;tm<4;tm++)
        #pragma unroll
        for(int tn=0;tn<4;tn++) acc[tm][tn]=binit[tm];
      #pragma unroll
      for(int ks=0;ks<3;ks++){
        bf8 b[4];
        #pragma unroll
        for(int tn=0;tn<4;tn++)
          b[tn]=*(const bf8*)(Xl[sub] + (tn*16+lr)*XROW + ks*32 + hi*8);
        #pragma unroll
        for(int tm=0;tm<4;tm++)
          #pragma unroll
          for(int tn=0;tn<4;tn++)
            acc[tm][tn]=__builtin_amdgcn_mfma_f32_16x16x32_bf16(w1f[tm][ks],b[tn],acc[tm][tn],0,0,0);
      }
      #pragma unroll
      for(int tm=0;tm<4;tm++)
        #pragma unroll
        for(int tn=0;tn<4;tn++)
          #pragma unroll
          for(int r=0;r<4;r++){
            float vv=fmaxf(acc[tm][tn][r],0.f);
            s[tm][r]+=vv; q[tm][r]+=vv*vv;
          }
    }
    __syncthreads();                             // B2: Xl reads done
    pb^=1;
  }
  #pragma unroll
  for(int m=1;m<16;m<<=1)
    #pragma unroll
    for(int tm=0;tm<4;tm++)
      #pragma unroll
      for(int r=0;r<4;r++){
        s[tm][r]+=__shfl_xor(s[tm][r],m);
        q[tm][r]+=__shfl_xor(q[tm][r],m);
      }
  if(lr==0){
    #pragma unroll
    for(int tm=0;tm<4;tm++)
      #pragma unroll
      for(int r=0;r<4;r++){
        int o=mb+tm*16+hi*4+r;
        bnred[o]=s[tm][r]; bnred[256+o]=q[tm][r];
      }
  }
  __syncthreads();
  for(int e=tid;e<512;e+=256) atomicAdd(&bnsum[e],bnred[e]);
}

// pass B (persistent, r13-proven): build(t+1) || gemm1(t); bias in C; cvt_pk packs
__global__ __launch_bounds__(256,2) void k_gemmB(const float* __restrict__ ws,
      const float* __restrict__ conv_b, float* __restrict__ out,
      float* __restrict__ bn2sum){
  __shared__ unsigned short hT[2400], lT[2400];   // 9600 B
  __shared__ float aw[2][288];                    // 2304 B
  __shared__ unsigned short Xl[2][NT*XROW];       // 26624 B
  __shared__ unsigned short C1s[NT*C1ROW];        // 34304 B (C2s reuses this)
  __shared__ float bnred[256];                    // 1024 B
  int tid=threadIdx.x;
  int l=tid&63, w=tid>>6, lr=l&15, hi=l>>4, mb=w*64, mb2=w*32;
  stage_tables(hT,lT,ws,tid);
  const unsigned short* W1p =(const unsigned short*)(ws+W_W1P);
  const unsigned short* W2bf=(const unsigned short*)(ws+W_W2BF);
  const float* bias2=ws+W_BIAS2;
  unsigned* outu=(unsigned*)out;
  bf8 w1f[4][3];
  #pragma unroll
  for(int tm=0;tm<4;tm++)
    #pragma unroll
    for(int ks=0;ks<3;ks++)
      w1f[tm][ks]=*(const bf8*)(W1p + (mb+tm*16+lr)*96 + ks*32 + hi*8);
  bf8 w2f[2][8];
  #pragma unroll
  for(int tm2=0;tm2<2;tm2++)
    #pragma unroll
    for(int ks=0;ks<8;ks++)
      w2f[tm2][ks]=*(const bf8*)(W2bf + (mb2+tm2*16+lr)*HC + ks*32 + hi*8);
  f32x4 binit[4];
  #pragma unroll
  for(int tm=0;tm<4;tm++)
    #pragma unroll
    for(int r=0;r<4;r++) binit[tm][r]=conv_b[mb+tm*16+hi*4+r];
  f32x4 b2init[2];
  #pragma unroll
  for(int tm2=0;tm2<2;tm2++)
    #pragma unroll
    for(int r=0;r<4;r++) b2init[tm2][r]=bias2[mb2+tm2*16+hi*4+r];
  float s2[2][4], q2[2][4];
  #pragma unroll
  for(int tm2=0;tm2<2;tm2++)
    #pragma unroll
    for(int r=0;r<4;r++){ s2[tm2][r]=0.f; q2[tm2][r]=0.f; }
  // prologue
  {
    int t0=blockIdx.x;
    if(tid<72) ((float4*)aw[0])[tid]=*(((const float4*)(ws+W_AWT+((t0*NT)/100)*144))+tid);
    __syncthreads();
    build_X(Xl[0],aw[0],hT,lT,t0*NT,(t0*NT)/100,tid);
    if(tid<72 && t0+GRIDP<TILES)
      ((float4*)aw[1])[tid]=*(((const float4*)(ws+W_AWT+(((t0+GRIDP)*NT)/100)*144))+tid);
    __syncthreads();
  }

  int p=0, qb=1;
  for(int t=blockIdx.x;t<TILES;t+=GRIDP){
    int n0=t*NT, nxt=t+GRIDP, nn2=t+2*GRIDP;
    if(tid<72 && nn2<TILES)
      ((float4*)aw[qb^1])[tid]=*(((const float4*)(ws+W_AWT+((nn2*NT)/100)*144))+tid);
    if(nxt<TILES) build_X(Xl[p^1],aw[qb],hT,lT,nxt*NT,(nxt*NT)/100,tid);
    f32x4 acc[4][4];
    #pragma unroll
    for(int tm=0;tm<4;tm++)
      #pragma unroll
      for(int tn=0;tn<4;tn++) acc[tm][tn]=binit[tm];
    #pragma unroll
    for(int ks=0;ks<3;ks++){
      bf8 b[4];
      #pragma unroll
      for(int tn=0;tn<4;tn++)
        b[tn]=*(const bf8*)(Xl[p] + (tn*16+lr)*XROW + ks*32 + hi*8);
      #pragma unroll
      for(int tm=0;tm<4;tm++)
        #pragma unroll
        for(int tn=0;tn<4;tn++)
          acc[tm][tn]=__builtin_amdgcn_mfma_f32_16x16x32_bf16(w1f[tm][ks],b[tn],acc[tm][tn],0,0,0);
    }
    __syncthreads();                           // B1: build done; Xl[p] reads done
    #pragma unroll
    for(int tm=0;tm<4;tm++)
      #pragma unroll
      for(int tn=0;tn<4;tn++){
        int n=tn*16+lr, ob=mb+tm*16+hi*4;
        float v0=fmaxf(acc[tm][tn][0],0.f);
        float v1=fmaxf(acc[tm][tn][1],0.f);
        float v2=fmaxf(acc[tm][tn][2],0.f);
        float v3=fmaxf(acc[tm][tn][3],0.f);
        uint2 pv; pv.x=pkcvt(v0,v1); pv.y=pkcvt(v2,v3);
        *(uint2*)&C1s[n*C1ROW+ob]=pv;
      }
    __syncthreads();                           // B2: C1 visible
    f32x4 acc2[2][4];
    #pragma unroll
    for(int tm2=0;tm2<2;tm2++)
      #pragma unroll
      for(int tn=0;tn<4;tn++) acc2[tm2][tn]=b2init[tm2];
    #pragma unroll
    for(int ks=0;ks<8;ks++){
      bf8 b2[4];
      #pragma unroll
      for(int tn=0;tn<4;tn++)
        b2[tn]=*(const bf8*)(C1s + (tn*16+lr)*C1ROW + ks*32 + hi*8);
      #pragma unroll
      for(int tm2=0;tm2<2;tm2++)
        #pragma unroll
        for(int tn=0;tn<4;tn++)
          acc2[tm2][tn]=__builtin_amdgcn_mfma_f32_16x16x32_bf16(w2f[tm2][ks],b2[tn],acc2[tm2][tn],0,0,0);
    }
    __syncthreads();                           // B3: C1 reads done
    unsigned* C2s=(unsigned*)C1s;
    #pragma unroll
    for(int tm2=0;tm2<2;tm2++)
      #pragma unroll
      for(int tn=0;tn<4;tn++){
        float v0=fmaxf(acc2[tm2][tn][0],0.f);
        float v1=fmaxf(acc2[tm2][tn][1],0.f);
        float v2=fmaxf(acc2[tm2][tn][2],0.f);
        float v3=fmaxf(acc2[tm2][tn][3],0.f);
        s2[tm2][0]+=v0; q2[tm2][0]+=v0*v0;
        s2[tm2][1]+=v1; q2[tm2][1]+=v1*v1;
        s2[tm2][2]+=v2; q2[tm2][2]+=v2*v2;
        s2[tm2][3]+=v3; q2[tm2][3]+=v3*v3;
        int n=tn*16+lr;
        int q0=(mb2+tm2*16+hi*4)>>1;
        C2s[q0*C2PAD+n]    =pkcvt(v0,v1);
        C2s[(q0+1)*C2PAD+n]=pkcvt(v2,v3);
      }
    __syncthreads();                           // B4: C2s ready
    #pragma unroll
    for(int p16=0;p16<4;p16++){
      int row=p16*16+(tid>>4), chunk=tid&15;
      u32x4 v=*(const u32x4*)&C2s[row*C2PAD+chunk*4];
      *(u32x4*)(outu + (size_t)(2*row)*NPOS + n0 + chunk*4) = v;
    }
    p^=1; qb^=1;
  }
  #pragma unroll
  for(int m=1;m<16;m<<=1)
    #pragma unroll
    for(int tm2=0;tm2<2;tm2++)
      #pragma unroll
      for(int r=0;r<4;r++){
        s2[tm2][r]+=__shfl_xor(s2[tm2][r],m);
        q2[tm2][r]+=__shfl_xor(q2[tm2][r],m);
      }
  if(lr==0){
    #pragma unroll
    for(int tm2=0;tm2<2;tm2++)
      #pragma unroll
      for(int r=0;r<4;r++){
        int o=mb2+tm2*16+hi*4+r;
        bnred[o]=s2[tm2][r]; bnred[128+o]=q2[tm2][r];
      }
  }
  __syncthreads();
  if(tid<256) atomicAdd(&bn2sum[tid],bnred[tid]);
}

// pass C: bf16 pair u32 from even row -> BN2 affine (params inline) -> f32 even+odd
__global__ void k_passC(float* __restrict__ out, const float* __restrict__ ws,
                        const float* __restrict__ g2, const float* __restrict__ b2){
  const int NQ4=NPOS/4;
  const float inv=1.0f/(float)NPOS;
  int idx=blockIdx.x*256+threadIdx.x;
  int stride=gridDim.x*256;
  unsigned* outu=(unsigned*)out;
  for(int e=idx;e<64*NQ4;e+=stride){
    int qq=e/NQ4, nb=(e-qq*NQ4)*4;
    size_t base=(size_t)(2*qq)*NPOS + nb;
    u32x4 v=__builtin_nontemporal_load((const u32x4*)(outu+base));
    float mu0=ws[W_BN2S+2*qq]*inv,   ex0=ws[W_BN2S+H2C+2*qq]*inv;
    float mu1=ws[W_BN2S+2*qq+1]*inv, ex1=ws[W_BN2S+H2C+2*qq+1]*inv;
    float var0=ex0-mu0*mu0; if(var0<0.f) var0=0.f;
    float var1=ex1-mu1*mu1; if(var1<0.f) var1=0.f;
    float sc0=g2[2*qq]*rsqrtf(var0+EPSV),   sh0=b2[2*qq]-mu0*sc0;
    float sc1=g2[2*qq+1]*rsqrtf(var1+EPSV), sh1=b2[2*qq+1]-mu1*sc1;
    f32x4 o0,o1;
    o0.x=bf2f((unsigned short)(v.x&0xffff))*sc0+sh0;
    o1.x=bf2f((unsigned short)(v.x>>16))  *sc1+sh1;
    o0.y=bf2f((unsigned short)(v.y&0xffff))*sc0+sh0;
    o1.y=bf2f((unsigned short)(v.y>>16))  *sc1+sh1;
    o0.z=bf2f((unsigned short)(v.z&0xffff))*sc0+sh0;
    o1.z=bf2f((unsigned short)(v.z>>16))  *sc1+sh1;
    o0.w=bf2f((unsigned short)(v.w&0xffff))*sc0+sh0;
    o1.w=bf2f((unsigned short)(v.w>>16))  *sc1+sh1;
    __builtin_nontemporal_store(o0,(f32x4*)(out+base));
    __builtin_nontemporal_store(o1,(f32x4*)(out+base+NPOS));
  }
}

extern "C" void kernel_launch(void* const* d_in, const int* in_sizes, int n_in,
                              void* d_out, int out_size, void* d_ws, size_t ws_size,
                              hipStream_t stream){
  const float* z0     =(const float*)d_in[0];
  const float* z1     =(const float*)d_in[1];
  const float* we1    =(const float*)d_in[2];
  const float* we2    =(const float*)d_in[3];
  const float* we3    =(const float*)d_in[4];
  const float* we4    =(const float*)d_in[5];
  const float* we5    =(const float*)d_in[6];
  const float* conv_w =(const float*)d_in[7];
  const float* conv_b =(const float*)d_in[8];
  const float* bn_g   =(const float*)d_in[9];
  const float* bn_b   =(const float*)d_in[10];
  const float* conv2_w=(const float*)d_in[11];
  const float* conv2_b=(const float*)d_in[12];
  const float* bn2_g  =(const float*)d_in[13];
  const float* bn2_b  =(const float*)d_in[14];
  const int* cdrH=(const int*)d_in[15];
  const int* cdrL=(const int*)d_in[16];
  const int* notH=(const int*)d_in[17];
  const int* notL=(const int*)d_in[18];
  int nCdrH=in_sizes[15], nCdrL=in_sizes[16], nNotH=in_sizes[17], nNotL=in_sizes[18];
  float* ws=(float*)d_ws;
  float* out=(float*)d_out;

  hipLaunchKernelGGL(k_prepmeans,dim3(96+DD),dim3(256),0,stream, conv_w,z0,z1,cdrH,notH,cdrL,notL,
                     nCdrH,nNotH,nCdrL,nNotL,ws);
  hipLaunchKernelGGL(k_scales,   dim3(1),    dim3(256),0,stream, we1,we2,we3,we4,we5,ws);
  hipLaunchKernelGGL(k_aw,       dim3((LL0*48+255)/256), dim3(256),0,stream, z0,ws);
  hipLaunchKernelGGL(k_gemmA,    dim3(GRIDP),dim3(256),0,stream, ws,conv_b, ws+W_BN1S);
  hipLaunchKernelGGL(k_prep2,    dim3(H2C),  dim3(256),0,stream, conv2_w,conv2_b,bn_g,bn_b,ws);
  hipLaunchKernelGGL(k_gemmB,    dim3(GRIDP),dim3(256),0,stream, ws,conv_b, out, ws+W_BN2S);
  hipLaunchKernelGGL(k_passC,    dim3(2048), dim3(256),0,stream, out, ws, bn2_g, bn2_b);
}

// Round 15
// 207.827 us; speedup vs baseline: 1.5471x; 1.0121x over previous
//
#include <hip/hip_runtime.h>
#include <math.h>

#define DD   46
#define LL0  4000
#define LL1  600
#define CATV 250
#define NC   50
#define NJ   100
#define HC   256
#define H2C  128
#define NPOS (LL0*NJ)
#define EPSV 1e-5f
#define NT   64
#define XROW 104
#define C1ROW 268
#define C2PAD 68
#define TILES (NPOS/NT)   // 6250
#define GROUPS (TILES/2)  // 3125
#define GRIDP 512

// ---- workspace float offsets ----
#define W_MEAN0   0
#define W_MEANH   64
#define W_MEANL   128
#define W_RM4     192
#define W_RM5     256
#define W_S1      320
#define W_HBAR    384
#define W_RAWMH   448
#define W_RAWML   2752
#define W_H       5056
#define W_L       7360
#define W_BN1S    9664            // 256 sum + 256 sumsq
#define W_BN2S    10688           // 128+128
#define W_HBF     11200           // 2400 ushort [j][48]
#define W_LBF     12400           // 2400 ushort
#define W_AWT     13632           // [4001][144] f32
#define W_W1P     589776          // 256*96 bf16
#define W_W2BF    602064          // 128*256 bf16
#define W_BIAS2   618448          // 128 floats

typedef __attribute__((ext_vector_type(8))) short bf8;
typedef __attribute__((ext_vector_type(4))) float f32x4;
typedef __attribute__((ext_vector_type(4))) unsigned u32x4;

__device__ __forceinline__ float sigf(float x){ return 1.0f/(1.0f+__expf(-x)); }

__device__ __forceinline__ unsigned short f2bf(float f){
  unsigned u = __float_as_uint(f);
  return (unsigned short)((u + 0x7FFFu + ((u>>16)&1u)) >> 16);
}
// HW packed f32->bf16 (RTNE): lo=a, hi=b
__device__ __forceinline__ unsigned pkcvt(float a, float b){
  unsigned r;
  asm("v_cvt_pk_bf16_f32 %0, %1, %2" : "=v"(r) : "v"(a), "v"(b));
  return r;
}
__device__ __forceinline__ float bf2f(unsigned short h){
  return __uint_as_float(((unsigned)h)<<16);
}

__device__ float blockReduceSum(float v, float* sm){
  int tid=threadIdx.x;
  sm[tid]=v; __syncthreads();
  for(int s=128;s>0;s>>=1){ if(tid<s) sm[tid]+=sm[tid+s]; __syncthreads(); }
  float r=sm[0]; __syncthreads();
  return r;
}

// fused: blocks 0..95 -> W1 bf16 permute (+stat zero); blocks 96..141 -> means
__global__ void k_prepmeans(const float* __restrict__ conv_w,
                            const float* __restrict__ z0, const float* __restrict__ z1,
                            const int* cdrH, const int* notH,
                            const int* cdrL, const int* notL,
                            int nCdrH,int nNotH,int nCdrL,int nNotL, float* ws){
  __shared__ float v[LL1];
  __shared__ float sm[256];
  int tid=threadIdx.x;
  if(blockIdx.x<96){
    int t=blockIdx.x*256+tid;
    if(blockIdx.x==0){ for(int e=tid;e<1536;e+=256) ws[W_BN1S+e]=0.f; }
    if(t<HC*96){
      int o=t/96, c=t-o*96;
      unsigned short vv=0;
      if(c<92){ int d=c>>1, p=c&1; vv=f2bf(conv_w[o*92 + (p? 46+d : d)]); }
      ((unsigned short*)(ws+W_W1P))[t]=vv;
    }
    return;
  }
  int d=blockIdx.x-96;
  float s0=0.f; for(int i=tid;i<LL0;i+=256) s0+=z0[i*DD+d];
  for(int k=tid;k<LL1;k+=256) v[k]=z1[k*DD+d];
  float r0=blockReduceSum(s0,sm);
  __syncthreads();
  float sH=0.f; for(int k=tid;k<CATV;k+=256) sH+=v[k];
  float sL=0.f; for(int k=CATV+tid;k<LL1;k+=256) sL+=v[k];
  float rH=blockReduceSum(sH,sm);
  float rL=blockReduceSum(sL,sm);
  float partH=0.f, partL=0.f;
  for(int i=tid;i<nCdrH;i+=256){
    float c=v[cdrH[i]]; float s=0.f;
    for(int j=0;j<nNotH;j++) s+=fabsf(c-v[notH[j]]);
    s/= (float)nNotH;
    ws[W_RAWMH+d*NC+i]=s; partH+=s;
  }
  for(int i=tid;i<nCdrL;i+=256){
    float c=v[CATV+cdrL[i]]; float s=0.f;
    for(int j=0;j<nNotL;j++) s+=fabsf(c-v[CATV+notL[j]]);
    s/= (float)nNotL;
    ws[W_RAWML+d*NC+i]=s; partL+=s;
  }
  float pH=blockReduceSum(partH,sm);
  float pL=blockReduceSum(partL,sm);
  if(tid==0){
    ws[W_MEAN0+d]=r0/(float)LL0;
    ws[W_MEANH+d]=rH/(float)CATV;
    ws[W_MEANL+d]=rL/(float)(LL1-CATV);
    ws[W_RM4+d]=pH/(float)nCdrH;
    ws[W_RM5+d]=pL/(float)nCdrL;
  }
}

// W2' = W2*sc1 (bf16), bias2' = b2 + sum_k W2[o2,k]*sh1[k]; sc1/sh1 computed inline
__global__ void k_prep2(const float* __restrict__ conv2_w, const float* __restrict__ conv2_b,
                        const float* __restrict__ g1, const float* __restrict__ b1,
                        float* __restrict__ ws){
  __shared__ float sm[256];
  int o2=blockIdx.x, t=threadIdx.x;
  float mu =ws[W_BN1S+t]    *(1.0f/(float)NPOS);
  float ex2=ws[W_BN1S+256+t]*(1.0f/(float)NPOS);
  float var=ex2-mu*mu; if(var<0.f) var=0.f;
  float sc=g1[t]*rsqrtf(var+EPSV);
  float sh=b1[t]-mu*sc;
  float wv=conv2_w[o2*HC+t];
  ((unsigned short*)(ws+W_W2BF))[o2*HC+t]=f2bf(wv*sc);
  float r=blockReduceSum(wv*sh,sm);
  if(t==0) ws[W_BIAS2+o2]=conv2_b[o2]+r;
}

__device__ __forceinline__ float conv3(const float* a, int d, const float* w){
  float acc = w[1]*a[d];
  if(d>0)    acc += w[0]*a[d-1];
  if(d<DD-1) acc += w[2]*a[d+1];
  return acc;
}

// scales + final h, l, hbar + bf16 table copies [j][48]
__global__ void k_scales(const float* w1,const float* w2,const float* w3,
                         const float* w4,const float* w5, float* ws){
  __shared__ float m0[DD], mH[DD], mL[DD];
  __shared__ float s1s[DD],s2s[DD],s3s[DD],s4s[DD],s5s[DD],y4[DD],y5[DD];
  int tid=threadIdx.x;
  if(tid<DD){ m0[tid]=ws[W_MEAN0+tid]; mH[tid]=ws[W_MEANH+tid]; mL[tid]=ws[W_MEANL+tid]; }
  __syncthreads();
  if(tid<DD){
    s1s[tid]=sigf(conv3(m0,tid,w1));
    s2s[tid]=sigf(conv3(mH,tid,w2));
    s3s[tid]=sigf(conv3(mL,tid,w3));
  }
  __syncthreads();
  if(tid<DD){ y4[tid]=s2s[tid]*ws[W_RM4+tid]; y5[tid]=s3s[tid]*ws[W_RM5+tid]; }
  __syncthreads();
  if(tid<DD){
    s4s[tid]=sigf(conv3(y4,tid,w4));
    s5s[tid]=sigf(conv3(y5,tid,w5));
    ws[W_S1+tid]=s1s[tid];
  }
  __syncthreads();
  for(int e=tid;e<DD*NC;e+=256){
    int d=e/NC;
    ws[W_H+e]=s4s[d]*s2s[d]*ws[W_RAWMH+e];
    ws[W_L+e]=s5s[d]*s3s[d]*ws[W_RAWML+e];
  }
  __syncthreads();
  if(tid<DD){
    float s=0.f;
    for(int j=0;j<NC;j++) s+=ws[W_H+tid*NC+j];
    ws[W_HBAR+tid]=s/(float)NC;
  }
  __syncthreads();
  for(int e=tid;e<2400;e+=256){
    int j=e/48, d=e-48*j;
    unsigned short hv=0, lv=0;
    if(d<DD){ hv=f2bf(ws[W_H+d*NC+j]); lv=f2bf(ws[W_L+d*NC+j]); }
    ((unsigned short*)(ws+W_HBF))[e]=hv;
    ((unsigned short*)(ws+W_LBF))[e]=lv;
  }
}

// AWt[i][144] = { a0[48] | dif[48] | mul[48] }
__global__ void k_aw(const float* __restrict__ z0, float* __restrict__ ws){
  int e=blockIdx.x*256+threadIdx.x;
  if(e>=LL0*48) return;
  int i=e/48, d=e-48*i;
  float a=0.f, df=0.f, ml=0.f;
  if(d<DD){
    a = ws[W_S1+d]*z0[i*DD+d];
    float s=0.f;
    #pragma unroll 10
    for(int j=0;j<NC;j++) s+=fabsf(a-ws[W_H+d*NC+j]);
    df = s*(1.0f/(float)NC);
    ml = a*ws[W_HBAR+d];
  }
  ws[W_AWT + i*144 + d]      = a;
  ws[W_AWT + i*144 + 48 + d] = df;
  ws[W_AWT + i*144 + 96 + d] = ml;
}

// stage bf16 h/l tables into LDS via 16B vectors
__device__ __forceinline__ void stage_tables(unsigned short* hT, unsigned short* lT,
                                             const float* __restrict__ ws, int tid){
  for(int e=tid;e<300;e+=256){
    ((u32x4*)hT)[e]=((const u32x4*)(ws+W_HBF))[e];
    ((u32x4*)lT)[e]=((const u32x4*)(ws+W_LBF))[e];
  }
}

// build X tile (bf16, interleaved c=2d+p); HW packed cvt
__device__ __forceinline__ void build_X(unsigned short* Xl, const float* aw,
                                        const unsigned short* hT, const unsigned short* lT,
                                        int n0, int i0, int tid){
  int ibase=i0*100, ib1=ibase+100;
  for(int e=tid;e<NT*12;e+=256){
    int n=e/12, g=e-12*n, d4=g*4;
    int ncol=n0+n;
    int ii=(ncol>=ib1)?1:0;
    int j=ncol-ibase-ii*100;
    const float* ar=aw+ii*144;
    float x10,x11,x12,x13, x20,x21,x22,x23;
    if(j<NC){
      float4 a=*(const float4*)(ar+d4);
      ushort4 hb=*(const ushort4*)(hT+j*48+d4);
      float h0=bf2f(hb.x),h1=bf2f(hb.y),h2=bf2f(hb.z),h3=bf2f(hb.w);
      x10=fabsf(a.x-h0); x20=a.x*h0;
      x11=fabsf(a.y-h1); x21=a.y*h1;
      x12=fabsf(a.z-h2); x22=a.z*h2;
      x13=fabsf(a.w-h3); x23=a.w*h3;
    }else{
      float4 df=*(const float4*)(ar+48+d4);
      float4 ml=*(const float4*)(ar+96+d4);
      ushort4 lb=*(const ushort4*)(lT+(j-NC)*48+d4);
      float l0=bf2f(lb.x),l1=bf2f(lb.y),l2=bf2f(lb.z),l3=bf2f(lb.w);
      x10=fabsf(df.x-l0); x20=fabsf(ml.x-l0);
      x11=fabsf(df.y-l1); x21=fabsf(ml.y-l1);
      x12=fabsf(df.z-l2); x22=fabsf(ml.z-l2);
      x13=fabsf(df.w-l3); x23=fabsf(ml.w-l3);
    }
    u32x4 pv;
    pv.x=pkcvt(x10,x20); pv.y=pkcvt(x11,x21); pv.z=pkcvt(x12,x22); pv.w=pkcvt(x13,x23);
    *(u32x4*)(Xl + n*XROW + 8*g) = pv;
  }
}

// pass A (persistent, group-of-2): build both tiles -> B1 -> gemm both + stats -> B2
__global__ __launch_bounds__(256,2) void k_gemmA(const float* __restrict__ ws,
                                                 const float* __restrict__ conv_b,
                                                 float* __restrict__ bnsum){
  __shared__ unsigned short hT[2400], lT[2400];
  __shared__ float aw[2][576];
  __shared__ unsigned short Xl[2][NT*XROW];
  __shared__ float bnred[512];
  int tid=threadIdx.x;
  int l=tid&63, w=tid>>6, lr=l&15, hi=l>>4, mb=w*64;
  stage_tables(hT,lT,ws,tid);
  const unsigned short* W1p=(const unsigned short*)(ws+W_W1P);
  bf8 w1f[4][3];
  #pragma unroll
  for(int tm=0;tm<4;tm++)
    #pragma unroll
    for(int ks=0;ks<3;ks++)
      w1f[tm][ks]=*(const bf8*)(W1p + (mb+tm*16+lr)*96 + ks*32 + hi*8);
  f32x4 binit[4];
  #pragma unroll
  for(int tm=0;tm<4;tm++)
    #pragma unroll
    for(int r=0;r<4;r++) binit[tm][r]=conv_b[mb+tm*16+hi*4+r];
  float s[4][4], q[4][4];
  #pragma unroll
  for(int tm=0;tm<4;tm++)
    #pragma unroll
    for(int r=0;r<4;r++){ s[tm][r]=0.f; q[tm][r]=0.f; }
  // prologue aw load for group g0 (both tiles)
  if(tid<144){
    int tl=tid/72, off=tid-72*tl;
    int n0=(blockIdx.x*2+tl)*NT;
    ((float4*)aw[0])[tid]=*(((const float4*)(ws+W_AWT+(n0/100)*144))+off);
  }
  __syncthreads();

  int pb=0;
  for(int g=blockIdx.x;g<GROUPS;g+=GRIDP){
    int n0=g*2*NT;
    build_X(Xl[0],aw[pb],     hT,lT,n0,    n0/100,     tid);
    build_X(Xl[1],aw[pb]+288, hT,lT,n0+NT,(n0+NT)/100, tid);
    __syncthreads();                             // B1: X ready; aw consumed
    int nxt=g+GRIDP;
    if(tid<144 && nxt<GROUPS){
      int tl=tid/72, off=tid-72*tl;
      int nn=(nxt*2+tl)*NT;
      ((float4*)aw[pb^1])[tid]=*(((const float4*)(ws+W_AWT+(nn/100)*144))+off);
    }
    #pragma unroll
    for(int sub=0;sub<2;sub++){
      f32x4 acc[4][4];
      #pragma unroll
      for(int tm=0;tm<4;tm++)
        #pragma unroll
        for(int tn=0;tn<4;tn++) acc[tm][tn]=binit[tm];
      __builtin_amdgcn_s_setprio(1);
      #pragma unroll
      for(int ks=0;ks<3;ks++){
        bf8 b[4];
        #pragma unroll
        for(int tn=0;tn<4;tn++)
          b[tn]=*(const bf8*)(Xl[sub] + (tn*16+lr)*XROW + ks*32 + hi*8);
        #pragma unroll
        for(int tm=0;tm<4;tm++)
          #pragma unroll
          for(int tn=0;tn<4;tn++)
            acc[tm][tn]=__builtin_amdgcn_mfma_f32_16x16x32_bf16(w1f[tm][ks],b[tn],acc[tm][tn],0,0,0);
      }
      __builtin_amdgcn_s_setprio(0);
      #pragma unroll
      for(int tm=0;tm<4;tm++)
        #pragma unroll
        for(int tn=0;tn<4;tn++)
          #pragma unroll
          for(int r=0;r<4;r++){
            float vv=fmaxf(acc[tm][tn][r],0.f);
            s[tm][r]+=vv; q[tm][r]+=vv*vv;
          }
    }
    __syncthreads();                             // B2: Xl reads done
    pb^=1;
  }
  #pragma unroll
  for(int m=1;m<16;m<<=1)
    #pragma unroll
    for(int tm=0;tm<4;tm++)
      #pragma unroll
      for(int r=0;r<4;r++){
        s[tm][r]+=__shfl_xor(s[tm][r],m);
        q[tm][r]+=__shfl_xor(q[tm][r],m);
      }
  if(lr==0){
    #pragma unroll
    for(int tm=0;tm<4;tm++)
      #pragma unroll
      for(int r=0;r<4;r++){
        int o=mb+tm*16+hi*4+r;
        bnred[o]=s[tm][r]; bnred[256+o]=q[tm][r];
      }
  }
  __syncthreads();
  for(int e=tid;e<512;e+=256) atomicAdd(&bnsum[e],bnred[e]);
}

// pass B (persistent, pipelined): build(t+1) || gemm1(t); bias in C; cvt_pk packs
__global__ __launch_bounds__(256,2) void k_gemmB(const float* __restrict__ ws,
      const float* __restrict__ conv_b, float* __restrict__ out,
      float* __restrict__ bn2sum){
  __shared__ unsigned short hT[2400], lT[2400];   // 9600 B
  __shared__ float aw[2][288];                    // 2304 B
  __shared__ unsigned short Xl[2][NT*XROW];       // 26624 B
  __shared__ unsigned short C1s[NT*C1ROW];        // 34304 B (C2s reuses this)
  __shared__ float bnred[256];                    // 1024 B
  int tid=threadIdx.x;
  int l=tid&63, w=tid>>6, lr=l&15, hi=l>>4, mb=w*64, mb2=w*32;
  stage_tables(hT,lT,ws,tid);
  const unsigned short* W1p =(const unsigned short*)(ws+W_W1P);
  const unsigned short* W2bf=(const unsigned short*)(ws+W_W2BF);
  const float* bias2=ws+W_BIAS2;
  unsigned* outu=(unsigned*)out;
  bf8 w1f[4][3];
  #pragma unroll
  for(int tm=0;tm<4;tm++)
    #pragma unroll
    for(int ks=0;ks<3;ks++)
      w1f[tm][ks]=*(const bf8*)(W1p + (mb+tm*16+lr)*96 + ks*32 + hi*8);
  bf8 w2f[2][8];
  #pragma unroll
  for(int tm2=0;tm2<2;tm2++)
    #pragma unroll
    for(int ks=0;ks<8;ks++)
      w2f[tm2][ks]=*(const bf8*)(W2bf + (mb2+tm2*16+lr)*HC + ks*32 + hi*8);
  f32x4 binit[4];
  #pragma unroll
  for(int tm=0;tm<4;tm++)
    #pragma unroll
    for(int r=0;r<4;r++) binit[tm][r]=conv_b[mb+tm*16+hi*4+r];
  f32x4 b2init[2];
  #pragma unroll
  for(int tm2=0;tm2<2;tm2++)
    #pragma unroll
    for(int r=0;r<4;r++) b2init[tm2][r]=bias2[mb2+tm2*16+hi*4+r];
  float s2[2][4], q2[2][4];
  #pragma unroll
  for(int tm2=0;tm2<2;tm2++)
    #pragma unroll
    for(int r=0;r<4;r++){ s2[tm2][r]=0.f; q2[tm2][r]=0.f; }
  // prologue
  {
    int t0=blockIdx.x;
    if(tid<72) ((float4*)aw[0])[tid]=*(((const float4*)(ws+W_AWT+((t0*NT)/100)*144))+tid);
    __syncthreads();
    build_X(Xl[0],aw[0],hT,lT,t0*NT,(t0*NT)/100,tid);
    if(tid<72 && t0+GRIDP<TILES)
      ((float4*)aw[1])[tid]=*(((const float4*)(ws+W_AWT+(((t0+GRIDP)*NT)/100)*144))+tid);
    __syncthreads();
  }

  int p=0, qb=1;
  for(int t=blockIdx.x;t<TILES;t+=GRIDP){
    int n0=t*NT, nxt=t+GRIDP, nn2=t+2*GRIDP;
    if(tid<72 && nn2<TILES)
      ((float4*)aw[qb^1])[tid]=*(((const float4*)(ws+W_AWT+((nn2*NT)/100)*144))+tid);
    if(nxt<TILES) build_X(Xl[p^1],aw[qb],hT,lT,nxt*NT,(nxt*NT)/100,tid);
    f32x4 acc[4][4];
    #pragma unroll
    for(int tm=0;tm<4;tm++)
      #pragma unroll
      for(int tn=0;tn<4;tn++) acc[tm][tn]=binit[tm];
    __builtin_amdgcn_s_setprio(1);
    #pragma unroll
    for(int ks=0;ks<3;ks++){
      bf8 b[4];
      #pragma unroll
      for(int tn=0;tn<4;tn++)
        b[tn]=*(const bf8*)(Xl[p] + (tn*16+lr)*XROW + ks*32 + hi*8);
      #pragma unroll
      for(int tm=0;tm<4;tm++)
        #pragma unroll
        for(int tn=0;tn<4;tn++)
          acc[tm][tn]=__builtin_amdgcn_mfma_f32_16x16x32_bf16(w1f[tm][ks],b[tn],acc[tm][tn],0,0,0);
    }
    __builtin_amdgcn_s_setprio(0);
    __syncthreads();                           // B1: build done; Xl[p] reads done
    #pragma unroll
    for(int tm=0;tm<4;tm++)
      #pragma unroll
      for(int tn=0;tn<4;tn++){
        int n=tn*16+lr, ob=mb+tm*16+hi*4;
        float v0=fmaxf(acc[tm][tn][0],0.f);
        float v1=fmaxf(acc[tm][tn][1],0.f);
        float v2=fmaxf(acc[tm][tn][2],0.f);
        float v3=fmaxf(acc[tm][tn][3],0.f);
        uint2 pv; pv.x=pkcvt(v0,v1); pv.y=pkcvt(v2,v3);
        *(uint2*)&C1s[n*C1ROW+ob]=pv;
      }
    __syncthreads();                           // B2: C1 visible
    f32x4 acc2[2][4];
    #pragma unroll
    for(int tm2=0;tm2<2;tm2++)
      #pragma unroll
      for(int tn=0;tn<4;tn++) acc2[tm2][tn]=b2init[tm2];
    __builtin_amdgcn_s_setprio(1);
    #pragma unroll
    for(int ks=0;ks<8;ks++){
      bf8 b2[4];
      #pragma unroll
      for(int tn=0;tn<4;tn++)
        b2[tn]=*(const bf8*)(C1s + (tn*16+lr)*C1ROW + ks*32 + hi*8);
      #pragma unroll
      for(int tm2=0;tm2<2;tm2++)
        #pragma unroll
        for(int tn=0;tn<4;tn++)
          acc2[tm2][tn]=__builtin_amdgcn_mfma_f32_16x16x32_bf16(w2f[tm2][ks],b2[tn],acc2[tm2][tn],0,0,0);
    }
    __builtin_amdgcn_s_setprio(0);
    __syncthreads();                           // B3: C1 reads done
    unsigned* C2s=(unsigned*)C1s;
    #pragma unroll
    for(int tm2=0;tm2<2;tm2++)
      #pragma unroll
      for(int tn=0;tn<4;tn++){
        float v0=fmaxf(acc2[tm2][tn][0],0.f);
        float v1=fmaxf(acc2[tm2][tn][1],0.f);
        float v2=fmaxf(acc2[tm2][tn][2],0.f);
        float v3=fmaxf(acc2[tm2][tn][3],0.f);
        s2[tm2][0]+=v0; q2[tm2][0]+=v0*v0;
        s2[tm2][1]+=v1; q2[tm2][1]+=v1*v1;
        s2[tm2][2]+=v2; q2[tm2][2]+=v2*v2;
        s2[tm2][3]+=v3; q2[tm2][3]+=v3*v3;
        int n=tn*16+lr;
        int q0=(mb2+tm2*16+hi*4)>>1;
        C2s[q0*C2PAD+n]    =pkcvt(v0,v1);
        C2s[(q0+1)*C2PAD+n]=pkcvt(v2,v3);
      }
    __syncthreads();                           // B4: C2s ready
    #pragma unroll
    for(int p16=0;p16<4;p16++){
      int row=p16*16+(tid>>4), chunk=tid&15;
      u32x4 v=*(const u32x4*)&C2s[row*C2PAD+chunk*4];
      *(u32x4*)(outu + (size_t)(2*row)*NPOS + n0 + chunk*4) = v;
    }
    p^=1; qb^=1;
  }
  #pragma unroll
  for(int m=1;m<16;m<<=1)
    #pragma unroll
    for(int tm2=0;tm2<2;tm2++)
      #pragma unroll
      for(int r=0;r<4;r++){
        s2[tm2][r]+=__shfl_xor(s2[tm2][r],m);
        q2[tm2][r]+=__shfl_xor(q2[tm2][r],m);
      }
  if(lr==0){
    #pragma unroll
    for(int tm2=0;tm2<2;tm2++)
      #pragma unroll
      for(int r=0;r<4;r++){
        int o=mb2+tm2*16+hi*4+r;
        bnred[o]=s2[tm2][r]; bnred[128+o]=q2[tm2][r];
      }
  }
  __syncthreads();
  if(tid<256) atomicAdd(&bn2sum[tid],bnred[tid]);
}

// pass C: bf16 pair u32 from even row -> BN2 affine (params inline) -> f32 even+odd
__global__ void k_passC(float* __restrict__ out, const float* __restrict__ ws,
                        const float* __restrict__ g2, const float* __restrict__ b2){
  const int NQ4=NPOS/4;
  const float inv=1.0f/(float)NPOS;
  int idx=blockIdx.x*256+threadIdx.x;
  int stride=gridDim.x*256;
  unsigned* outu=(unsigned*)out;
  for(int e=idx;e<64*NQ4;e+=stride){
    int qq=e/NQ4, nb=(e-qq*NQ4)*4;
    size_t base=(size_t)(2*qq)*NPOS + nb;
    u32x4 v=__builtin_nontemporal_load((const u32x4*)(outu+base));
    float mu0=ws[W_BN2S+2*qq]*inv,   ex0=ws[W_BN2S+H2C+2*qq]*inv;
    float mu1=ws[W_BN2S+2*qq+1]*inv, ex1=ws[W_BN2S+H2C+2*qq+1]*inv;
    float var0=ex0-mu0*mu0; if(var0<0.f) var0=0.f;
    float var1=ex1-mu1*mu1; if(var1<0.f) var1=0.f;
    float sc0=g2[2*qq]*rsqrtf(var0+EPSV),   sh0=b2[2*qq]-mu0*sc0;
    float sc1=g2[2*qq+1]*rsqrtf(var1+EPSV), sh1=b2[2*qq+1]-mu1*sc1;
    f32x4 o0,o1;
    o0.x=bf2f((unsigned short)(v.x&0xffff))*sc0+sh0;
    o1.x=bf2f((unsigned short)(v.x>>16))  *sc1+sh1;
    o0.y=bf2f((unsigned short)(v.y&0xffff))*sc0+sh0;
    o1.y=bf2f((unsigned short)(v.y>>16))  *sc1+sh1;
    o0.z=bf2f((unsigned short)(v.z&0xffff))*sc0+sh0;
    o1.z=bf2f((unsigned short)(v.z>>16))  *sc1+sh1;
    o0.w=bf2f((unsigned short)(v.w&0xffff))*sc0+sh0;
    o1.w=bf2f((unsigned short)(v.w>>16))  *sc1+sh1;
    __builtin_nontemporal_store(o0,(f32x4*)(out+base));
    __builtin_nontemporal_store(o1,(f32x4*)(out+base+NPOS));
  }
}

extern "C" void kernel_launch(void* const* d_in, const int* in_sizes, int n_in,
                              void* d_out, int out_size, void* d_ws, size_t ws_size,
                              hipStream_t stream){
  const float* z0     =(const float*)d_in[0];
  const float* z1     =(const float*)d_in[1];
  const float* we1    =(const float*)d_in[2];
  const float* we2    =(const float*)d_in[3];
  const float* we3    =(const float*)d_in[4];
  const float* we4    =(const float*)d_in[5];
  const float* we5    =(const float*)d_in[6];
  const float* conv_w =(const float*)d_in[7];
  const float* conv_b =(const float*)d_in[8];
  const float* bn_g   =(const float*)d_in[9];
  const float* bn_b   =(const float*)d_in[10];
  const float* conv2_w=(const float*)d_in[11];
  const float* conv2_b=(const float*)d_in[12];
  const float* bn2_g  =(const float*)d_in[13];
  const float* bn2_b  =(const float*)d_in[14];
  const int* cdrH=(const int*)d_in[15];
  const int* cdrL=(const int*)d_in[16];
  const int* notH=(const int*)d_in[17];
  const int* notL=(const int*)d_in[18];
  int nCdrH=in_sizes[15], nCdrL=in_sizes[16], nNotH=in_sizes[17], nNotL=in_sizes[18];
  float* ws=(float*)d_ws;
  float* out=(float*)d_out;

  hipLaunchKernelGGL(k_prepmeans,dim3(96+DD),dim3(256),0,stream, conv_w,z0,z1,cdrH,notH,cdrL,notL,
                     nCdrH,nNotH,nCdrL,nNotL,ws);
  hipLaunchKernelGGL(k_scales,   dim3(1),    dim3(256),0,stream, we1,we2,we3,we4,we5,ws);
  hipLaunchKernelGGL(k_aw,       dim3((LL0*48+255)/256), dim3(256),0,stream, z0,ws);
  hipLaunchKernelGGL(k_gemmA,    dim3(GRIDP),dim3(256),0,stream, ws,conv_b, ws+W_BN1S);
  hipLaunchKernelGGL(k_prep2,    dim3(H2C),  dim3(256),0,stream, conv2_w,conv2_b,bn_g,bn_b,ws);
  hipLaunchKernelGGL(k_gemmB,    dim3(GRIDP),dim3(256),0,stream, ws,conv_b, out, ws+W_BN2S);
  hipLaunchKernelGGL(k_passC,    dim3(2048), dim3(256),0,stream, out, ws, bn2_g, bn2_b);
}

// Round 17
// 206.893 us; speedup vs baseline: 1.5541x; 1.0045x over previous
//
#include <hip/hip_runtime.h>
#include <math.h>

#define DD   46
#define LL0  4000
#define LL1  600
#define CATV 250
#define NC   50
#define NJ   100
#define HC   256
#define H2C  128
#define NPOS (LL0*NJ)
#define EPSV 1e-5f
#define NT   64
#define XROW 104
#define C1ROW 268
#define C2PAD 68
#define TILES (NPOS/NT)   // 6250
#define GROUPS (TILES/2)  // 3125
#define GRIDP 512

// ---- workspace float offsets ----
#define W_MEAN0   0
#define W_MEANH   64
#define W_MEANL   128
#define W_RM4     192
#define W_RM5     256
#define W_S1      320
#define W_HBAR    384
#define W_RAWMH   448
#define W_RAWML   2752
#define W_H       5056
#define W_L       7360
#define W_BN1S    9664            // 256 sum + 256 sumsq
#define W_BN2S    10688           // 128+128
#define W_HBF     11200           // 2400 ushort [j][48]
#define W_LBF     12400           // 2400 ushort
#define W_AWT     13632           // [4001][144] f32
#define W_W1P     589776          // 256*96 bf16
#define W_W2BF    602064          // 128*256 bf16
#define W_BIAS2   618448          // 128 floats

typedef __attribute__((ext_vector_type(8))) short bf8;
typedef __attribute__((ext_vector_type(4))) float f32x4;
typedef __attribute__((ext_vector_type(4))) unsigned u32x4;

__device__ __forceinline__ float sigf(float x){ return 1.0f/(1.0f+__expf(-x)); }

__device__ __forceinline__ unsigned short f2bf(float f){
  unsigned u = __float_as_uint(f);
  return (unsigned short)((u + 0x7FFFu + ((u>>16)&1u)) >> 16);
}
// HW packed f32->bf16 (RTNE): lo=a, hi=b
__device__ __forceinline__ unsigned pkcvt(float a, float b){
  unsigned r;
  asm("v_cvt_pk_bf16_f32 %0, %1, %2" : "=v"(r) : "v"(a), "v"(b));
  return r;
}
__device__ __forceinline__ float bf2f(unsigned short h){
  return __uint_as_float(((unsigned)h)<<16);
}

__device__ float blockReduceSum(float v, float* sm){
  int tid=threadIdx.x;
  sm[tid]=v; __syncthreads();
  for(int s=128;s>0;s>>=1){ if(tid<s) sm[tid]+=sm[tid+s]; __syncthreads(); }
  float r=sm[0]; __syncthreads();
  return r;
}

// fused: blocks 0..95 -> W1 bf16 permute (+stat zero); blocks 96..141 -> means
__global__ void k_prepmeans(const float* __restrict__ conv_w,
                            const float* __restrict__ z0, const float* __restrict__ z1,
                            const int* cdrH, const int* notH,
                            const int* cdrL, const int* notL,
                            int nCdrH,int nNotH,int nCdrL,int nNotL, float* ws){
  __shared__ float v[LL1];
  __shared__ float sm[256];
  int tid=threadIdx.x;
  if(blockIdx.x<96){
    int t=blockIdx.x*256+tid;
    if(blockIdx.x==0){ for(int e=tid;e<1536;e+=256) ws[W_BN1S+e]=0.f; }
    if(t<HC*96){
      int o=t/96, c=t-o*96;
      unsigned short vv=0;
      if(c<92){ int d=c>>1, p=c&1; vv=f2bf(conv_w[o*92 + (p? 46+d : d)]); }
      ((unsigned short*)(ws+W_W1P))[t]=vv;
    }
    return;
  }
  int d=blockIdx.x-96;
  float s0=0.f; for(int i=tid;i<LL0;i+=256) s0+=z0[i*DD+d];
  for(int k=tid;k<LL1;k+=256) v[k]=z1[k*DD+d];
  float r0=blockReduceSum(s0,sm);
  __syncthreads();
  float sH=0.f; for(int k=tid;k<CATV;k+=256) sH+=v[k];
  float sL=0.f; for(int k=CATV+tid;k<LL1;k+=256) sL+=v[k];
  float rH=blockReduceSum(sH,sm);
  float rL=blockReduceSum(sL,sm);
  float partH=0.f, partL=0.f;
  for(int i=tid;i<nCdrH;i+=256){
    float c=v[cdrH[i]]; float s=0.f;
    for(int j=0;j<nNotH;j++) s+=fabsf(c-v[notH[j]]);
    s/= (float)nNotH;
    ws[W_RAWMH+d*NC+i]=s; partH+=s;
  }
  for(int i=tid;i<nCdrL;i+=256){
    float c=v[CATV+cdrL[i]]; float s=0.f;
    for(int j=0;j<nNotL;j++) s+=fabsf(c-v[CATV+notL[j]]);
    s/= (float)nNotL;
    ws[W_RAWML+d*NC+i]=s; partL+=s;
  }
  float pH=blockReduceSum(partH,sm);
  float pL=blockReduceSum(partL,sm);
  if(tid==0){
    ws[W_MEAN0+d]=r0/(float)LL0;
    ws[W_MEANH+d]=rH/(float)CATV;
    ws[W_MEANL+d]=rL/(float)(LL1-CATV);
    ws[W_RM4+d]=pH/(float)nCdrH;
    ws[W_RM5+d]=pL/(float)nCdrL;
  }
}

// W2' = W2*sc1 (bf16), bias2' = b2 + sum_k W2[o2,k]*sh1[k]; sc1/sh1 computed inline
__global__ void k_prep2(const float* __restrict__ conv2_w, const float* __restrict__ conv2_b,
                        const float* __restrict__ g1, const float* __restrict__ b1,
                        float* __restrict__ ws){
  __shared__ float sm[256];
  int o2=blockIdx.x, t=threadIdx.x;
  float mu =ws[W_BN1S+t]    *(1.0f/(float)NPOS);
  float ex2=ws[W_BN1S+256+t]*(1.0f/(float)NPOS);
  float var=ex2-mu*mu; if(var<0.f) var=0.f;
  float sc=g1[t]*rsqrtf(var+EPSV);
  float sh=b1[t]-mu*sc;
  float wv=conv2_w[o2*HC+t];
  ((unsigned short*)(ws+W_W2BF))[o2*HC+t]=f2bf(wv*sc);
  float r=blockReduceSum(wv*sh,sm);
  if(t==0) ws[W_BIAS2+o2]=conv2_b[o2]+r;
}

__device__ __forceinline__ float conv3(const float* a, int d, const float* w){
  float acc = w[1]*a[d];
  if(d>0)    acc += w[0]*a[d-1];
  if(d<DD-1) acc += w[2]*a[d+1];
  return acc;
}

// scales + final h, l, hbar + bf16 table copies [j][48]
__global__ void k_scales(const float* w1,const float* w2,const float* w3,
                         const float* w4,const float* w5, float* ws){
  __shared__ float m0[DD], mH[DD], mL[DD];
  __shared__ float s1s[DD],s2s[DD],s3s[DD],s4s[DD],s5s[DD],y4[DD],y5[DD];
  int tid=threadIdx.x;
  if(tid<DD){ m0[tid]=ws[W_MEAN0+tid]; mH[tid]=ws[W_MEANH+tid]; mL[tid]=ws[W_MEANL+tid]; }
  __syncthreads();
  if(tid<DD){
    s1s[tid]=sigf(conv3(m0,tid,w1));
    s2s[tid]=sigf(conv3(mH,tid,w2));
    s3s[tid]=sigf(conv3(mL,tid,w3));
  }
  __syncthreads();
  if(tid<DD){ y4[tid]=s2s[tid]*ws[W_RM4+tid]; y5[tid]=s3s[tid]*ws[W_RM5+tid]; }
  __syncthreads();
  if(tid<DD){
    s4s[tid]=sigf(conv3(y4,tid,w4));
    s5s[tid]=sigf(conv3(y5,tid,w5));
    ws[W_S1+tid]=s1s[tid];
  }
  __syncthreads();
  for(int e=tid;e<DD*NC;e+=256){
    int d=e/NC;
    ws[W_H+e]=s4s[d]*s2s[d]*ws[W_RAWMH+e];
    ws[W_L+e]=s5s[d]*s3s[d]*ws[W_RAWML+e];
  }
  __syncthreads();
  if(tid<DD){
    float s=0.f;
    for(int j=0;j<NC;j++) s+=ws[W_H+tid*NC+j];
    ws[W_HBAR+tid]=s/(float)NC;
  }
  __syncthreads();
  for(int e=tid;e<2400;e+=256){
    int j=e/48, d=e-48*j;
    unsigned short hv=0, lv=0;
    if(d<DD){ hv=f2bf(ws[W_H+d*NC+j]); lv=f2bf(ws[W_L+d*NC+j]); }
    ((unsigned short*)(ws+W_HBF))[e]=hv;
    ((unsigned short*)(ws+W_LBF))[e]=lv;
  }
}

// AWt[i][144] = { a0[48] | dif[48] | mul[48] }
__global__ void k_aw(const float* __restrict__ z0, float* __restrict__ ws){
  int e=blockIdx.x*256+threadIdx.x;
  if(e>=LL0*48) return;
  int i=e/48, d=e-48*i;
  float a=0.f, df=0.f, ml=0.f;
  if(d<DD){
    a = ws[W_S1+d]*z0[i*DD+d];
    float s=0.f;
    #pragma unroll 10
    for(int j=0;j<NC;j++) s+=fabsf(a-ws[W_H+d*NC+j]);
    df = s*(1.0f/(float)NC);
    ml = a*ws[W_HBAR+d];
  }
  ws[W_AWT + i*144 + d]      = a;
  ws[W_AWT + i*144 + 48 + d] = df;
  ws[W_AWT + i*144 + 96 + d] = ml;
}

// stage bf16 h/l tables into LDS via 16B vectors
__device__ __forceinline__ void stage_tables(unsigned short* hT, unsigned short* lT,
                                             const float* __restrict__ ws, int tid){
  for(int e=tid;e<300;e+=256){
    ((u32x4*)hT)[e]=((const u32x4*)(ws+W_HBF))[e];
    ((u32x4*)lT)[e]=((const u32x4*)(ws+W_LBF))[e];
  }
}

// build X tile (bf16, interleaved c=2d+p); HW packed cvt
__device__ __forceinline__ void build_X(unsigned short* Xl, const float* aw,
                                        const unsigned short* hT, const unsigned short* lT,
                                        int n0, int i0, int tid){
  int ibase=i0*100, ib1=ibase+100;
  for(int e=tid;e<NT*12;e+=256){
    int n=e/12, g=e-12*n, d4=g*4;
    int ncol=n0+n;
    int ii=(ncol>=ib1)?1:0;
    int j=ncol-ibase-ii*100;
    const float* ar=aw+ii*144;
    float x10,x11,x12,x13, x20,x21,x22,x23;
    if(j<NC){
      float4 a=*(const float4*)(ar+d4);
      ushort4 hb=*(const ushort4*)(hT+j*48+d4);
      float h0=bf2f(hb.x),h1=bf2f(hb.y),h2=bf2f(hb.z),h3=bf2f(hb.w);
      x10=fabsf(a.x-h0); x20=a.x*h0;
      x11=fabsf(a.y-h1); x21=a.y*h1;
      x12=fabsf(a.z-h2); x22=a.z*h2;
      x13=fabsf(a.w-h3); x23=a.w*h3;
    }else{
      float4 df=*(const float4*)(ar+48+d4);
      float4 ml=*(const float4*)(ar+96+d4);
      ushort4 lb=*(const ushort4*)(lT+(j-NC)*48+d4);
      float l0=bf2f(lb.x),l1=bf2f(lb.y),l2=bf2f(lb.z),l3=bf2f(lb.w);
      x10=fabsf(df.x-l0); x20=fabsf(ml.x-l0);
      x11=fabsf(df.y-l1); x21=fabsf(ml.y-l1);
      x12=fabsf(df.z-l2); x22=fabsf(ml.z-l2);
      x13=fabsf(df.w-l3); x23=fabsf(ml.w-l3);
    }
    u32x4 pv;
    pv.x=pkcvt(x10,x20); pv.y=pkcvt(x11,x21); pv.z=pkcvt(x12,x22); pv.w=pkcvt(x13,x23);
    *(u32x4*)(Xl + n*XROW + 8*g) = pv;
  }
}

// pass A (persistent, group-of-2): build both tiles -> B1 -> gemm both + stats -> B2
__global__ __launch_bounds__(256,2) void k_gemmA(const float* __restrict__ ws,
                                                 const float* __restrict__ conv_b,
                                                 float* __restrict__ bnsum){
  __shared__ unsigned short hT[2400], lT[2400];
  __shared__ float aw[2][576];
  __shared__ unsigned short Xl[2][NT*XROW];
  __shared__ float bnred[512];
  int tid=threadIdx.x;
  int l=tid&63, w=tid>>6, lr=l&15, hi=l>>4, mb=w*64;
  stage_tables(hT,lT,ws,tid);
  const unsigned short* W1p=(const unsigned short*)(ws+W_W1P);
  bf8 w1f[4][3];
  #pragma unroll
  for(int tm=0;tm<4;tm++)
    #pragma unroll
    for(int ks=0;ks<3;ks++)
      w1f[tm][ks]=*(const bf8*)(W1p + (mb+tm*16+lr)*96 + ks*32 + hi*8);
  f32x4 binit[4];
  #pragma unroll
  for(int tm=0;tm<4;tm++)
    #pragma unroll
    for(int r=0;r<4;r++) binit[tm][r]=conv_b[mb+tm*16+hi*4+r];
  float s[4][4], q[4][4];
  #pragma unroll
  for(int tm=0;tm<4;tm++)
    #pragma unroll
    for(int r=0;r<4;r++){ s[tm][r]=0.f; q[tm][r]=0.f; }
  // prologue aw load for group g0 (both tiles)
  if(tid<144){
    int tl=tid/72, off=tid-72*tl;
    int n0=(blockIdx.x*2+tl)*NT;
    ((float4*)aw[0])[tid]=*(((const float4*)(ws+W_AWT+(n0/100)*144))+off);
  }
  __syncthreads();

  int pb=0;
  for(int g=blockIdx.x;g<GROUPS;g+=GRIDP){
    int n0=g*2*NT;
    build_X(Xl[0],aw[pb],     hT,lT,n0,    n0/100,     tid);
    build_X(Xl[1],aw[pb]+288, hT,lT,n0+NT,(n0+NT)/100, tid);
    __syncthreads();                             // B1: X ready; aw consumed
    int nxt=g+GRIDP;
    if(tid<144 && nxt<GROUPS){
      int tl=tid/72, off=tid-72*tl;
      int nn=(nxt*2+tl)*NT;
      ((float4*)aw[pb^1])[tid]=*(((const float4*)(ws+W_AWT+(nn/100)*144))+off);
    }
    #pragma unroll
    for(int sub=0;sub<2;sub++){
      f32x4 acc[4][4];
      #pragma unroll
      for(int tm=0;tm<4;tm++)
        #pragma unroll
        for(int tn=0;tn<4;tn++) acc[tm][tn]=binit[tm];
      __builtin_amdgcn_s_setprio(1);
      #pragma unroll
      for(int ks=0;ks<3;ks++){
        bf8 b[4];
        #pragma unroll
        for(int tn=0;tn<4;tn++)
          b[tn]=*(const bf8*)(Xl[sub] + (tn*16+lr)*XROW + ks*32 + hi*8);
        #pragma unroll
        for(int tm=0;tm<4;tm++)
          #pragma unroll
          for(int tn=0;tn<4;tn++)
            acc[tm][tn]=__builtin_amdgcn_mfma_f32_16x16x32_bf16(w1f[tm][ks],b[tn],acc[tm][tn],0,0,0);
      }
      __builtin_amdgcn_s_setprio(0);
      #pragma unroll
      for(int tm=0;tm<4;tm++)
        #pragma unroll
        for(int tn=0;tn<4;tn++)
          #pragma unroll
          for(int r=0;r<4;r++){
            float vv=fmaxf(acc[tm][tn][r],0.f);
            s[tm][r]+=vv; q[tm][r]+=vv*vv;
          }
    }
    __syncthreads();                             // B2: Xl reads done
    pb^=1;
  }
  #pragma unroll
  for(int m=1;m<16;m<<=1)
    #pragma unroll
    for(int tm=0;tm<4;tm++)
      #pragma unroll
      for(int r=0;r<4;r++){
        s[tm][r]+=__shfl_xor(s[tm][r],m);
        q[tm][r]+=__shfl_xor(q[tm][r],m);
      }
  if(lr==0){
    #pragma unroll
    for(int tm=0;tm<4;tm++)
      #pragma unroll
      for(int r=0;r<4;r++){
        int o=mb+tm*16+hi*4+r;
        bnred[o]=s[tm][r]; bnred[256+o]=q[tm][r];
      }
  }
  __syncthreads();
  for(int e=tid;e<512;e+=256) atomicAdd(&bnsum[e],bnred[e]);
}

// pass B (persistent, pipelined): build(t+1) || gemm1(t); bias in C; cvt_pk packs
__global__ __launch_bounds__(256,2) void k_gemmB(const float* __restrict__ ws,
      const float* __restrict__ conv_b, float* __restrict__ out,
      float* __restrict__ bn2sum){
  __shared__ unsigned short hT[2400], lT[2400];   // 9600 B
  __shared__ float aw[2][288];                    // 2304 B
  __shared__ unsigned short Xl[2][NT*XROW];       // 26624 B
  __shared__ unsigned short C1s[NT*C1ROW];        // 34304 B (C2s reuses this)
  __shared__ float bnred[256];                    // 1024 B
  int tid=threadIdx.x;
  int l=tid&63, w=tid>>6, lr=l&15, hi=l>>4, mb=w*64, mb2=w*32;
  stage_tables(hT,lT,ws,tid);
  const unsigned short* W1p =(const unsigned short*)(ws+W_W1P);
  const unsigned short* W2bf=(const unsigned short*)(ws+W_W2BF);
  const float* bias2=ws+W_BIAS2;
  unsigned* outu=(unsigned*)out;
  bf8 w1f[4][3];
  #pragma unroll
  for(int tm=0;tm<4;tm++)
    #pragma unroll
    for(int ks=0;ks<3;ks++)
      w1f[tm][ks]=*(const bf8*)(W1p + (mb+tm*16+lr)*96 + ks*32 + hi*8);
  bf8 w2f[2][8];
  #pragma unroll
  for(int tm2=0;tm2<2;tm2++)
    #pragma unroll
    for(int ks=0;ks<8;ks++)
      w2f[tm2][ks]=*(const bf8*)(W2bf + (mb2+tm2*16+lr)*HC + ks*32 + hi*8);
  f32x4 binit[4];
  #pragma unroll
  for(int tm=0;tm<4;tm++)
    #pragma unroll
    for(int r=0;r<4;r++) binit[tm][r]=conv_b[mb+tm*16+hi*4+r];
  f32x4 b2init[2];
  #pragma unroll
  for(int tm2=0;tm2<2;tm2++)
    #pragma unroll
    for(int r=0;r<4;r++) b2init[tm2][r]=bias2[mb2+tm2*16+hi*4+r];
  float s2[2][4], q2[2][4];
  #pragma unroll
  for(int tm2=0;tm2<2;tm2++)
    #pragma unroll
    for(int r=0;r<4;r++){ s2[tm2][r]=0.f; q2[tm2][r]=0.f; }
  // prologue
  {
    int t0=blockIdx.x;
    if(tid<72) ((float4*)aw[0])[tid]=*(((const float4*)(ws+W_AWT+((t0*NT)/100)*144))+tid);
    __syncthreads();
    build_X(Xl[0],aw[0],hT,lT,t0*NT,(t0*NT)/100,tid);
    if(tid<72 && t0+GRIDP<TILES)
      ((float4*)aw[1])[tid]=*(((const float4*)(ws+W_AWT+(((t0+GRIDP)*NT)/100)*144))+tid);
    __syncthreads();
  }

  int p=0, qb=1;
  for(int t=blockIdx.x;t<TILES;t+=GRIDP){
    int n0=t*NT, nxt=t+GRIDP, nn2=t+2*GRIDP;
    if(tid<72 && nn2<TILES)
      ((float4*)aw[qb^1])[tid]=*(((const float4*)(ws+W_AWT+((nn2*NT)/100)*144))+tid);
    if(nxt<TILES) build_X(Xl[p^1],aw[qb],hT,lT,nxt*NT,(nxt*NT)/100,tid);
    f32x4 acc[4][4];
    #pragma unroll
    for(int tm=0;tm<4;tm++)
      #pragma unroll
      for(int tn=0;tn<4;tn++) acc[tm][tn]=binit[tm];
    __builtin_amdgcn_s_setprio(1);
    #pragma unroll
    for(int ks=0;ks<3;ks++){
      bf8 b[4];
      #pragma unroll
      for(int tn=0;tn<4;tn++)
        b[tn]=*(const bf8*)(Xl[p] + (tn*16+lr)*XROW + ks*32 + hi*8);
      #pragma unroll
      for(int tm=0;tm<4;tm++)
        #pragma unroll
        for(int tn=0;tn<4;tn++)
          acc[tm][tn]=__builtin_amdgcn_mfma_f32_16x16x32_bf16(w1f[tm][ks],b[tn],acc[tm][tn],0,0,0);
    }
    __builtin_amdgcn_s_setprio(0);
    __syncthreads();                           // B1: build done; Xl[p] reads done
    #pragma unroll
    for(int tm=0;tm<4;tm++)
      #pragma unroll
      for(int tn=0;tn<4;tn++){
        int n=tn*16+lr, ob=mb+tm*16+hi*4;
        float v0=fmaxf(acc[tm][tn][0],0.f);
        float v1=fmaxf(acc[tm][tn][1],0.f);
        float v2=fmaxf(acc[tm][tn][2],0.f);
        float v3=fmaxf(acc[tm][tn][3],0.f);
        uint2 pv; pv.x=pkcvt(v0,v1); pv.y=pkcvt(v2,v3);
        *(uint2*)&C1s[n*C1ROW+ob]=pv;
      }
    __syncthreads();                           // B2: C1 visible
    f32x4 acc2[2][4];
    #pragma unroll
    for(int tm2=0;tm2<2;tm2++)
      #pragma unroll
      for(int tn=0;tn<4;tn++) acc2[tm2][tn]=b2init[tm2];
    __builtin_amdgcn_s_setprio(1);
    #pragma unroll
    for(int ks=0;ks<8;ks++){
      bf8 b2[4];
      #pragma unroll
      for(int tn=0;tn<4;tn++)
        b2[tn]=*(const bf8*)(C1s + (tn*16+lr)*C1ROW + ks*32 + hi*8);
      #pragma unroll
      for(int tm2=0;tm2<2;tm2++)
        #pragma unroll
        for(int tn=0;tn<4;tn++)
          acc2[tm2][tn]=__builtin_amdgcn_mfma_f32_16x16x32_bf16(w2f[tm2][ks],b2[tn],acc2[tm2][tn],0,0,0);
    }
    __builtin_amdgcn_s_setprio(0);
    __syncthreads();                           // B3: C1 reads done
    unsigned* C2s=(unsigned*)C1s;
    #pragma unroll
    for(int tm2=0;tm2<2;tm2++)
      #pragma unroll
      for(int tn=0;tn<4;tn++){
        float v0=fmaxf(acc2[tm2][tn][0],0.f);
        float v1=fmaxf(acc2[tm2][tn][1],0.f);
        float v2=fmaxf(acc2[tm2][tn][2],0.f);
        float v3=fmaxf(acc2[tm2][tn][3],0.f);
        s2[tm2][0]+=v0; q2[tm2][0]+=v0*v0;
        s2[tm2][1]+=v1; q2[tm2][1]+=v1*v1;
        s2[tm2][2]+=v2; q2[tm2][2]+=v2*v2;
        s2[tm2][3]+=v3; q2[tm2][3]+=v3*v3;
        int n=tn*16+lr;
        int q0=(mb2+tm2*16+hi*4)>>1;
        C2s[q0*C2PAD+n]    =pkcvt(v0,v1);
        C2s[(q0+1)*C2PAD+n]=pkcvt(v2,v3);
      }
    __syncthreads();                           // B4: C2s ready
    #pragma unroll
    for(int p16=0;p16<4;p16++){
      int row=p16*16+(tid>>4), chunk=tid&15;
      u32x4 v=*(const u32x4*)&C2s[row*C2PAD+chunk*4];
      *(u32x4*)(outu + (size_t)(2*row)*NPOS + n0 + chunk*4) = v;
    }
    p^=1; qb^=1;
  }
  #pragma unroll
  for(int m=1;m<16;m<<=1)
    #pragma unroll
    for(int tm2=0;tm2<2;tm2++)
      #pragma unroll
      for(int r=0;r<4;r++){
        s2[tm2][r]+=__shfl_xor(s2[tm2][r],m);
        q2[tm2][r]+=__shfl_xor(q2[tm2][r],m);
      }
  if(lr==0){
    #pragma unroll
    for(int tm2=0;tm2<2;tm2++)
      #pragma unroll
      for(int r=0;r<4;r++){
        int o=mb2+tm2*16+hi*4+r;
        bnred[o]=s2[tm2][r]; bnred[128+o]=q2[tm2][r];
      }
  }
  __syncthreads();
  if(tid<256) atomicAdd(&bn2sum[tid],bnred[tid]);
}

// pass C: bf16 pair u32 from even row -> BN2 affine (params inline) -> f32 even+odd
__global__ void k_passC(float* __restrict__ out, const float* __restrict__ ws,
                        const float* __restrict__ g2, const float* __restrict__ b2){
  const int NQ4=NPOS/4;
  const float inv=1.0f/(float)NPOS;
  int idx=blockIdx.x*256+threadIdx.x;
  int stride=gridDim.x*256;
  unsigned* outu=(unsigned*)out;
  for(int e=idx;e<64*NQ4;e+=stride){
    int qq=e/NQ4, nb=(e-qq*NQ4)*4;
    size_t base=(size_t)(2*qq)*NPOS + nb;
    u32x4 v=__builtin_nontemporal_load((const u32x4*)(outu+base));
    float mu0=ws[W_BN2S+2*qq]*inv,   ex0=ws[W_BN2S+H2C+2*qq]*inv;
    float mu1=ws[W_BN2S+2*qq+1]*inv, ex1=ws[W_BN2S+H2C+2*qq+1]*inv;
    float var0=ex0-mu0*mu0; if(var0<0.f) var0=0.f;
    float var1=ex1-mu1*mu1; if(var1<0.f) var1=0.f;
    float sc0=g2[2*qq]*rsqrtf(var0+EPSV),   sh0=b2[2*qq]-mu0*sc0;
    float sc1=g2[2*qq+1]*rsqrtf(var1+EPSV), sh1=b2[2*qq+1]-mu1*sc1;
    f32x4 o0,o1;
    o0.x=bf2f((unsigned short)(v.x&0xffff))*sc0+sh0;
    o1.x=bf2f((unsigned short)(v.x>>16))  *sc1+sh1;
    o0.y=bf2f((unsigned short)(v.y&0xffff))*sc0+sh0;
    o1.y=bf2f((unsigned short)(v.y>>16))  *sc1+sh1;
    o0.z=bf2f((unsigned short)(v.z&0xffff))*sc0+sh0;
    o1.z=bf2f((unsigned short)(v.z>>16))  *sc1+sh1;
    o0.w=bf2f((unsigned short)(v.w&0xffff))*sc0+sh0;
    o1.w=bf2f((unsigned short)(v.w>>16))  *sc1+sh1;
    __builtin_nontemporal_store(o0,(f32x4*)(out+base));
    __builtin_nontemporal_store(o1,(f32x4*)(out+base+NPOS));
  }
}

extern "C" void kernel_launch(void* const* d_in, const int* in_sizes, int n_in,
                              void* d_out, int out_size, void* d_ws, size_t ws_size,
                              hipStream_t stream){
  const float* z0     =(const float*)d_in[0];
  const float* z1     =(const float*)d_in[1];
  const float* we1    =(const float*)d_in[2];
  const float* we2    =(const float*)d_in[3];
  const float* we3    =(const float*)d_in[4];
  const float* we4    =(const float*)d_in[5];
  const float* we5    =(const float*)d_in[6];
  const float* conv_w =(const float*)d_in[7];
  const float* conv_b =(const float*)d_in[8];
  const float* bn_g   =(const float*)d_in[9];
  const float* bn_b   =(const float*)d_in[10];
  const float* conv2_w=(const float*)d_in[11];
  const float* conv2_b=(const float*)d_in[12];
  const float* bn2_g  =(const float*)d_in[13];
  const float* bn2_b  =(const float*)d_in[14];
  const int* cdrH=(const int*)d_in[15];
  const int* cdrL=(const int*)d_in[16];
  const int* notH=(const int*)d_in[17];
  const int* notL=(const int*)d_in[18];
  int nCdrH=in_sizes[15], nCdrL=in_sizes[16], nNotH=in_sizes[17], nNotL=in_sizes[18];
  float* ws=(float*)d_ws;
  float* out=(float*)d_out;

  hipLaunchKernelGGL(k_prepmeans,dim3(96+DD),dim3(256),0,stream, conv_w,z0,z1,cdrH,notH,cdrL,notL,
                     nCdrH,nNotH,nCdrL,nNotL,ws);
  hipLaunchKernelGGL(k_scales,   dim3(1),    dim3(256),0,stream, we1,we2,we3,we4,we5,ws);
  hipLaunchKernelGGL(k_aw,       dim3((LL0*48+255)/256), dim3(256),0,stream, z0,ws);
  hipLaunchKernelGGL(k_gemmA,    dim3(GRIDP),dim3(256),0,stream, ws,conv_b, ws+W_BN1S);
  hipLaunchKernelGGL(k_prep2,    dim3(H2C),  dim3(256),0,stream, conv2_w,conv2_b,bn_g,bn_b,ws);
  hipLaunchKernelGGL(k_gemmB,    dim3(GRIDP),dim3(256),0,stream, ws,conv_b, out, ws+W_BN2S);
  hipLaunchKernelGGL(k_passC,    dim3(2048), dim3(256),0,stream, out, ws, bn2_g, bn2_b);
}